// Round 1
// baseline (1030.349 us; speedup 1.0000x reference)
//
#include <hip/hip_runtime.h>
#include <hip/hip_bf16.h>

// Problem constants (FraudRGTAN)
#define NN 30000
#define EE 480000
#define DHID 128
#define DNEI 64
#define SNEI 10

// ---------------------------------------------------------------------------
// k_fuse: fusedW[64][128] = mha_out_w @ w_nei ; fusedB = b_in + b_nei + mha_out_b @ w_nei
// (mean over seq commutes with the linear out-proj, so the whole MHA tail
//  collapses to mean_o @ fusedW + fusedB)
// ---------------------------------------------------------------------------
__global__ __launch_bounds__(128) void k_fuse(
    const float* __restrict__ out_w, const float* __restrict__ out_b,
    const float* __restrict__ w_nei, const float* __restrict__ b_nei,
    const float* __restrict__ b_in,
    float* __restrict__ fusedW, float* __restrict__ fusedB) {
  int i = blockIdx.x, j = threadIdx.x;
  if (i < 64) {
    float a = 0.f;
    for (int kk = 0; kk < 64; ++kk) a = fmaf(out_w[i * 64 + kk], w_nei[kk * 128 + j], a);
    fusedW[i * 128 + j] = a;
  } else {
    float a = b_in[j] + b_nei[j];
    for (int kk = 0; kk < 64; ++kk) a = fmaf(out_b[kk], w_nei[kk * 128 + j], a);
    fusedB[j] = a;
  }
}

// ---------------------------------------------------------------------------
// k_mha: per-node multihead self-attention over [10,64], 4 heads of 16.
// One wave per node, 4 nodes per 256-thread block. Output: seq-mean of the
// per-head attention output (pre out-proj) -> mean_o[N][64].
// ---------------------------------------------------------------------------
__global__ __launch_bounds__(256) void k_mha(
    const float* __restrict__ nei, const float* __restrict__ in_w,
    const float* __restrict__ in_b, float* __restrict__ mean_o) {
  __shared__ float xs[4][10 * 68];
  __shared__ float qs[4][10 * 68];
  __shared__ float ks[4][10 * 68];
  __shared__ float vs[4][10 * 68];
  __shared__ float at[4][4 * 10 * 11];
  __shared__ float cs[4][4 * 11];
  int t = threadIdx.x, w = t >> 6, c = t & 63;
  int n = blockIdx.x * 4 + w;

  const float* xp = nei + (size_t)n * (SNEI * DNEI);
  for (int i = 0; i < 10; ++i) xs[w][i * 68 + c] = xp[i * 64 + c];
  __syncthreads();

  // qkv projection: lane c computes column c of q, k, v for all 10 rows
  float qa[10], ka[10], va[10];
  for (int i = 0; i < 10; ++i) { qa[i] = in_b[c]; ka[i] = in_b[64 + c]; va[i] = in_b[128 + c]; }
  for (int kk = 0; kk < 64; ++kk) {
    float wq_ = in_w[kk * 192 + c];
    float wk_ = in_w[kk * 192 + 64 + c];
    float wv_ = in_w[kk * 192 + 128 + c];
#pragma unroll
    for (int i = 0; i < 10; ++i) {
      float xv = xs[w][i * 68 + kk];
      qa[i] = fmaf(xv, wq_, qa[i]);
      ka[i] = fmaf(xv, wk_, ka[i]);
      va[i] = fmaf(xv, wv_, va[i]);
    }
  }
  for (int i = 0; i < 10; ++i) {
    qs[w][i * 68 + c] = qa[i];
    ks[w][i * 68 + c] = ka[i];
    vs[w][i * 68 + c] = va[i];
  }
  __syncthreads();

  // scores + softmax: lane -> (head hh = c>>4, query row qi = c&15), qi<10 active
  int hh = c >> 4, qi = c & 15;
  if (qi < 10) {
    float qreg[16];
#pragma unroll
    for (int d = 0; d < 16; ++d) qreg[d] = qs[w][qi * 68 + hh * 16 + d];
    float sr[10];
    float m = -1e30f;
    for (int j = 0; j < 10; ++j) {
      float s = 0.f;
#pragma unroll
      for (int d = 0; d < 16; ++d) s = fmaf(qreg[d], ks[w][j * 68 + hh * 16 + d], s);
      s *= 0.25f;  // 1/sqrt(hd=16)
      sr[j] = s;
      m = fmaxf(m, s);
    }
    float sum = 0.f;
    for (int j = 0; j < 10; ++j) { sr[j] = expf(sr[j] - m); sum += sr[j]; }
    float inv = 1.f / sum;
    for (int j = 0; j < 10; ++j) at[w][(hh * 10 + qi) * 11 + j] = sr[j] * inv;
  }
  __syncthreads();

  // column sums of attn (mean over i pre-summed): 40 lanes active
  if (c < 40) {
    int h2 = c / 10, j = c % 10;
    float s = 0.f;
    for (int i = 0; i < 10; ++i) s += at[w][(h2 * 10 + i) * 11 + j];
    cs[w][h2 * 11 + j] = s;
  }
  __syncthreads();

  // mean_o[d] = 0.1 * sum_j colsum[head(d)][j] * v[j][d]
  int hd = c >> 4;
  float acc = 0.f;
  for (int j = 0; j < 10; ++j) acc = fmaf(cs[w][hd * 11 + j], vs[w][j * 68 + c], acc);
  mean_o[(size_t)n * 64 + c] = acc * 0.1f;
}

// ---------------------------------------------------------------------------
// k_proj: h = x @ w_in + mean_o @ fusedW + fusedB. Weights persistent in LDS,
// 8 nodes per iteration, 4-node register blocking per thread.
// ---------------------------------------------------------------------------
__global__ __launch_bounds__(256) void k_proj(
    const float* __restrict__ x, const float* __restrict__ w_in,
    const float* __restrict__ fusedW, const float* __restrict__ fusedB,
    const float* __restrict__ mean_o, float* __restrict__ h) {
  __shared__ float ws_[128 * 128];
  __shared__ float fs[64 * 128];
  __shared__ float xs[8][128];
  __shared__ float ms[8][64];
  int t = threadIdx.x;
  for (int i = t; i < 128 * 128; i += 256) ws_[i] = w_in[i];
  for (int i = t; i < 64 * 128; i += 256) fs[i] = fusedW[i];
  float fb = fusedB[t & 127];
  __syncthreads();
  int sub = t >> 7, j = t & 127, nb = sub * 4;
  for (int p = blockIdx.x; p < NN / 8; p += gridDim.x) {
    int n0 = p * 8;
    for (int i = t; i < 1024; i += 256) xs[i >> 7][i & 127] = x[(size_t)(n0 + (i >> 7)) * 128 + (i & 127)];
    for (int i = t; i < 512; i += 256) ms[i >> 6][i & 63] = mean_o[(size_t)(n0 + (i >> 6)) * 64 + (i & 63)];
    __syncthreads();
    float a0 = fb, a1 = fb, a2 = fb, a3 = fb;
    for (int kk = 0; kk < 128; ++kk) {
      float wv_ = ws_[kk * 128 + j];
      a0 = fmaf(xs[nb][kk], wv_, a0);
      a1 = fmaf(xs[nb + 1][kk], wv_, a1);
      a2 = fmaf(xs[nb + 2][kk], wv_, a2);
      a3 = fmaf(xs[nb + 3][kk], wv_, a3);
    }
    for (int kk = 0; kk < 64; ++kk) {
      float fv = fs[kk * 128 + j];
      a0 = fmaf(ms[nb][kk], fv, a0);
      a1 = fmaf(ms[nb + 1][kk], fv, a1);
      a2 = fmaf(ms[nb + 2][kk], fv, a2);
      a3 = fmaf(ms[nb + 3][kk], fv, a3);
    }
    h[(size_t)(n0 + nb) * 128 + j] = a0;
    h[(size_t)(n0 + nb + 1) * 128 + j] = a1;
    h[(size_t)(n0 + nb + 2) * 128 + j] = a2;
    h[(size_t)(n0 + nb + 3) * 128 + j] = a3;
    __syncthreads();
  }
}

// ---------------------------------------------------------------------------
// k_qkv: one of q/k/v = h @ W + b per blockIdx.y. Weight in LDS, 8 nodes/iter.
// ---------------------------------------------------------------------------
__global__ __launch_bounds__(256) void k_qkv(
    const float* __restrict__ h,
    const float* __restrict__ wq, const float* __restrict__ bq,
    const float* __restrict__ wk, const float* __restrict__ bk,
    const float* __restrict__ wv, const float* __restrict__ bv,
    float* __restrict__ q, float* __restrict__ k, float* __restrict__ v) {
  __shared__ float ws_[128 * 128];
  __shared__ float hs[8][128];
  int which = blockIdx.y;
  const float* w = which == 0 ? wq : which == 1 ? wk : wv;
  const float* b = which == 0 ? bq : which == 1 ? bk : bv;
  float* o = which == 0 ? q : which == 1 ? k : v;
  int t = threadIdx.x;
  for (int i = t; i < 128 * 128; i += 256) ws_[i] = w[i];
  float bias = b[t & 127];
  __syncthreads();
  int sub = t >> 7, j = t & 127, nb = sub * 4;
  for (int p = blockIdx.x; p < NN / 8; p += gridDim.x) {
    int n0 = p * 8;
    for (int i = t; i < 1024; i += 256) hs[i >> 7][i & 127] = h[(size_t)(n0 + (i >> 7)) * 128 + (i & 127)];
    __syncthreads();
    float a0 = bias, a1 = bias, a2 = bias, a3 = bias;
    for (int kk = 0; kk < 128; ++kk) {
      float wv_ = ws_[kk * 128 + j];
      a0 = fmaf(hs[nb][kk], wv_, a0);
      a1 = fmaf(hs[nb + 1][kk], wv_, a1);
      a2 = fmaf(hs[nb + 2][kk], wv_, a2);
      a3 = fmaf(hs[nb + 3][kk], wv_, a3);
    }
    o[(size_t)(n0 + nb) * 128 + j] = a0;
    o[(size_t)(n0 + nb + 1) * 128 + j] = a1;
    o[(size_t)(n0 + nb + 2) * 128 + j] = a2;
    o[(size_t)(n0 + nb + 3) * 128 + j] = a3;
    __syncthreads();
  }
}

// ---------------------------------------------------------------------------
// CSR build: histogram -> single-block scan -> scatter
// ---------------------------------------------------------------------------
__global__ __launch_bounds__(256) void k_hist(const int* __restrict__ dst, int* __restrict__ deg) {
  int e = blockIdx.x * 256 + threadIdx.x;
  if (e < EE) atomicAdd(&deg[dst[e]], 1);
}

__global__ __launch_bounds__(1024) void k_scan(const int* __restrict__ deg,
                                               int* __restrict__ rowptr,
                                               int* __restrict__ cursor, int n) {
  __shared__ int wsum[16];
  int t = threadIdx.x, lane = t & 63, wid = t >> 6;
  if (t == 0) rowptr[0] = 0;
  int carry = 0;
  for (int base = 0; base < n; base += 1024) {
    int i = base + t;
    int v = (i < n) ? deg[i] : 0;
    int incl = v;
    for (int off = 1; off < 64; off <<= 1) {
      int x = __shfl_up(incl, off, 64);
      if (lane >= off) incl += x;
    }
    if (lane == 63) wsum[wid] = incl;
    __syncthreads();
    if (wid == 0) {
      int s = (lane < 16) ? wsum[lane] : 0;
      for (int off = 1; off < 16; off <<= 1) {
        int x = __shfl_up(s, off, 64);
        if (lane >= off) s += x;
      }
      if (lane < 16) wsum[lane] = s;
    }
    __syncthreads();
    int waveoff = (wid == 0) ? 0 : wsum[wid - 1];
    int total = wsum[15];
    int excl = carry + waveoff + incl - v;
    if (i < n) { cursor[i] = excl; rowptr[i + 1] = excl + v; }
    carry += total;
    __syncthreads();
  }
}

__global__ __launch_bounds__(256) void k_scatter(const int* __restrict__ dst,
                                                 int* __restrict__ cursor,
                                                 int* __restrict__ eidx) {
  int e = blockIdx.x * 256 + threadIdx.x;
  if (e < EE) {
    int p = atomicAdd(&cursor[dst[e]], 1);
    eidx[p] = e;
  }
}

// ---------------------------------------------------------------------------
// k_score: score[e][hh] = dot32(q[dst] head hh, k[src] head hh) / sqrt(32)
// ---------------------------------------------------------------------------
__global__ __launch_bounds__(256) void k_score(
    const float* __restrict__ q, const float* __restrict__ k,
    const int* __restrict__ src, const int* __restrict__ dst,
    float* __restrict__ score) {
  int gid = blockIdx.x * 256 + threadIdx.x;
  if (gid >= EE * 4) return;
  int e = gid >> 2, hh = gid & 3;
  int d = dst[e], s = src[e];
  const float4* qp = (const float4*)(q + (size_t)d * 128 + hh * 32);
  const float4* kp = (const float4*)(k + (size_t)s * 128 + hh * 32);
  float acc = 0.f;
#pragma unroll
  for (int i = 0; i < 8; ++i) {
    float4 a = qp[i], b = kp[i];
    acc += a.x * b.x + a.y * b.y + a.z * b.z + a.w * b.w;
  }
  score[gid] = acc * 0.17677669529663687f;  // 1/sqrt(32)
}

// ---------------------------------------------------------------------------
// k_agg: gather-based fused segment-softmax + PV + ReLU + LayerNorm.
// One wave per node; lane d handles dims d and d+64 (heads d/32 and 2+d/32).
// ---------------------------------------------------------------------------
__global__ __launch_bounds__(256) void k_agg(
    const float* __restrict__ v, const float* __restrict__ score,
    const int* __restrict__ src, const int* __restrict__ rowptr,
    const int* __restrict__ eidx, const float* __restrict__ g,
    const float* __restrict__ bb, float* __restrict__ h) {
  int t = threadIdx.x, w = t >> 6, lane = t & 63;
  int n = blockIdx.x * 4 + w;
  int start = rowptr[n], end = rowptr[n + 1];
  int hlo = lane >> 5;
  float mlo = -1e30f, mhi = -1e30f;
  for (int i = start; i < end; ++i) {
    int e = eidx[i];
    mlo = fmaxf(mlo, score[e * 4 + hlo]);
    mhi = fmaxf(mhi, score[e * 4 + 2 + hlo]);
  }
  float a0 = 0.f, a1 = 0.f, dlo = 0.f, dhi = 0.f;
  for (int i = start; i < end; ++i) {
    int e = eidx[i];
    int s = src[e];
    float exl = __expf(score[e * 4 + hlo] - mlo);
    float exh = __expf(score[e * 4 + 2 + hlo] - mhi);
    a0 = fmaf(exl, v[(size_t)s * 128 + lane], a0);
    a1 = fmaf(exh, v[(size_t)s * 128 + 64 + lane], a1);
    dlo += exl;
    dhi += exh;
  }
  float o0 = fmaxf(a0 / fmaxf(dlo, 1e-9f), 0.f);
  float o1 = fmaxf(a1 / fmaxf(dhi, 1e-9f), 0.f);
  // LayerNorm over 128 dims (2 per lane)
  float s1 = o0 + o1, s2 = o0 * o0 + o1 * o1;
  for (int off = 1; off < 64; off <<= 1) {
    s1 += __shfl_xor(s1, off, 64);
    s2 += __shfl_xor(s2, off, 64);
  }
  float mean = s1 * (1.f / 128.f);
  float var = s2 * (1.f / 128.f) - mean * mean;
  float rs = rsqrtf(var + 1e-5f);
  h[(size_t)n * 128 + lane] = (o0 - mean) * rs * g[lane] + bb[lane];
  h[(size_t)n * 128 + 64 + lane] = (o1 - mean) * rs * g[64 + lane] + bb[64 + lane];
}

// ---------------------------------------------------------------------------
// k_out: out[n][c] = h[n] . w_out[:,c] + b_out[c]; wave per node, shfl reduce.
// ---------------------------------------------------------------------------
__global__ __launch_bounds__(256) void k_out(
    const float* __restrict__ h, const float* __restrict__ w_out,
    const float* __restrict__ b_out, float* __restrict__ out) {
  int t = threadIdx.x, w = t >> 6, lane = t & 63;
  int n = blockIdx.x * 4 + w;
  float h0 = h[(size_t)n * 128 + lane], h1 = h[(size_t)n * 128 + 64 + lane];
  float p0 = h0 * w_out[lane * 2] + h1 * w_out[(lane + 64) * 2];
  float p1 = h0 * w_out[lane * 2 + 1] + h1 * w_out[(lane + 64) * 2 + 1];
  for (int off = 1; off < 64; off <<= 1) {
    p0 += __shfl_xor(p0, off, 64);
    p1 += __shfl_xor(p1, off, 64);
  }
  if (lane == 0) {
    out[n * 2] = p0 + b_out[0];
    out[n * 2 + 1] = p1 + b_out[1];
  }
}

// ---------------------------------------------------------------------------
extern "C" void kernel_launch(void* const* d_in, const int* in_sizes, int n_in,
                              void* d_out, int out_size, void* d_ws, size_t ws_size,
                              hipStream_t stream) {
  const float* x = (const float*)d_in[0];
  const float* neif = (const float*)d_in[1];
  const int* ei = (const int*)d_in[2];
  const float* w_in = (const float*)d_in[3];
  const float* b_in = (const float*)d_in[4];
  const float* mha_in_w = (const float*)d_in[5];
  const float* mha_in_b = (const float*)d_in[6];
  const float* mha_out_w = (const float*)d_in[7];
  const float* mha_out_b = (const float*)d_in[8];
  const float* w_nei = (const float*)d_in[9];
  const float* b_nei = (const float*)d_in[10];
  const float* wq = (const float*)d_in[11];
  const float* bq = (const float*)d_in[12];
  const float* wk = (const float*)d_in[13];
  const float* bk = (const float*)d_in[14];
  const float* wv = (const float*)d_in[15];
  const float* bv = (const float*)d_in[16];
  const float* ln_g = (const float*)d_in[17];
  const float* ln_b = (const float*)d_in[18];
  const float* w_out = (const float*)d_in[19];
  const float* b_out = (const float*)d_in[20];
  float* out = (float*)d_out;

  // workspace layout (~71.4 MB)
  float* wsf = (float*)d_ws;
  float* h = wsf;                              // N*128
  float* qb = h + (size_t)NN * 128;            // N*128
  float* kb = qb + (size_t)NN * 128;           // N*128
  float* vb = kb + (size_t)NN * 128;           // N*128
  float* score = vb + (size_t)NN * 128;        // E*4  (aliases mean_o = N*64)
  float* fusedW = score + (size_t)EE * 4;      // 64*128
  float* fusedB = fusedW + 64 * 128;           // 128
  int* deg = (int*)(fusedB + 128);             // N
  int* rowptr = deg + NN;                      // N+1
  int* cursor = rowptr + NN + 1;               // N
  int* eidx = cursor + NN;                     // E
  float* mean_o = score;

  k_fuse<<<65, 128, 0, stream>>>(mha_out_w, mha_out_b, w_nei, b_nei, b_in, fusedW, fusedB);
  k_mha<<<NN / 4, 256, 0, stream>>>(neif, mha_in_w, mha_in_b, mean_o);
  k_proj<<<256, 256, 0, stream>>>(x, w_in, fusedW, fusedB, mean_o, h);

  for (int l = 0; l < 2; ++l) {
    const int* srcA = ei + (size_t)l * 2 * EE;
    const int* dstA = srcA + EE;
    k_qkv<<<dim3(170, 3), 256, 0, stream>>>(h, wq + (size_t)l * 128 * 128, bq + l * 128,
                                            wk + (size_t)l * 128 * 128, bk + l * 128,
                                            wv + (size_t)l * 128 * 128, bv + l * 128,
                                            qb, kb, vb);
    hipMemsetAsync(deg, 0, NN * sizeof(int), stream);
    k_hist<<<(EE + 255) / 256, 256, 0, stream>>>(dstA, deg);
    k_scan<<<1, 1024, 0, stream>>>(deg, rowptr, cursor, NN);
    k_scatter<<<(EE + 255) / 256, 256, 0, stream>>>(dstA, cursor, eidx);
    k_score<<<(EE * 4 + 255) / 256, 256, 0, stream>>>(qb, kb, srcA, dstA, score);
    k_agg<<<NN / 4, 256, 0, stream>>>(vb, score, srcA, rowptr, eidx,
                                      ln_g + l * 128, ln_b + l * 128, h);
  }

  k_out<<<NN / 4, 256, 0, stream>>>(h, w_out, b_out, out);
}

// Round 2
// 813.171 us; speedup vs baseline: 1.2671x; 1.2671x over previous
//
#include <hip/hip_runtime.h>
#include <hip/hip_bf16.h>

#define NN 30000
#define EE 480000
#define DHID 128
#define DNEI 64
#define SNEI 10

typedef __attribute__((ext_vector_type(8))) short short8;
typedef __attribute__((ext_vector_type(4))) float floatx4;

__device__ __forceinline__ short f2bf(float f) {
  union { float f; unsigned u; } v; v.f = f;
  unsigned u = v.u;
  u += 0x7FFFu + ((u >> 16) & 1u);  // RNE
  return (short)(u >> 16);
}

// ---------------------------------------------------------------------------
// k_fuse: fusedW[64][128] = mha_out_w @ w_nei ; fusedB = b_in + b_nei + mha_out_b @ w_nei
// ---------------------------------------------------------------------------
__global__ __launch_bounds__(128) void k_fuse(
    const float* __restrict__ out_w, const float* __restrict__ out_b,
    const float* __restrict__ w_nei, const float* __restrict__ b_nei,
    const float* __restrict__ b_in,
    float* __restrict__ fusedW, float* __restrict__ fusedB) {
  int i = blockIdx.x, j = threadIdx.x;
  if (i < 64) {
    float a = 0.f;
    for (int kk = 0; kk < 64; ++kk) a = fmaf(out_w[i * 64 + kk], w_nei[kk * 128 + j], a);
    fusedW[i * 128 + j] = a;
  } else {
    float a = b_in[j] + b_nei[j];
    for (int kk = 0; kk < 64; ++kk) a = fmaf(out_b[kk], w_nei[kk * 128 + j], a);
    fusedB[j] = a;
  }
}

// ---------------------------------------------------------------------------
// k_mha2: fused QKV-MFMA-GEMM + per-node attention. 16 nodes / block (640 thr,
// 10 waves). QKV = X[160,64]@W[64,192] via mfma_f32_16x16x32_bf16, fp32 result
// staged in LDS (stride 194), then register/shuffle attention -> mean_o.
// ---------------------------------------------------------------------------
__global__ __launch_bounds__(640) void k_mha2(
    const float* __restrict__ x,     // nei_features flat [300000, 64]
    const float* __restrict__ in_w,  // [64, 192]
    const float* __restrict__ in_b,  // [192]
    float* __restrict__ mean_o) {    // [NN, 64]
  __shared__ __align__(16) short bt[192 * 64];   // B^T bf16, XOR-swizzled 16B blocks
  __shared__ float qk[160 * 194];                // QKV fp32
  int t = threadIdx.x;
  for (int i = t; i < 192 * 64; i += 640) {
    int c = i >> 6, k = i & 63;
    bt[c * 64 + (((k >> 3) ^ (c & 7)) << 3) + (k & 7)] = f2bf(in_w[k * 192 + c]);
  }
  __syncthreads();

  int w = t >> 6, l = t & 63;
  int lr = l & 15, lq = l >> 4;
  int row0 = blockIdx.x * 160 + w * 16;

  // A fragments (2 K-halves) straight from global, convert to bf16
  const float* xp = x + (size_t)(row0 + lr) * 64 + (lq << 3);
  float4 fa0 = *(const float4*)xp;
  float4 fa1 = *(const float4*)(xp + 4);
  float4 fb0 = *(const float4*)(xp + 32);
  float4 fb1 = *(const float4*)(xp + 36);
  short8 a0, a1;
  a0[0] = f2bf(fa0.x); a0[1] = f2bf(fa0.y); a0[2] = f2bf(fa0.z); a0[3] = f2bf(fa0.w);
  a0[4] = f2bf(fa1.x); a0[5] = f2bf(fa1.y); a0[6] = f2bf(fa1.z); a0[7] = f2bf(fa1.w);
  a1[0] = f2bf(fb0.x); a1[1] = f2bf(fb0.y); a1[2] = f2bf(fb0.z); a1[3] = f2bf(fb0.w);
  a1[4] = f2bf(fb1.x); a1[5] = f2bf(fb1.y); a1[6] = f2bf(fb1.z); a1[7] = f2bf(fb1.w);

  floatx4 acc[12];
#pragma unroll
  for (int n = 0; n < 12; ++n) acc[n] = (floatx4){0.f, 0.f, 0.f, 0.f};
#pragma unroll
  for (int n = 0; n < 12; ++n) {
    int c = n * 16 + lr;
    short8 b0 = *(const short8*)&bt[c * 64 + ((lq ^ (c & 7)) << 3)];
    short8 b1 = *(const short8*)&bt[c * 64 + (((4 + lq) ^ (c & 7)) << 3)];
    acc[n] = __builtin_amdgcn_mfma_f32_16x16x32_bf16(a0, b0, acc[n], 0, 0, 0);
    acc[n] = __builtin_amdgcn_mfma_f32_16x16x32_bf16(a1, b1, acc[n], 0, 0, 0);
  }
  // epilogue: C[(lq*4+r)][n*16+lr] + bias -> LDS
#pragma unroll
  for (int n = 0; n < 12; ++n) {
    float bias = in_b[n * 16 + lr];
#pragma unroll
    for (int r = 0; r < 4; ++r) {
      int m = (lq << 2) + r;
      qk[(w * 16 + m) * 194 + n * 16 + lr] = acc[n][r] + bias;
    }
  }
  __syncthreads();

  // attention: wave handles nodes w, w+10. lane = (head hh, query qi).
  int hh = lq, qi = lr;
  for (int node = w; node < 16; node += 10) {
    int nb = node * 10;
    float at_row[10];
    if (qi < 10) {
      float qreg[16];
#pragma unroll
      for (int d = 0; d < 16; ++d) qreg[d] = qk[(nb + qi) * 194 + hh * 16 + d];
      float m = -1e30f;
#pragma unroll
      for (int j = 0; j < 10; ++j) {
        float s = 0.f;
#pragma unroll
        for (int d = 0; d < 16; ++d) s = fmaf(qreg[d], qk[(nb + j) * 194 + 64 + hh * 16 + d], s);
        s *= 0.25f;
        at_row[j] = s;
        m = fmaxf(m, s);
      }
      float sum = 0.f;
#pragma unroll
      for (int j = 0; j < 10; ++j) { at_row[j] = __expf(at_row[j] - m); sum += at_row[j]; }
      float inv = 1.f / sum;
#pragma unroll
      for (int j = 0; j < 10; ++j) at_row[j] *= inv;
    } else {
#pragma unroll
      for (int j = 0; j < 10; ++j) at_row[j] = 0.f;
    }
    float acc2 = 0.f;
#pragma unroll
    for (int j = 0; j < 10; ++j) {
      float cs = at_row[j];
      cs += __shfl_xor(cs, 1, 16);
      cs += __shfl_xor(cs, 2, 16);
      cs += __shfl_xor(cs, 4, 16);
      cs += __shfl_xor(cs, 8, 16);
      acc2 = fmaf(cs, qk[(nb + j) * 194 + 128 + l], acc2);
    }
    mean_o[(size_t)(blockIdx.x * 16 + node) * 64 + l] = acc2 * 0.1f;
  }
}

// ---------------------------------------------------------------------------
// k_proj: h = x @ w_in + mean_o @ fusedW + fusedB
// ---------------------------------------------------------------------------
__global__ __launch_bounds__(256) void k_proj(
    const float* __restrict__ x, const float* __restrict__ w_in,
    const float* __restrict__ fusedW, const float* __restrict__ fusedB,
    const float* __restrict__ mean_o, float* __restrict__ h) {
  __shared__ float ws_[128 * 128];
  __shared__ float fs[64 * 128];
  __shared__ float xs[8][128];
  __shared__ float ms[8][64];
  int t = threadIdx.x;
  for (int i = t; i < 128 * 128; i += 256) ws_[i] = w_in[i];
  for (int i = t; i < 64 * 128; i += 256) fs[i] = fusedW[i];
  float fb = fusedB[t & 127];
  __syncthreads();
  int sub = t >> 7, j = t & 127, nb = sub * 4;
  for (int p = blockIdx.x; p < NN / 8; p += gridDim.x) {
    int n0 = p * 8;
    for (int i = t; i < 1024; i += 256) xs[i >> 7][i & 127] = x[(size_t)(n0 + (i >> 7)) * 128 + (i & 127)];
    for (int i = t; i < 512; i += 256) ms[i >> 6][i & 63] = mean_o[(size_t)(n0 + (i >> 6)) * 64 + (i & 63)];
    __syncthreads();
    float a0 = fb, a1 = fb, a2 = fb, a3 = fb;
    for (int kk = 0; kk < 128; ++kk) {
      float wv_ = ws_[kk * 128 + j];
      a0 = fmaf(xs[nb][kk], wv_, a0);
      a1 = fmaf(xs[nb + 1][kk], wv_, a1);
      a2 = fmaf(xs[nb + 2][kk], wv_, a2);
      a3 = fmaf(xs[nb + 3][kk], wv_, a3);
    }
    for (int kk = 0; kk < 64; ++kk) {
      float fv = fs[kk * 128 + j];
      a0 = fmaf(ms[nb][kk], fv, a0);
      a1 = fmaf(ms[nb + 1][kk], fv, a1);
      a2 = fmaf(ms[nb + 2][kk], fv, a2);
      a3 = fmaf(ms[nb + 3][kk], fv, a3);
    }
    h[(size_t)(n0 + nb) * 128 + j] = a0;
    h[(size_t)(n0 + nb + 1) * 128 + j] = a1;
    h[(size_t)(n0 + nb + 2) * 128 + j] = a2;
    h[(size_t)(n0 + nb + 3) * 128 + j] = a3;
    __syncthreads();
  }
}

// ---------------------------------------------------------------------------
// k_qkv: q/k/v = h @ W + b (blockIdx.y picks which)
// ---------------------------------------------------------------------------
__global__ __launch_bounds__(256) void k_qkv(
    const float* __restrict__ h,
    const float* __restrict__ wq, const float* __restrict__ bq,
    const float* __restrict__ wk, const float* __restrict__ bk,
    const float* __restrict__ wv, const float* __restrict__ bv,
    float* __restrict__ q, float* __restrict__ k, float* __restrict__ v) {
  __shared__ float ws_[128 * 128];
  __shared__ float hs[8][128];
  int which = blockIdx.y;
  const float* w = which == 0 ? wq : which == 1 ? wk : wv;
  const float* b = which == 0 ? bq : which == 1 ? bk : bv;
  float* o = which == 0 ? q : which == 1 ? k : v;
  int t = threadIdx.x;
  for (int i = t; i < 128 * 128; i += 256) ws_[i] = w[i];
  float bias = b[t & 127];
  __syncthreads();
  int sub = t >> 7, j = t & 127, nb = sub * 4;
  for (int p = blockIdx.x; p < NN / 8; p += gridDim.x) {
    int n0 = p * 8;
    for (int i = t; i < 1024; i += 256) hs[i >> 7][i & 127] = h[(size_t)(n0 + (i >> 7)) * 128 + (i & 127)];
    __syncthreads();
    float a0 = bias, a1 = bias, a2 = bias, a3 = bias;
    for (int kk = 0; kk < 128; ++kk) {
      float wv_ = ws_[kk * 128 + j];
      a0 = fmaf(hs[nb][kk], wv_, a0);
      a1 = fmaf(hs[nb + 1][kk], wv_, a1);
      a2 = fmaf(hs[nb + 2][kk], wv_, a2);
      a3 = fmaf(hs[nb + 3][kk], wv_, a3);
    }
    o[(size_t)(n0 + nb) * 128 + j] = a0;
    o[(size_t)(n0 + nb + 1) * 128 + j] = a1;
    o[(size_t)(n0 + nb + 2) * 128 + j] = a2;
    o[(size_t)(n0 + nb + 3) * 128 + j] = a3;
    __syncthreads();
  }
}

// ---------------------------------------------------------------------------
// CSR build, both layers at once. Segments: l*NN + dst.
// ---------------------------------------------------------------------------
__global__ __launch_bounds__(256) void k_hist2(const int* __restrict__ ei, int* __restrict__ deg) {
  int g = blockIdx.x * 256 + threadIdx.x;
  if (g < 2 * EE) {
    int l = g >= EE;
    int e = g - l * EE;
    int d = ei[(size_t)(2 * l + 1) * EE + e];
    atomicAdd(&deg[l * NN + d], 1);
  }
}

__global__ __launch_bounds__(1024) void k_scan(const int* __restrict__ deg,
                                               int* __restrict__ rowptr,
                                               int* __restrict__ cursor, int n) {
  __shared__ int wsum[16];
  int t = threadIdx.x, lane = t & 63, wid = t >> 6;
  if (t == 0) rowptr[0] = 0;
  int carry = 0;
  for (int base = 0; base < n; base += 1024) {
    int i = base + t;
    int v = (i < n) ? deg[i] : 0;
    int incl = v;
    for (int off = 1; off < 64; off <<= 1) {
      int x = __shfl_up(incl, off, 64);
      if (lane >= off) incl += x;
    }
    if (lane == 63) wsum[wid] = incl;
    __syncthreads();
    if (wid == 0) {
      int s = (lane < 16) ? wsum[lane] : 0;
      for (int off = 1; off < 16; off <<= 1) {
        int x = __shfl_up(s, off, 64);
        if (lane >= off) s += x;
      }
      if (lane < 16) wsum[lane] = s;
    }
    __syncthreads();
    int waveoff = (wid == 0) ? 0 : wsum[wid - 1];
    int total = wsum[15];
    int excl = carry + waveoff + incl - v;
    if (i < n) { cursor[i] = excl; rowptr[i + 1] = excl + v; }
    carry += total;
    __syncthreads();
  }
}

__global__ __launch_bounds__(256) void k_scatter2(const int* __restrict__ ei,
                                                  int* __restrict__ cursor,
                                                  int* __restrict__ srcS,
                                                  int* __restrict__ dstS) {
  int g = blockIdx.x * 256 + threadIdx.x;
  if (g < 2 * EE) {
    int l = g >= EE;
    int e = g - l * EE;
    int s = ei[(size_t)(2 * l) * EE + e];
    int d = ei[(size_t)(2 * l + 1) * EE + e];
    int p = atomicAdd(&cursor[l * NN + d], 1);
    srcS[p] = s;
    dstS[p] = d;
  }
}

// ---------------------------------------------------------------------------
// k_score2: sorted edges -> score[i*4+h] = dot32(q[dstS[i]],k[srcS[i]])/sqrt(32)
// ---------------------------------------------------------------------------
__global__ __launch_bounds__(256) void k_score2(
    const float* __restrict__ q, const float* __restrict__ k,
    const int* __restrict__ srcS, const int* __restrict__ dstS,
    float* __restrict__ score) {
  int gid = blockIdx.x * 256 + threadIdx.x;
  if (gid >= EE * 4) return;
  int i = gid >> 2, hh = gid & 3;
  int d = dstS[i], s = srcS[i];
  const float4* qp = (const float4*)(q + (size_t)d * 128 + hh * 32);
  const float4* kp = (const float4*)(k + (size_t)s * 128 + hh * 32);
  float acc = 0.f;
#pragma unroll
  for (int u = 0; u < 8; ++u) {
    float4 a = qp[u], b = kp[u];
    acc += a.x * b.x + a.y * b.y + a.z * b.z + a.w * b.w;
  }
  score[gid] = acc * 0.17677669529663687f;
}

// ---------------------------------------------------------------------------
// k_agg2: single-pass online segment-softmax + PV + ReLU + LayerNorm.
// Sorted edge layout: positions [rowptr[n], rowptr[n+1]) sequential.
// ---------------------------------------------------------------------------
__global__ __launch_bounds__(256) void k_agg2(
    const float* __restrict__ v, const float* __restrict__ score,
    const int* __restrict__ srcS, const int* __restrict__ rowptr, int base,
    const float* __restrict__ g, const float* __restrict__ bb,
    float* __restrict__ h) {
  int t = threadIdx.x, w = t >> 6, lane = t & 63;
  int n = blockIdx.x * 4 + w;
  int start = rowptr[n], end = rowptr[n + 1];
  int hlo = lane >> 5;
  float m0 = -1e30f, m1 = -1e30f, a0 = 0.f, a1 = 0.f, d0 = 0.f, d1 = 0.f;
  for (int p = start; p < end; ++p) {
    int s = srcS[p];
    float sc0 = score[(p - base) * 4 + hlo];
    float sc1 = score[(p - base) * 4 + 2 + hlo];
    if (sc0 > m0) { float r = __expf(m0 - sc0); a0 *= r; d0 *= r; m0 = sc0; }
    if (sc1 > m1) { float r = __expf(m1 - sc1); a1 *= r; d1 *= r; m1 = sc1; }
    float f0 = __expf(sc0 - m0), f1 = __expf(sc1 - m1);
    a0 = fmaf(f0, v[(size_t)s * 128 + lane], a0);
    a1 = fmaf(f1, v[(size_t)s * 128 + 64 + lane], a1);
    d0 += f0;
    d1 += f1;
  }
  float o0 = fmaxf(a0 / fmaxf(d0, 1e-9f), 0.f);
  float o1 = fmaxf(a1 / fmaxf(d1, 1e-9f), 0.f);
  float s1 = o0 + o1, s2 = o0 * o0 + o1 * o1;
  for (int off = 1; off < 64; off <<= 1) {
    s1 += __shfl_xor(s1, off, 64);
    s2 += __shfl_xor(s2, off, 64);
  }
  float mean = s1 * (1.f / 128.f);
  float var = s2 * (1.f / 128.f) - mean * mean;
  float rs = rsqrtf(var + 1e-5f);
  h[(size_t)n * 128 + lane] = (o0 - mean) * rs * g[lane] + bb[lane];
  h[(size_t)n * 128 + 64 + lane] = (o1 - mean) * rs * g[64 + lane] + bb[64 + lane];
}

// ---------------------------------------------------------------------------
__global__ __launch_bounds__(256) void k_out(
    const float* __restrict__ h, const float* __restrict__ w_out,
    const float* __restrict__ b_out, float* __restrict__ out) {
  int t = threadIdx.x, w = t >> 6, lane = t & 63;
  int n = blockIdx.x * 4 + w;
  float h0 = h[(size_t)n * 128 + lane], h1 = h[(size_t)n * 128 + 64 + lane];
  float p0 = h0 * w_out[lane * 2] + h1 * w_out[(lane + 64) * 2];
  float p1 = h0 * w_out[lane * 2 + 1] + h1 * w_out[(lane + 64) * 2 + 1];
  for (int off = 1; off < 64; off <<= 1) {
    p0 += __shfl_xor(p0, off, 64);
    p1 += __shfl_xor(p1, off, 64);
  }
  if (lane == 0) {
    out[n * 2] = p0 + b_out[0];
    out[n * 2 + 1] = p1 + b_out[1];
  }
}

// ---------------------------------------------------------------------------
extern "C" void kernel_launch(void* const* d_in, const int* in_sizes, int n_in,
                              void* d_out, int out_size, void* d_ws, size_t ws_size,
                              hipStream_t stream) {
  const float* x = (const float*)d_in[0];
  const float* neif = (const float*)d_in[1];
  const int* ei = (const int*)d_in[2];
  const float* w_in = (const float*)d_in[3];
  const float* b_in = (const float*)d_in[4];
  const float* mha_in_w = (const float*)d_in[5];
  const float* mha_in_b = (const float*)d_in[6];
  const float* mha_out_w = (const float*)d_in[7];
  const float* mha_out_b = (const float*)d_in[8];
  const float* w_nei = (const float*)d_in[9];
  const float* b_nei = (const float*)d_in[10];
  const float* wq = (const float*)d_in[11];
  const float* bq = (const float*)d_in[12];
  const float* wk = (const float*)d_in[13];
  const float* bk = (const float*)d_in[14];
  const float* wv = (const float*)d_in[15];
  const float* bv = (const float*)d_in[16];
  const float* ln_g = (const float*)d_in[17];
  const float* ln_b = (const float*)d_in[18];
  const float* w_out = (const float*)d_in[19];
  const float* b_out = (const float*)d_in[20];
  float* out = (float*)d_out;

  // workspace layout (~78 MB)
  float* wsf = (float*)d_ws;
  float* h = wsf;                           // N*128
  float* qb = h + (size_t)NN * 128;         // N*128
  float* kb = qb + (size_t)NN * 128;        // N*128
  float* vb = kb + (size_t)NN * 128;        // N*128
  float* score = vb + (size_t)NN * 128;     // E*4 (aliases mean_o = N*64)
  float* fusedW = score + (size_t)EE * 4;   // 64*128
  float* fusedB = fusedW + 64 * 128;        // 128
  int* deg = (int*)(fusedB + 128);          // 2N
  int* rowptr = deg + 2 * NN;               // 2N+1
  int* cursor = rowptr + 2 * NN + 1;        // 2N
  int* srcS = cursor + 2 * NN;              // 2E
  int* dstS = srcS + 2 * EE;                // 2E
  float* mean_o = score;

  k_fuse<<<65, 128, 0, stream>>>(mha_out_w, mha_out_b, w_nei, b_nei, b_in, fusedW, fusedB);
  k_mha2<<<NN / 16, 640, 0, stream>>>(neif, mha_in_w, mha_in_b, mean_o);
  k_proj<<<256, 256, 0, stream>>>(x, w_in, fusedW, fusedB, mean_o, h);

  // CSR for both layers, once
  hipMemsetAsync(deg, 0, 2 * NN * sizeof(int), stream);
  k_hist2<<<(2 * EE + 255) / 256, 256, 0, stream>>>(ei, deg);
  k_scan<<<1, 1024, 0, stream>>>(deg, rowptr, cursor, 2 * NN);
  k_scatter2<<<(2 * EE + 255) / 256, 256, 0, stream>>>(ei, cursor, srcS, dstS);

  for (int l = 0; l < 2; ++l) {
    k_qkv<<<dim3(170, 3), 256, 0, stream>>>(h, wq + (size_t)l * 128 * 128, bq + l * 128,
                                            wk + (size_t)l * 128 * 128, bk + l * 128,
                                            wv + (size_t)l * 128 * 128, bv + l * 128,
                                            qb, kb, vb);
    k_score2<<<(EE * 4 + 255) / 256, 256, 0, stream>>>(qb, kb, srcS + (size_t)l * EE,
                                                       dstS + (size_t)l * EE, score);
    k_agg2<<<NN / 4, 256, 0, stream>>>(vb, score, srcS, rowptr + l * NN, l * EE,
                                       ln_g + l * 128, ln_b + l * 128, h);
  }

  k_out<<<NN / 4, 256, 0, stream>>>(h, w_out, b_out, out);
}

// Round 3
// 540.873 us; speedup vs baseline: 1.9050x; 1.5034x over previous
//
#include <hip/hip_runtime.h>
#include <hip/hip_bf16.h>

#define NN 30000
#define EE 480000

typedef __attribute__((ext_vector_type(8))) short short8;
typedef __attribute__((ext_vector_type(4))) float floatx4;
typedef unsigned short u16;

__device__ __forceinline__ u16 f2bf(float f) {
  union { float f; unsigned u; } v; v.f = f;
  unsigned u = v.u;
  u += 0x7FFFu + ((u >> 16) & 1u);  // RNE
  return (u16)(u >> 16);
}
__device__ __forceinline__ float bf2f(u16 u) {
  union { unsigned u; float f; } v; v.u = ((unsigned)u) << 16;
  return v.f;
}

// ---------------------------------------------------------------------------
// k_fuse: fusedW[64][128] = mha_out_w @ w_nei ; fusedB = b_in + b_nei + mha_out_b @ w_nei
// ---------------------------------------------------------------------------
__global__ __launch_bounds__(128) void k_fuse(
    const float* __restrict__ out_w, const float* __restrict__ out_b,
    const float* __restrict__ w_nei, const float* __restrict__ b_nei,
    const float* __restrict__ b_in,
    float* __restrict__ fusedW, float* __restrict__ fusedB) {
  int i = blockIdx.x, j = threadIdx.x;
  if (i < 64) {
    float a = 0.f;
    for (int kk = 0; kk < 64; ++kk) a = fmaf(out_w[i * 64 + kk], w_nei[kk * 128 + j], a);
    fusedW[i * 128 + j] = a;
  } else {
    float a = b_in[j] + b_nei[j];
    for (int kk = 0; kk < 64; ++kk) a = fmaf(out_b[kk], w_nei[kk * 128 + j], a);
    fusedB[j] = a;
  }
}

// ---------------------------------------------------------------------------
// prep kernels: transpose weights to bf16 [c][k] scratch; convert x to bf16
// ---------------------------------------------------------------------------
__global__ __launch_bounds__(128) void k_prepW(
    const float* __restrict__ wq, const float* __restrict__ wk,
    const float* __restrict__ wv, u16* __restrict__ wt3) {
  int bx = blockIdx.x;            // (l*3+o)*128 + c, 768 blocks
  int l = bx / 384, rem = bx % 384, o = rem >> 7, c = rem & 127, k = threadIdx.x;
  const float* w = (o == 0 ? wq : (o == 1 ? wk : wv)) + (size_t)l * 16384;
  wt3[(size_t)bx * 128 + k] = f2bf(w[(size_t)k * 128 + c]);
}

__global__ __launch_bounds__(192) void k_prepP(
    const float* __restrict__ w_in, const float* __restrict__ fusedW,
    u16* __restrict__ wtP) {
  int c = blockIdx.x, k = threadIdx.x;
  float v = (k < 128) ? w_in[(size_t)k * 128 + c] : fusedW[(size_t)(k - 128) * 128 + c];
  wtP[(size_t)c * 192 + k] = f2bf(v);
}

__global__ __launch_bounds__(256) void k_prepX(const float* __restrict__ x, u16* __restrict__ xb) {
  int i = blockIdx.x * 256 + threadIdx.x;
  if (i < NN * 128 / 4) {
    float4 v = ((const float4*)x)[i];
    uint2 o;
    o.x = (unsigned)f2bf(v.x) | ((unsigned)f2bf(v.y) << 16);
    o.y = (unsigned)f2bf(v.z) | ((unsigned)f2bf(v.w) << 16);
    ((uint2*)xb)[i] = o;
  }
}

// ---------------------------------------------------------------------------
// k_mha2: fused QKV-MFMA + per-node attention over [10,64], 16 nodes/block.
// Output mean_o in bf16.
// ---------------------------------------------------------------------------
__global__ __launch_bounds__(640) void k_mha2(
    const float* __restrict__ x, const float* __restrict__ in_w,
    const float* __restrict__ in_b, u16* __restrict__ mob) {
  __shared__ __align__(16) short bt[192 * 64];
  __shared__ float qk[160 * 194];
  int t = threadIdx.x;
  for (int i = t; i < 192 * 64; i += 640) {
    int c = i >> 6, k = i & 63;
    bt[c * 64 + (((k >> 3) ^ (c & 7)) << 3) + (k & 7)] = (short)f2bf(in_w[k * 192 + c]);
  }
  __syncthreads();

  int w = t >> 6, l = t & 63;
  int lr = l & 15, lq = l >> 4;
  int row0 = blockIdx.x * 160 + w * 16;

  const float* xp = x + (size_t)(row0 + lr) * 64 + (lq << 3);
  float4 fa0 = *(const float4*)xp;
  float4 fa1 = *(const float4*)(xp + 4);
  float4 fb0 = *(const float4*)(xp + 32);
  float4 fb1 = *(const float4*)(xp + 36);
  short8 a0, a1;
  a0[0] = f2bf(fa0.x); a0[1] = f2bf(fa0.y); a0[2] = f2bf(fa0.z); a0[3] = f2bf(fa0.w);
  a0[4] = f2bf(fa1.x); a0[5] = f2bf(fa1.y); a0[6] = f2bf(fa1.z); a0[7] = f2bf(fa1.w);
  a1[0] = f2bf(fb0.x); a1[1] = f2bf(fb0.y); a1[2] = f2bf(fb0.z); a1[3] = f2bf(fb0.w);
  a1[4] = f2bf(fb1.x); a1[5] = f2bf(fb1.y); a1[6] = f2bf(fb1.z); a1[7] = f2bf(fb1.w);

  floatx4 acc[12];
#pragma unroll
  for (int n = 0; n < 12; ++n) acc[n] = (floatx4){0.f, 0.f, 0.f, 0.f};
#pragma unroll
  for (int n = 0; n < 12; ++n) {
    int c = n * 16 + lr;
    short8 b0 = *(const short8*)&bt[c * 64 + ((lq ^ (c & 7)) << 3)];
    short8 b1 = *(const short8*)&bt[c * 64 + (((4 + lq) ^ (c & 7)) << 3)];
    acc[n] = __builtin_amdgcn_mfma_f32_16x16x32_bf16(a0, b0, acc[n], 0, 0, 0);
    acc[n] = __builtin_amdgcn_mfma_f32_16x16x32_bf16(a1, b1, acc[n], 0, 0, 0);
  }
#pragma unroll
  for (int n = 0; n < 12; ++n) {
    float bias = in_b[n * 16 + lr];
#pragma unroll
    for (int r = 0; r < 4; ++r) {
      int m = (lq << 2) + r;
      qk[(w * 16 + m) * 194 + n * 16 + lr] = acc[n][r] + bias;
    }
  }
  __syncthreads();

  int hh = lq, qi = lr;
  for (int node = w; node < 16; node += 10) {
    int nb = node * 10;
    float at_row[10];
    if (qi < 10) {
      float qreg[16];
#pragma unroll
      for (int d = 0; d < 16; ++d) qreg[d] = qk[(nb + qi) * 194 + hh * 16 + d];
      float m = -1e30f;
#pragma unroll
      for (int j = 0; j < 10; ++j) {
        float s = 0.f;
#pragma unroll
        for (int d = 0; d < 16; ++d) s = fmaf(qreg[d], qk[(nb + j) * 194 + 64 + hh * 16 + d], s);
        s *= 0.25f;
        at_row[j] = s;
        m = fmaxf(m, s);
      }
      float sum = 0.f;
#pragma unroll
      for (int j = 0; j < 10; ++j) { at_row[j] = __expf(at_row[j] - m); sum += at_row[j]; }
      float inv = 1.f / sum;
#pragma unroll
      for (int j = 0; j < 10; ++j) at_row[j] *= inv;
    } else {
#pragma unroll
      for (int j = 0; j < 10; ++j) at_row[j] = 0.f;
    }
    float acc2 = 0.f;
#pragma unroll
    for (int j = 0; j < 10; ++j) {
      float cs = at_row[j];
      cs += __shfl_xor(cs, 1, 16);
      cs += __shfl_xor(cs, 2, 16);
      cs += __shfl_xor(cs, 4, 16);
      cs += __shfl_xor(cs, 8, 16);
      acc2 = fmaf(cs, qk[(nb + j) * 194 + 128 + l], acc2);
    }
    mob[(size_t)(blockIdx.x * 16 + node) * 64 + l] = f2bf(acc2 * 0.1f);
  }
}

// ---------------------------------------------------------------------------
// k_proj3: h_bf = bf16( x@w_in + mean_o@fusedW + fusedB ), MFMA, K=192.
// 64 rows/block, wave = 16 rows x 128 cols.
// ---------------------------------------------------------------------------
__global__ __launch_bounds__(256) void k_proj3(
    const u16* __restrict__ xb, const u16* __restrict__ mob,
    const u16* __restrict__ wtP, const float* __restrict__ fusedB,
    u16* __restrict__ hb) {
  int t = threadIdx.x, w = t >> 6, l = t & 63, lr = l & 15, lq = l >> 4;
  int row0 = blockIdx.x * 64 + w * 16;
  int arow = row0 + lr; if (arow >= NN) arow = NN - 1;
  const short8* ap = (const short8*)(xb + (size_t)arow * 128);
  const short8* mp = (const short8*)(mob + (size_t)arow * 64);
  short8 a0 = ap[lq], a1 = ap[4 + lq], a2 = ap[8 + lq], a3 = ap[12 + lq];
  short8 a4 = mp[lq], a5 = mp[4 + lq];
  const short8* wt8 = (const short8*)wtP;
  floatx4 acc[8];
#pragma unroll
  for (int ct = 0; ct < 8; ++ct) acc[ct] = (floatx4){0.f, 0.f, 0.f, 0.f};
#pragma unroll
  for (int ct = 0; ct < 8; ++ct) {
    const short8* bp = wt8 + (size_t)(ct * 16 + lr) * 24;
    acc[ct] = __builtin_amdgcn_mfma_f32_16x16x32_bf16(a0, bp[lq], acc[ct], 0, 0, 0);
    acc[ct] = __builtin_amdgcn_mfma_f32_16x16x32_bf16(a1, bp[4 + lq], acc[ct], 0, 0, 0);
    acc[ct] = __builtin_amdgcn_mfma_f32_16x16x32_bf16(a2, bp[8 + lq], acc[ct], 0, 0, 0);
    acc[ct] = __builtin_amdgcn_mfma_f32_16x16x32_bf16(a3, bp[12 + lq], acc[ct], 0, 0, 0);
    acc[ct] = __builtin_amdgcn_mfma_f32_16x16x32_bf16(a4, bp[16 + lq], acc[ct], 0, 0, 0);
    acc[ct] = __builtin_amdgcn_mfma_f32_16x16x32_bf16(a5, bp[20 + lq], acc[ct], 0, 0, 0);
  }
#pragma unroll
  for (int ct = 0; ct < 8; ++ct) {
    int col = ct * 16 + lr;
    float bias = fusedB[col];
#pragma unroll
    for (int r = 0; r < 4; ++r) {
      int row = row0 + lq * 4 + r;
      if (row < NN) hb[(size_t)row * 128 + col] = f2bf(acc[ct][r] + bias);
    }
  }
}

// ---------------------------------------------------------------------------
// k_qkv3: q,k,v (bf16) = h_bf @ {wq,wk,wv} + b, MFMA, K=128, cols=384.
// 64 rows/block, wave = 16 rows x 384 cols (24 col-tiles).
// ---------------------------------------------------------------------------
__global__ __launch_bounds__(256) void k_qkv3(
    const u16* __restrict__ hb, const u16* __restrict__ wt3l,
    const float* __restrict__ bqL, const float* __restrict__ bkL,
    const float* __restrict__ bvL,
    u16* __restrict__ qb, u16* __restrict__ kb, u16* __restrict__ vb) {
  int t = threadIdx.x, w = t >> 6, l = t & 63, lr = l & 15, lq = l >> 4;
  int row0 = blockIdx.x * 64 + w * 16;
  int arow = row0 + lr; if (arow >= NN) arow = NN - 1;
  const short8* ap = (const short8*)(hb + (size_t)arow * 128);
  short8 a0 = ap[lq], a1 = ap[4 + lq], a2 = ap[8 + lq], a3 = ap[12 + lq];
  const short8* wt8 = (const short8*)wt3l;
  floatx4 acc[24];
#pragma unroll
  for (int ct = 0; ct < 24; ++ct) acc[ct] = (floatx4){0.f, 0.f, 0.f, 0.f};
#pragma unroll
  for (int ct = 0; ct < 24; ++ct) {
    const short8* bp = wt8 + (size_t)((ct >> 3) * 128 + (ct & 7) * 16 + lr) * 16;
    acc[ct] = __builtin_amdgcn_mfma_f32_16x16x32_bf16(a0, bp[lq], acc[ct], 0, 0, 0);
    acc[ct] = __builtin_amdgcn_mfma_f32_16x16x32_bf16(a1, bp[4 + lq], acc[ct], 0, 0, 0);
    acc[ct] = __builtin_amdgcn_mfma_f32_16x16x32_bf16(a2, bp[8 + lq], acc[ct], 0, 0, 0);
    acc[ct] = __builtin_amdgcn_mfma_f32_16x16x32_bf16(a3, bp[12 + lq], acc[ct], 0, 0, 0);
  }
#pragma unroll
  for (int ct = 0; ct < 24; ++ct) {
    int o = ct >> 3, col = (ct & 7) * 16 + lr;
    const float* bp2 = o == 0 ? bqL : (o == 1 ? bkL : bvL);
    u16* op = o == 0 ? qb : (o == 1 ? kb : vb);
    float bias = bp2[col];
#pragma unroll
    for (int r = 0; r < 4; ++r) {
      int row = row0 + lq * 4 + r;
      if (row < NN) op[(size_t)row * 128 + col] = f2bf(acc[ct][r] + bias);
    }
  }
}

// ---------------------------------------------------------------------------
// CSR build over both layers (segments l*NN + dst)
// ---------------------------------------------------------------------------
__global__ __launch_bounds__(256) void k_hist2(const int* __restrict__ ei, int* __restrict__ deg) {
  int g = blockIdx.x * 256 + threadIdx.x;
  if (g < 2 * EE) {
    int l = g >= EE;
    int e = g - l * EE;
    int d = ei[(size_t)(2 * l + 1) * EE + e];
    atomicAdd(&deg[l * NN + d], 1);
  }
}

__global__ __launch_bounds__(1024) void k_scan(const int* __restrict__ deg,
                                               int* __restrict__ rowptr,
                                               int* __restrict__ cursor, int n) {
  __shared__ int wsum[16];
  int t = threadIdx.x, lane = t & 63, wid = t >> 6;
  if (t == 0) rowptr[0] = 0;
  int carry = 0;
  for (int base = 0; base < n; base += 1024) {
    int i = base + t;
    int v = (i < n) ? deg[i] : 0;
    int incl = v;
    for (int off = 1; off < 64; off <<= 1) {
      int x = __shfl_up(incl, off, 64);
      if (lane >= off) incl += x;
    }
    if (lane == 63) wsum[wid] = incl;
    __syncthreads();
    if (wid == 0) {
      int s = (lane < 16) ? wsum[lane] : 0;
      for (int off = 1; off < 16; off <<= 1) {
        int x = __shfl_up(s, off, 64);
        if (lane >= off) s += x;
      }
      if (lane < 16) wsum[lane] = s;
    }
    __syncthreads();
    int waveoff = (wid == 0) ? 0 : wsum[wid - 1];
    int total = wsum[15];
    int excl = carry + waveoff + incl - v;
    if (i < n) { cursor[i] = excl; rowptr[i + 1] = excl + v; }
    carry += total;
    __syncthreads();
  }
}

__global__ __launch_bounds__(256) void k_scatter2(const int* __restrict__ ei,
                                                  int* __restrict__ cursor,
                                                  int* __restrict__ srcS) {
  int g = blockIdx.x * 256 + threadIdx.x;
  if (g < 2 * EE) {
    int l = g >= EE;
    int e = g - l * EE;
    int s = ei[(size_t)(2 * l) * EE + e];
    int d = ei[(size_t)(2 * l + 1) * EE + e];
    int p = atomicAdd(&cursor[l * NN + d], 1);
    srcS[p] = s;
  }
}

// ---------------------------------------------------------------------------
// k_sagg: fused edge-score + online segment-softmax + PV + ReLU + LayerNorm.
// One wave per node; per edge: dot(q[n],k[src]) via shfl reduce, then PV.
// ---------------------------------------------------------------------------
__global__ __launch_bounds__(256) void k_sagg(
    const u16* __restrict__ qb, const u16* __restrict__ kb,
    const u16* __restrict__ vb, const int* __restrict__ srcS,
    const int* __restrict__ rowptr, const float* __restrict__ g,
    const float* __restrict__ bb, u16* __restrict__ hb) {
  int t = threadIdx.x, w = t >> 6, lane = t & 63;
  int n = blockIdx.x * 4 + w;
  int start = rowptr[n], end = rowptr[n + 1];
  float qlo = bf2f(qb[(size_t)n * 128 + lane]);
  float qhi = bf2f(qb[(size_t)n * 128 + 64 + lane]);
  float m0 = -1e30f, m1 = -1e30f, a0 = 0.f, a1 = 0.f, d0 = 0.f, d1 = 0.f;
  for (int p = start; p < end; ++p) {
    int s = srcS[p];
    const u16* kr = kb + (size_t)s * 128;
    const u16* vr = vb + (size_t)s * 128;
    float klo = bf2f(kr[lane]), khi = bf2f(kr[64 + lane]);
    float vlo = bf2f(vr[lane]), vhi = bf2f(vr[64 + lane]);
    float r0 = qlo * klo, r1 = qhi * khi;
#pragma unroll
    for (int off = 1; off < 32; off <<= 1) {
      r0 += __shfl_xor(r0, off, 64);
      r1 += __shfl_xor(r1, off, 64);
    }
    float sc0 = r0 * 0.17677669529663687f;
    float sc1 = r1 * 0.17677669529663687f;
    if (sc0 > m0) { float rr = __expf(m0 - sc0); a0 *= rr; d0 *= rr; m0 = sc0; }
    if (sc1 > m1) { float rr = __expf(m1 - sc1); a1 *= rr; d1 *= rr; m1 = sc1; }
    float f0 = __expf(sc0 - m0), f1 = __expf(sc1 - m1);
    a0 = fmaf(f0, vlo, a0); d0 += f0;
    a1 = fmaf(f1, vhi, a1); d1 += f1;
  }
  float o0 = fmaxf(a0 / fmaxf(d0, 1e-9f), 0.f);
  float o1 = fmaxf(a1 / fmaxf(d1, 1e-9f), 0.f);
  float s1 = o0 + o1, s2 = o0 * o0 + o1 * o1;
#pragma unroll
  for (int off = 1; off < 64; off <<= 1) {
    s1 += __shfl_xor(s1, off, 64);
    s2 += __shfl_xor(s2, off, 64);
  }
  float mean = s1 * (1.f / 128.f);
  float var = s2 * (1.f / 128.f) - mean * mean;
  float rs = rsqrtf(var + 1e-5f);
  hb[(size_t)n * 128 + lane] = f2bf((o0 - mean) * rs * g[lane] + bb[lane]);
  hb[(size_t)n * 128 + 64 + lane] = f2bf((o1 - mean) * rs * g[64 + lane] + bb[64 + lane]);
}

// ---------------------------------------------------------------------------
__global__ __launch_bounds__(256) void k_out(
    const u16* __restrict__ hb, const float* __restrict__ w_out,
    const float* __restrict__ b_out, float* __restrict__ out) {
  int t = threadIdx.x, w = t >> 6, lane = t & 63;
  int n = blockIdx.x * 4 + w;
  float h0 = bf2f(hb[(size_t)n * 128 + lane]);
  float h1 = bf2f(hb[(size_t)n * 128 + 64 + lane]);
  float p0 = h0 * w_out[lane * 2] + h1 * w_out[(lane + 64) * 2];
  float p1 = h0 * w_out[lane * 2 + 1] + h1 * w_out[(lane + 64) * 2 + 1];
#pragma unroll
  for (int off = 1; off < 64; off <<= 1) {
    p0 += __shfl_xor(p0, off, 64);
    p1 += __shfl_xor(p1, off, 64);
  }
  if (lane == 0) {
    out[n * 2] = p0 + b_out[0];
    out[n * 2 + 1] = p1 + b_out[1];
  }
}

// ---------------------------------------------------------------------------
extern "C" void kernel_launch(void* const* d_in, const int* in_sizes, int n_in,
                              void* d_out, int out_size, void* d_ws, size_t ws_size,
                              hipStream_t stream) {
  const float* x = (const float*)d_in[0];
  const float* neif = (const float*)d_in[1];
  const int* ei = (const int*)d_in[2];
  const float* w_in = (const float*)d_in[3];
  const float* b_in = (const float*)d_in[4];
  const float* mha_in_w = (const float*)d_in[5];
  const float* mha_in_b = (const float*)d_in[6];
  const float* mha_out_w = (const float*)d_in[7];
  const float* mha_out_b = (const float*)d_in[8];
  const float* w_nei = (const float*)d_in[9];
  const float* b_nei = (const float*)d_in[10];
  const float* wq = (const float*)d_in[11];
  const float* bq = (const float*)d_in[12];
  const float* wk = (const float*)d_in[13];
  const float* bk = (const float*)d_in[14];
  const float* wv = (const float*)d_in[15];
  const float* bv = (const float*)d_in[16];
  const float* ln_g = (const float*)d_in[17];
  const float* ln_b = (const float*)d_in[18];
  const float* w_out = (const float*)d_in[19];
  const float* b_out = (const float*)d_in[20];
  float* out = (float*)d_out;

  // workspace layout (~47 MB)
  float* fusedW = (float*)d_ws;               // 64*128
  float* fusedB = fusedW + 64 * 128;          // 128
  u16* hb  = (u16*)(fusedB + 128);            // N*128
  u16* xb  = hb + (size_t)NN * 128;           // N*128
  u16* qb_ = xb + (size_t)NN * 128;           // N*128
  u16* kb_ = qb_ + (size_t)NN * 128;          // N*128
  u16* vb_ = kb_ + (size_t)NN * 128;          // N*128
  u16* mob = vb_ + (size_t)NN * 128;          // N*64
  u16* wt3 = mob + (size_t)NN * 64;           // 2*3*128*128
  u16* wtP = wt3 + 2 * 3 * 128 * 128;         // 128*192
  int* deg = (int*)(wtP + 128 * 192);         // 2N
  int* rowptr = deg + 2 * NN;                 // 2N+1
  int* cursor = rowptr + 2 * NN + 1;          // 2N
  int* srcS = cursor + 2 * NN;                // 2E

  k_fuse<<<65, 128, 0, stream>>>(mha_out_w, mha_out_b, w_nei, b_nei, b_in, fusedW, fusedB);
  k_prepW<<<768, 128, 0, stream>>>(wq, wk, wv, wt3);
  k_prepX<<<3750, 256, 0, stream>>>(x, xb);
  k_prepP<<<128, 192, 0, stream>>>(w_in, fusedW, wtP);
  k_mha2<<<NN / 16, 640, 0, stream>>>(neif, mha_in_w, mha_in_b, mob);
  k_proj3<<<469, 256, 0, stream>>>(xb, mob, wtP, fusedB, hb);

  hipMemsetAsync(deg, 0, 2 * NN * sizeof(int), stream);
  k_hist2<<<(2 * EE + 255) / 256, 256, 0, stream>>>(ei, deg);
  k_scan<<<1, 1024, 0, stream>>>(deg, rowptr, cursor, 2 * NN);
  k_scatter2<<<(2 * EE + 255) / 256, 256, 0, stream>>>(ei, cursor, srcS);

  for (int l = 0; l < 2; ++l) {
    k_qkv3<<<469, 256, 0, stream>>>(hb, wt3 + (size_t)l * 3 * 128 * 128,
                                    bq + l * 128, bk + l * 128, bv + l * 128,
                                    qb_, kb_, vb_);
    k_sagg<<<NN / 4, 256, 0, stream>>>(qb_, kb_, vb_, srcS, rowptr + l * NN,
                                       ln_g + l * 128, ln_b + l * 128, hb);
  }

  k_out<<<NN / 4, 256, 0, stream>>>(hb, w_out, b_out, out);
}

// Round 4
// 365.653 us; speedup vs baseline: 2.8178x; 1.4792x over previous
//
#include <hip/hip_runtime.h>
#include <hip/hip_bf16.h>

#define NN 30000
#define EE 480000

typedef __attribute__((ext_vector_type(8))) short short8;
typedef __attribute__((ext_vector_type(4))) short short4v;
typedef __attribute__((ext_vector_type(4))) float floatx4;
typedef unsigned short u16;

__device__ __forceinline__ u16 f2bf(float f) {
  union { float f; unsigned u; } v; v.f = f;
  unsigned u = v.u;
  u += 0x7FFFu + ((u >> 16) & 1u);  // RNE
  return (u16)(u >> 16);
}
__device__ __forceinline__ float bf2f(u16 u) {
  union { unsigned u; float f; } v; v.u = ((unsigned)u) << 16;
  return v.f;
}
__device__ __forceinline__ float bflo(unsigned u) {
  union { unsigned x; float f; } v; v.x = u << 16; return v.f;
}
__device__ __forceinline__ float bfhi(unsigned u) {
  union { unsigned x; float f; } v; v.x = u & 0xFFFF0000u; return v.f;
}
__device__ __forceinline__ unsigned packbf(float a, float b) {
  return (unsigned)f2bf(a) | ((unsigned)f2bf(b) << 16);
}

#define MFMA32 __builtin_amdgcn_mfma_f32_16x16x32_bf16

#if __has_builtin(__builtin_amdgcn_mfma_f32_16x16x16bf16_1k)
__device__ __forceinline__ floatx4 MFMA16(short4v a, short4v b, floatx4 c) {
  return __builtin_amdgcn_mfma_f32_16x16x16bf16_1k(a, b, c, 0, 0, 0);
}
#else
__device__ __forceinline__ floatx4 MFMA16(short4v a, short4v b, floatx4 c) {
  asm volatile("v_mfma_f32_16x16x16_bf16 %0, %1, %2, %0"
               : "+v"(c) : "v"(a), "v"(b));
  return c;
}
#endif

// ---------------------------------------------------------------------------
// k_fuse: fusedW[64][128] = mha_out_w @ w_nei ; fusedB = b_in + b_nei + mha_out_b @ w_nei
// ---------------------------------------------------------------------------
__global__ __launch_bounds__(128) void k_fuse(
    const float* __restrict__ out_w, const float* __restrict__ out_b,
    const float* __restrict__ w_nei, const float* __restrict__ b_nei,
    const float* __restrict__ b_in,
    float* __restrict__ fusedW, float* __restrict__ fusedB) {
  int i = blockIdx.x, j = threadIdx.x;
  if (i < 64) {
    float a = 0.f;
    for (int kk = 0; kk < 64; ++kk) a = fmaf(out_w[i * 64 + kk], w_nei[kk * 128 + j], a);
    fusedW[i * 128 + j] = a;
  } else {
    float a = b_in[j] + b_nei[j];
    for (int kk = 0; kk < 64; ++kk) a = fmaf(out_b[kk], w_nei[kk * 128 + j], a);
    fusedB[j] = a;
  }
}

// ---------------------------------------------------------------------------
// prep kernels
// ---------------------------------------------------------------------------
__global__ __launch_bounds__(128) void k_prepW(
    const float* __restrict__ wq, const float* __restrict__ wk,
    const float* __restrict__ wv, u16* __restrict__ wt3) {
  int bx = blockIdx.x;  // (l*3+o)*128 + c
  int l = bx / 384, rem = bx % 384, o = rem >> 7, c = rem & 127, k = threadIdx.x;
  const float* w = (o == 0 ? wq : (o == 1 ? wk : wv)) + (size_t)l * 16384;
  wt3[(size_t)bx * 128 + k] = f2bf(w[(size_t)k * 128 + c]);
}

__global__ __launch_bounds__(192) void k_prepP(
    const float* __restrict__ w_in, const float* __restrict__ fusedW,
    u16* __restrict__ wtP) {
  int c = blockIdx.x, k = threadIdx.x;
  float v = (k < 128) ? w_in[(size_t)k * 128 + c] : fusedW[(size_t)(k - 128) * 128 + c];
  wtP[(size_t)c * 192 + k] = f2bf(v);
}

__global__ __launch_bounds__(256) void k_prepX(const float* __restrict__ x, u16* __restrict__ xb) {
  int i = blockIdx.x * 256 + threadIdx.x;
  if (i < NN * 128 / 4) {
    float4 v = ((const float4*)x)[i];
    uint2 o;
    o.x = packbf(v.x, v.y);
    o.y = packbf(v.z, v.w);
    ((uint2*)xb)[i] = o;
  }
}

// nei_features f32 -> bf16 (19.2M elems)
__global__ __launch_bounds__(256) void k_prepN(const float* __restrict__ x, u16* __restrict__ xbN) {
  int i = blockIdx.x * 256 + threadIdx.x;
  if (i < NN * 10 * 64 / 4) {
    float4 v = ((const float4*)x)[i];
    uint2 o;
    o.x = packbf(v.x, v.y);
    o.y = packbf(v.z, v.w);
    ((uint2*)xbN)[i] = o;
  }
}

// mha in_w [64,192] -> wtN [192][64] bf16 (transposed)
__global__ __launch_bounds__(64) void k_prepM(const float* __restrict__ in_w, u16* __restrict__ wtN) {
  int c = blockIdx.x, k = threadIdx.x;
  wtN[(size_t)c * 64 + k] = f2bf(in_w[(size_t)k * 192 + c]);
}

// ---------------------------------------------------------------------------
// k_mha3: fully register-resident per-node MHA. One wave per node.
// QKV projections via MFMA (Q^T,K^T transposed GEMM; V normal), scores and PV
// via K=16 MFMA chaining D-frags directly. Zero LDS, zero barriers.
// ---------------------------------------------------------------------------
__global__ __launch_bounds__(256) void k_mha3(
    const u16* __restrict__ xbN, const u16* __restrict__ wtN,
    const float* __restrict__ in_b, u16* __restrict__ mob) {
  int t = threadIdx.x, w = t >> 6, l = t & 63;
  int g = l >> 4, lr = l & 15;
  int n = blockIdx.x * 4 + w;
  int seq = lr < 10 ? lr : 9;
  const u16* xp = xbN + ((size_t)n * 10 + seq) * 64;
  short8 a0 = *(const short8*)(xp + g * 8);
  short8 a1 = *(const short8*)(xp + 32 + g * 8);
  int j0 = g * 4;
  const floatx4 zf = {0.f, 0.f, 0.f, 0.f};
#pragma unroll
  for (int h = 0; h < 4; ++h) {
    const short8* wqp = (const short8*)(wtN + (size_t)(h * 16 + lr) * 64);
    const short8* wkp = (const short8*)(wtN + (size_t)((4 + h) * 16 + lr) * 64);
    const short8* wvp = (const short8*)(wtN + (size_t)((8 + h) * 16 + lr) * 64);
    floatx4 aq = zf, ak = zf, av = zf;
    aq = MFMA32(wqp[g], a0, aq, 0, 0, 0);       // Q^T tile: A=W^T frag, B=X^T frag
    aq = MFMA32(wqp[4 + g], a1, aq, 0, 0, 0);
    ak = MFMA32(wkp[g], a0, ak, 0, 0, 0);
    ak = MFMA32(wkp[4 + g], a1, ak, 0, 0, 0);
    av = MFMA32(a0, wvp[g], av, 0, 0, 0);       // V normal: A=X frag, B=W frag
    av = MFMA32(a1, wvp[4 + g], av, 0, 0, 0);
    floatx4 bq4 = *(const floatx4*)(in_b + h * 16 + j0);
    floatx4 bk4 = *(const floatx4*)(in_b + 64 + h * 16 + j0);
    float bv = in_b[128 + h * 16 + lr];
    short4v qf, kf, vf;
#pragma unroll
    for (int r = 0; r < 4; ++r) {
      qf[r] = (short)f2bf((aq[r] + bq4[r]) * 0.25f);
      kf[r] = (short)f2bf(ak[r] + bk4[r]);
      vf[r] = (short)f2bf(av[r] + bv);
    }
    // scores: S^T[j=g*4+r][i=lr]
    floatx4 s4 = MFMA16(kf, qf, zf);
    float e0 = (j0 + 0 < 10) ? __expf(s4[0]) : 0.f;
    float e1 = (j0 + 1 < 10) ? __expf(s4[1]) : 0.f;
    float e2 = (j0 + 2 < 10) ? __expf(s4[2]) : 0.f;
    float e3 = (j0 + 3 < 10) ? __expf(s4[3]) : 0.f;
    float den = e0 + e1 + e2 + e3;
    den += __shfl_xor(den, 16, 64);
    den += __shfl_xor(den, 32, 64);
    float rden = 1.f / den;
    short4v pf;
    pf[0] = (short)f2bf(e0 * rden);
    pf[1] = (short)f2bf(e1 * rden);
    pf[2] = (short)f2bf(e2 * rden);
    pf[3] = (short)f2bf(e3 * rden);
    // PV: O[i=g*4+r][d=lr]
    floatx4 o4 = MFMA16(pf, vf, zf);
    float om = 0.f;
    if (j0 + 0 < 10) om += o4[0];
    if (j0 + 1 < 10) om += o4[1];
    if (j0 + 2 < 10) om += o4[2];
    if (j0 + 3 < 10) om += o4[3];
    om += __shfl_xor(om, 16, 64);
    om += __shfl_xor(om, 32, 64);
    if (g == 0) mob[(size_t)n * 64 + h * 16 + lr] = f2bf(om * 0.1f);
  }
}

// ---------------------------------------------------------------------------
// k_proj3: h_bf = bf16( x@w_in + mean_o@fusedW + fusedB ), MFMA, K=192.
// ---------------------------------------------------------------------------
__global__ __launch_bounds__(256) void k_proj3(
    const u16* __restrict__ xb, const u16* __restrict__ mob,
    const u16* __restrict__ wtP, const float* __restrict__ fusedB,
    u16* __restrict__ hb) {
  int t = threadIdx.x, w = t >> 6, l = t & 63, lr = l & 15, lq = l >> 4;
  int row0 = blockIdx.x * 64 + w * 16;
  int arow = row0 + lr; if (arow >= NN) arow = NN - 1;
  const short8* ap = (const short8*)(xb + (size_t)arow * 128);
  const short8* mp = (const short8*)(mob + (size_t)arow * 64);
  short8 a0 = ap[lq], a1 = ap[4 + lq], a2 = ap[8 + lq], a3 = ap[12 + lq];
  short8 a4 = mp[lq], a5 = mp[4 + lq];
  const short8* wt8 = (const short8*)wtP;
  floatx4 acc[8];
#pragma unroll
  for (int ct = 0; ct < 8; ++ct) acc[ct] = (floatx4){0.f, 0.f, 0.f, 0.f};
#pragma unroll
  for (int ct = 0; ct < 8; ++ct) {
    const short8* bp = wt8 + (size_t)(ct * 16 + lr) * 24;
    acc[ct] = MFMA32(a0, bp[lq], acc[ct], 0, 0, 0);
    acc[ct] = MFMA32(a1, bp[4 + lq], acc[ct], 0, 0, 0);
    acc[ct] = MFMA32(a2, bp[8 + lq], acc[ct], 0, 0, 0);
    acc[ct] = MFMA32(a3, bp[12 + lq], acc[ct], 0, 0, 0);
    acc[ct] = MFMA32(a4, bp[16 + lq], acc[ct], 0, 0, 0);
    acc[ct] = MFMA32(a5, bp[20 + lq], acc[ct], 0, 0, 0);
  }
#pragma unroll
  for (int ct = 0; ct < 8; ++ct) {
    int col = ct * 16 + lr;
    float bias = fusedB[col];
#pragma unroll
    for (int r = 0; r < 4; ++r) {
      int row = row0 + lq * 4 + r;
      if (row < NN) hb[(size_t)row * 128 + col] = f2bf(acc[ct][r] + bias);
    }
  }
}

// ---------------------------------------------------------------------------
// k_qkv4: q,k,v = h_bf @ {wq,wk,wv} + b, MFMA; output in PAIRED u32 layout:
// word[row][c] = (bf16 col c, bf16 col c+64), c in 0..63.
// ---------------------------------------------------------------------------
__global__ __launch_bounds__(256) void k_qkv4(
    const u16* __restrict__ hb, const u16* __restrict__ wt3l,
    const float* __restrict__ bqL, const float* __restrict__ bkL,
    const float* __restrict__ bvL,
    unsigned* __restrict__ q2, unsigned* __restrict__ k2, unsigned* __restrict__ v2) {
  int t = threadIdx.x, w = t >> 6, l = t & 63, lr = l & 15, lq = l >> 4;
  int row0 = blockIdx.x * 64 + w * 16;
  int arow = row0 + lr; if (arow >= NN) arow = NN - 1;
  const short8* ap = (const short8*)(hb + (size_t)arow * 128);
  short8 a0 = ap[lq], a1 = ap[4 + lq], a2 = ap[8 + lq], a3 = ap[12 + lq];
  const short8* wt8 = (const short8*)wt3l;
  floatx4 acc[24];
#pragma unroll
  for (int ct = 0; ct < 24; ++ct) acc[ct] = (floatx4){0.f, 0.f, 0.f, 0.f};
#pragma unroll
  for (int ct = 0; ct < 24; ++ct) {
    const short8* bp = wt8 + (size_t)((ct >> 3) * 128 + (ct & 7) * 16 + lr) * 16;
    acc[ct] = MFMA32(a0, bp[lq], acc[ct], 0, 0, 0);
    acc[ct] = MFMA32(a1, bp[4 + lq], acc[ct], 0, 0, 0);
    acc[ct] = MFMA32(a2, bp[8 + lq], acc[ct], 0, 0, 0);
    acc[ct] = MFMA32(a3, bp[12 + lq], acc[ct], 0, 0, 0);
  }
#pragma unroll
  for (int o = 0; o < 3; ++o) {
    unsigned* op = o == 0 ? q2 : (o == 1 ? k2 : v2);
    const float* bp2 = o == 0 ? bqL : (o == 1 ? bkL : bvL);
#pragma unroll
    for (int cc = 0; cc < 4; ++cc) {
      int col = cc * 16 + lr;
      float blo = bp2[col], bhi = bp2[64 + col];
      floatx4 alo = acc[o * 8 + cc], ahi = acc[o * 8 + cc + 4];
#pragma unroll
      for (int r = 0; r < 4; ++r) {
        int row = row0 + lq * 4 + r;
        if (row < NN)
          op[(size_t)row * 64 + col] = packbf(alo[r] + blo, ahi[r] + bhi);
      }
    }
  }
}

// ---------------------------------------------------------------------------
// k_fill: bucketed adjacency, both layers. esrc[(l*NN+d)*64 + slot] = src.
// ---------------------------------------------------------------------------
__global__ __launch_bounds__(256) void k_fill(const int* __restrict__ ei,
                                              int* __restrict__ cnt,
                                              int* __restrict__ esrc) {
  int gthr = blockIdx.x * 256 + threadIdx.x;
  if (gthr < 2 * EE) {
    int l = gthr >= EE;
    int e = gthr - l * EE;
    int s = ei[(size_t)(2 * l) * EE + e];
    int d = ei[(size_t)(2 * l + 1) * EE + e];
    int c = atomicAdd(&cnt[l * NN + d], 1);
    if (c < 64) esrc[((size_t)l * NN + d) * 64 + c] = s;
  }
}

// ---------------------------------------------------------------------------
// k_sagg4: fused edge-score + online segment-softmax + PV + ReLU + LayerNorm.
// Wave per node; lanes = 4 edge-subgroups x 16 dim-chunks. Paired u32 q/k/v.
// ---------------------------------------------------------------------------
__global__ __launch_bounds__(256) void k_sagg4(
    const unsigned* __restrict__ q2, const unsigned* __restrict__ k2,
    const unsigned* __restrict__ v2, const int* __restrict__ esrc,
    const int* __restrict__ cnt, const float* __restrict__ g,
    const float* __restrict__ bb, u16* __restrict__ hb) {
  int t = threadIdx.x, w = t >> 6, l = t & 63;
  int e = l >> 4, dd = l & 15;
  int n = blockIdx.x * 4 + w;
  int deg = cnt[n]; if (deg > 64) deg = 64;
  const int* sp = esrc + (size_t)n * 64;
  uint4 qp = *(const uint4*)(q2 + (size_t)n * 64 + dd * 4);
  float ql0 = bflo(qp.x), ql1 = bflo(qp.y), ql2 = bflo(qp.z), ql3 = bflo(qp.w);
  float qh0 = bfhi(qp.x), qh1 = bfhi(qp.y), qh2 = bfhi(qp.z), qh3 = bfhi(qp.w);
  float m0 = -1e30f, m1 = -1e30f, d0 = 0.f, d1 = 0.f;
  float al0 = 0.f, al1 = 0.f, al2 = 0.f, al3 = 0.f;
  float ah0 = 0.f, ah1 = 0.f, ah2 = 0.f, ah3 = 0.f;
  uint4 kp_c, vp_c;
  bool v_c = false;
  if (deg > 0) {
    int ii = (e < deg) ? e : deg - 1;
    v_c = e < deg;
    int s = sp[ii];
    kp_c = *(const uint4*)(k2 + (size_t)s * 64 + dd * 4);
    vp_c = *(const uint4*)(v2 + (size_t)s * 64 + dd * 4);
  }
  for (int base = 0; base < deg; base += 4) {
    uint4 kp_n, vp_n;
    bool v_n = false;
    int nb = base + 4;
    if (nb < deg) {
      int idx = nb + e;
      int ii = (idx < deg) ? idx : deg - 1;
      v_n = idx < deg;
      int s = sp[ii];
      kp_n = *(const uint4*)(k2 + (size_t)s * 64 + dd * 4);
      vp_n = *(const uint4*)(v2 + (size_t)s * 64 + dd * 4);
    }
    float r0 = ql0 * bflo(kp_c.x) + ql1 * bflo(kp_c.y) + ql2 * bflo(kp_c.z) + ql3 * bflo(kp_c.w);
    float r1 = qh0 * bfhi(kp_c.x) + qh1 * bfhi(kp_c.y) + qh2 * bfhi(kp_c.z) + qh3 * bfhi(kp_c.w);
    r0 += __shfl_xor(r0, 1, 64); r0 += __shfl_xor(r0, 2, 64); r0 += __shfl_xor(r0, 4, 64);
    r1 += __shfl_xor(r1, 1, 64); r1 += __shfl_xor(r1, 2, 64); r1 += __shfl_xor(r1, 4, 64);
    float sc0 = v_c ? r0 * 0.17677669529663687f : -__builtin_inff();
    float sc1 = v_c ? r1 * 0.17677669529663687f : -__builtin_inff();
    if (sc0 > m0) {
      float f = __expf(m0 - sc0);
      d0 *= f; al0 *= f; al1 *= f; al2 *= f; al3 *= f; m0 = sc0;
    }
    if (sc1 > m1) {
      float f = __expf(m1 - sc1);
      d1 *= f; ah0 *= f; ah1 *= f; ah2 *= f; ah3 *= f; m1 = sc1;
    }
    float p0 = __expf(sc0 - m0), p1 = __expf(sc1 - m1);
    d0 += p0; d1 += p1;
    al0 = fmaf(p0, bflo(vp_c.x), al0); al1 = fmaf(p0, bflo(vp_c.y), al1);
    al2 = fmaf(p0, bflo(vp_c.z), al2); al3 = fmaf(p0, bflo(vp_c.w), al3);
    ah0 = fmaf(p1, bfhi(vp_c.x), ah0); ah1 = fmaf(p1, bfhi(vp_c.y), ah1);
    ah2 = fmaf(p1, bfhi(vp_c.z), ah2); ah3 = fmaf(p1, bfhi(vp_c.w), ah3);
    kp_c = kp_n; vp_c = vp_n; v_c = v_n;
  }
  // merge the 4 edge-subgroups (lanes differing in bits 4,5)
  float M0 = fmaxf(m0, __shfl_xor(m0, 16, 64)); M0 = fmaxf(M0, __shfl_xor(M0, 32, 64));
  float M1 = fmaxf(m1, __shfl_xor(m1, 16, 64)); M1 = fmaxf(M1, __shfl_xor(M1, 32, 64));
  float f0 = __expf(m0 - M0), f1 = __expf(m1 - M1);
  d0 *= f0; d1 *= f1;
  al0 *= f0; al1 *= f0; al2 *= f0; al3 *= f0;
  ah0 *= f1; ah1 *= f1; ah2 *= f1; ah3 *= f1;
  d0 += __shfl_xor(d0, 16, 64); d0 += __shfl_xor(d0, 32, 64);
  d1 += __shfl_xor(d1, 16, 64); d1 += __shfl_xor(d1, 32, 64);
  al0 += __shfl_xor(al0, 16, 64); al0 += __shfl_xor(al0, 32, 64);
  al1 += __shfl_xor(al1, 16, 64); al1 += __shfl_xor(al1, 32, 64);
  al2 += __shfl_xor(al2, 16, 64); al2 += __shfl_xor(al2, 32, 64);
  al3 += __shfl_xor(al3, 16, 64); al3 += __shfl_xor(al3, 32, 64);
  ah0 += __shfl_xor(ah0, 16, 64); ah0 += __shfl_xor(ah0, 32, 64);
  ah1 += __shfl_xor(ah1, 16, 64); ah1 += __shfl_xor(ah1, 32, 64);
  ah2 += __shfl_xor(ah2, 16, 64); ah2 += __shfl_xor(ah2, 32, 64);
  ah3 += __shfl_xor(ah3, 16, 64); ah3 += __shfl_xor(ah3, 32, 64);
  float rd0 = 1.f / fmaxf(d0, 1e-9f), rd1 = 1.f / fmaxf(d1, 1e-9f);
  float ol0 = fmaxf(al0 * rd0, 0.f), ol1 = fmaxf(al1 * rd0, 0.f);
  float ol2 = fmaxf(al2 * rd0, 0.f), ol3 = fmaxf(al3 * rd0, 0.f);
  float oh0 = fmaxf(ah0 * rd1, 0.f), oh1 = fmaxf(ah1 * rd1, 0.f);
  float oh2 = fmaxf(ah2 * rd1, 0.f), oh3 = fmaxf(ah3 * rd1, 0.f);
  float s1 = ol0 + ol1 + ol2 + ol3 + oh0 + oh1 + oh2 + oh3;
  float s2 = ol0 * ol0 + ol1 * ol1 + ol2 * ol2 + ol3 * ol3 +
             oh0 * oh0 + oh1 * oh1 + oh2 * oh2 + oh3 * oh3;
  s1 += __shfl_xor(s1, 1, 64); s1 += __shfl_xor(s1, 2, 64);
  s1 += __shfl_xor(s1, 4, 64); s1 += __shfl_xor(s1, 8, 64);
  s2 += __shfl_xor(s2, 1, 64); s2 += __shfl_xor(s2, 2, 64);
  s2 += __shfl_xor(s2, 4, 64); s2 += __shfl_xor(s2, 8, 64);
  float mean = s1 * (1.f / 128.f);
  float var = s2 * (1.f / 128.f) - mean * mean;
  float rs = rsqrtf(var + 1e-5f);
  if (e == 0) {
    floatx4 gl = *(const floatx4*)(g + dd * 4);
    floatx4 bl = *(const floatx4*)(bb + dd * 4);
    floatx4 gh = *(const floatx4*)(g + 64 + dd * 4);
    floatx4 bh = *(const floatx4*)(bb + 64 + dd * 4);
    uint2 w0, w1;
    w0.x = packbf((ol0 - mean) * rs * gl[0] + bl[0], (ol1 - mean) * rs * gl[1] + bl[1]);
    w0.y = packbf((ol2 - mean) * rs * gl[2] + bl[2], (ol3 - mean) * rs * gl[3] + bl[3]);
    w1.x = packbf((oh0 - mean) * rs * gh[0] + bh[0], (oh1 - mean) * rs * gh[1] + bh[1]);
    w1.y = packbf((oh2 - mean) * rs * gh[2] + bh[2], (oh3 - mean) * rs * gh[3] + bh[3]);
    *(uint2*)(hb + (size_t)n * 128 + dd * 4) = w0;
    *(uint2*)(hb + (size_t)n * 128 + 64 + dd * 4) = w1;
  }
}

// ---------------------------------------------------------------------------
__global__ __launch_bounds__(256) void k_out(
    const u16* __restrict__ hb, const float* __restrict__ w_out,
    const float* __restrict__ b_out, float* __restrict__ out) {
  int t = threadIdx.x, w = t >> 6, lane = t & 63;
  int n = blockIdx.x * 4 + w;
  float h0 = bf2f(hb[(size_t)n * 128 + lane]);
  float h1 = bf2f(hb[(size_t)n * 128 + 64 + lane]);
  float p0 = h0 * w_out[lane * 2] + h1 * w_out[(lane + 64) * 2];
  float p1 = h0 * w_out[lane * 2 + 1] + h1 * w_out[(lane + 64) * 2 + 1];
#pragma unroll
  for (int off = 1; off < 64; off <<= 1) {
    p0 += __shfl_xor(p0, off, 64);
    p1 += __shfl_xor(p1, off, 64);
  }
  if (lane == 0) {
    out[n * 2] = p0 + b_out[0];
    out[n * 2 + 1] = p1 + b_out[1];
  }
}

// ---------------------------------------------------------------------------
extern "C" void kernel_launch(void* const* d_in, const int* in_sizes, int n_in,
                              void* d_out, int out_size, void* d_ws, size_t ws_size,
                              hipStream_t stream) {
  const float* x = (const float*)d_in[0];
  const float* neif = (const float*)d_in[1];
  const int* ei = (const int*)d_in[2];
  const float* w_in = (const float*)d_in[3];
  const float* b_in = (const float*)d_in[4];
  const float* mha_in_w = (const float*)d_in[5];
  const float* mha_in_b = (const float*)d_in[6];
  const float* mha_out_w = (const float*)d_in[7];
  const float* mha_out_b = (const float*)d_in[8];
  const float* w_nei = (const float*)d_in[9];
  const float* b_nei = (const float*)d_in[10];
  const float* wq = (const float*)d_in[11];
  const float* bq = (const float*)d_in[12];
  const float* wk = (const float*)d_in[13];
  const float* bk = (const float*)d_in[14];
  const float* wv = (const float*)d_in[15];
  const float* bv = (const float*)d_in[16];
  const float* ln_g = (const float*)d_in[17];
  const float* ln_b = (const float*)d_in[18];
  const float* w_out = (const float*)d_in[19];
  const float* b_out = (const float*)d_in[20];
  float* out = (float*)d_out;

  // workspace layout (~58.1 MB). Region A (38.4MB) is time-shared:
  //   phase 1: xbN (nei bf16)   phase 2: q2,k2,v2 (paired u32) + esrc
  char* wsb = (char*)d_ws;
  u16* xbN = (u16*)wsb;                                   // 19.2M u16
  unsigned* q2 = (unsigned*)wsb;                          // NN*64 u32
  unsigned* k2 = q2 + (size_t)NN * 64;
  unsigned* v2 = k2 + (size_t)NN * 64;
  int* esrc = (int*)(v2 + (size_t)NN * 64);               // 2*NN*64 int
  size_t off = 38400000;
  u16* hb = (u16*)(wsb + off);   off += (size_t)NN * 128 * 2;     // 7.68MB
  u16* xb = (u16*)(wsb + off);   off += (size_t)NN * 128 * 2;     // 7.68MB
  u16* mob = (u16*)(wsb + off);  off += (size_t)NN * 64 * 2;      // 3.84MB
  u16* wt3 = (u16*)(wsb + off);  off += (size_t)768 * 128 * 2;
  u16* wtP = (u16*)(wsb + off);  off += (size_t)128 * 192 * 2;
  u16* wtN = (u16*)(wsb + off);  off += (size_t)192 * 64 * 2;
  float* fusedW = (float*)(wsb + off); off += 64 * 128 * 4;
  float* fusedB = (float*)(wsb + off); off += 128 * 4;
  int* cnt = (int*)(wsb + off);  off += (size_t)2 * NN * 4;

  k_fuse<<<65, 128, 0, stream>>>(mha_out_w, mha_out_b, w_nei, b_nei, b_in, fusedW, fusedB);
  k_prepW<<<768, 128, 0, stream>>>(wq, wk, wv, wt3);
  k_prepP<<<128, 192, 0, stream>>>(w_in, fusedW, wtP);
  k_prepX<<<3750, 256, 0, stream>>>(x, xb);
  k_prepN<<<18750, 256, 0, stream>>>(neif, xbN);
  k_prepM<<<192, 64, 0, stream>>>(mha_in_w, wtN);

  k_mha3<<<NN / 4, 256, 0, stream>>>(xbN, wtN, mha_in_b, mob);
  k_proj3<<<469, 256, 0, stream>>>(xb, mob, wtP, fusedB, hb);

  // adjacency buckets (region A now free of xbN readers)
  hipMemsetAsync(cnt, 0, 2 * NN * sizeof(int), stream);
  k_fill<<<3750, 256, 0, stream>>>(ei, cnt, esrc);

  for (int l = 0; l < 2; ++l) {
    k_qkv4<<<469, 256, 0, stream>>>(hb, wt3 + (size_t)l * 3 * 128 * 128,
                                    bq + l * 128, bk + l * 128, bv + l * 128,
                                    q2, k2, v2);
    k_sagg4<<<NN / 4, 256, 0, stream>>>(q2, k2, v2, esrc + (size_t)l * NN * 64,
                                        cnt + l * NN, ln_g + l * 128,
                                        ln_b + l * 128, hb);
  }

  k_out<<<NN / 4, 256, 0, stream>>>(hb, w_out, b_out, out);
}

// Round 5
// 349.459 us; speedup vs baseline: 2.9484x; 1.0463x over previous
//
#include <hip/hip_runtime.h>
#include <hip/hip_bf16.h>

#define NN 30000
#define EE 480000

typedef __attribute__((ext_vector_type(8))) short short8;
typedef __attribute__((ext_vector_type(4))) short short4v;
typedef __attribute__((ext_vector_type(4))) float floatx4;
typedef unsigned short u16;

__device__ __forceinline__ u16 f2bf(float f) {
  union { float f; unsigned u; } v; v.f = f;
  unsigned u = v.u;
  u += 0x7FFFu + ((u >> 16) & 1u);  // RNE
  return (u16)(u >> 16);
}
__device__ __forceinline__ float bf2f(u16 u) {
  union { unsigned u; float f; } v; v.u = ((unsigned)u) << 16;
  return v.f;
}
__device__ __forceinline__ float bflo(unsigned u) {
  union { unsigned x; float f; } v; v.x = u << 16; return v.f;
}
__device__ __forceinline__ float bfhi(unsigned u) {
  union { unsigned x; float f; } v; v.x = u & 0xFFFF0000u; return v.f;
}
__device__ __forceinline__ unsigned packbf(float a, float b) {
  return (unsigned)f2bf(a) | ((unsigned)f2bf(b) << 16);
}
__device__ __forceinline__ short8 pack8(float4 A, float4 B) {
  union { unsigned u[4]; short8 s; } r;
  r.u[0] = packbf(A.x, A.y);
  r.u[1] = packbf(A.z, A.w);
  r.u[2] = packbf(B.x, B.y);
  r.u[3] = packbf(B.z, B.w);
  return r.s;
}

#define MFMA32 __builtin_amdgcn_mfma_f32_16x16x32_bf16

#if __has_builtin(__builtin_amdgcn_mfma_f32_16x16x16bf16_1k)
__device__ __forceinline__ floatx4 MFMA16(short4v a, short4v b, floatx4 c) {
  return __builtin_amdgcn_mfma_f32_16x16x16bf16_1k(a, b, c, 0, 0, 0);
}
#else
__device__ __forceinline__ floatx4 MFMA16(short4v a, short4v b, floatx4 c) {
  asm volatile("v_mfma_f32_16x16x16_bf16 %0, %1, %2, %0"
               : "+v"(c) : "v"(a), "v"(b));
  return c;
}
#endif

// ---------------------------------------------------------------------------
// k_fuse: fusedW[64][128] = mha_out_w @ w_nei ; fusedB = b_in + b_nei + mha_out_b @ w_nei
// ---------------------------------------------------------------------------
__global__ __launch_bounds__(128) void k_fuse(
    const float* __restrict__ out_w, const float* __restrict__ out_b,
    const float* __restrict__ w_nei, const float* __restrict__ b_nei,
    const float* __restrict__ b_in,
    float* __restrict__ fusedW, float* __restrict__ fusedB) {
  int i = blockIdx.x, j = threadIdx.x;
  if (i < 64) {
    float a = 0.f;
    for (int kk = 0; kk < 64; ++kk) a = fmaf(out_w[i * 64 + kk], w_nei[kk * 128 + j], a);
    fusedW[i * 128 + j] = a;
  } else {
    float a = b_in[j] + b_nei[j];
    for (int kk = 0; kk < 64; ++kk) a = fmaf(out_b[kk], w_nei[kk * 128 + j], a);
    fusedB[j] = a;
  }
}

// fusedB2[c] = fusedB[c] + sum_d mha_in_b[128+d] * fusedW[d][c]   (bv @ fusedW)
__global__ __launch_bounds__(128) void k_fuseB(
    const float* __restrict__ fusedW, const float* __restrict__ fusedB,
    const float* __restrict__ in_b, float* __restrict__ fusedB2) {
  int c = threadIdx.x;
  float a = fusedB[c];
  for (int d = 0; d < 64; ++d) a = fmaf(in_b[128 + d], fusedW[d * 128 + c], a);
  fusedB2[c] = a;
}

// G[h*64+d][c] = sum_dd Wv[d][h*16+dd] * fusedW[h*16+dd][c]; Wv[d][e]=in_w[d*192+128+e]
__global__ __launch_bounds__(128) void k_prepG(
    const float* __restrict__ in_w, const float* __restrict__ fusedW,
    float* __restrict__ G) {
  int row = blockIdx.x, c = threadIdx.x;
  int h = row >> 6, d = row & 63;
  float a = 0.f;
  for (int dd = 0; dd < 16; ++dd)
    a = fmaf(in_w[d * 192 + 128 + h * 16 + dd], fusedW[(h * 16 + dd) * 128 + c], a);
  G[row * 128 + c] = a;
}

// wtP2[c][k] (k<128: w_in^T, k>=128: G^T), bf16
__global__ __launch_bounds__(384) void k_prepP2(
    const float* __restrict__ w_in, const float* __restrict__ G,
    u16* __restrict__ wtP2) {
  int c = blockIdx.x, k = threadIdx.x;
  float v = (k < 128) ? w_in[(size_t)k * 128 + c] : G[(size_t)(k - 128) * 128 + c];
  wtP2[(size_t)c * 384 + k] = f2bf(v);
}

// wtQK[c][kk] = (c<64 ? 0.25 : 1) * in_w[kk][c]  (Q cols pre-scaled by 1/sqrt(16))
__global__ __launch_bounds__(64) void k_prepQK(
    const float* __restrict__ in_w, u16* __restrict__ wtQK) {
  int c = blockIdx.x, kk = threadIdx.x;
  float s = (c < 64) ? 0.25f : 1.f;
  wtQK[(size_t)c * 64 + kk] = f2bf(s * in_w[(size_t)kk * 192 + c]);
}

__global__ __launch_bounds__(128) void k_prepW(
    const float* __restrict__ wq, const float* __restrict__ wk,
    const float* __restrict__ wv, u16* __restrict__ wt3) {
  int bx = blockIdx.x;  // (l*3+o)*128 + c
  int l = bx / 384, rem = bx % 384, o = rem >> 7, c = rem & 127, k = threadIdx.x;
  const float* w = (o == 0 ? wq : (o == 1 ? wk : wv)) + (size_t)l * 16384;
  wt3[(size_t)bx * 128 + k] = f2bf(w[(size_t)k * 128 + c]);
}

__global__ __launch_bounds__(256) void k_prepX(const float* __restrict__ x, u16* __restrict__ xb) {
  int i = blockIdx.x * 256 + threadIdx.x;
  if (i < NN * 128 / 4) {
    float4 v = ((const float4*)x)[i];
    uint2 o;
    o.x = packbf(v.x, v.y);
    o.y = packbf(v.z, v.w);
    ((uint2*)xb)[i] = o;
  }
}

// ---------------------------------------------------------------------------
// k_mha4: fused QK-GEMM (phase 1, MFMA into LDS) + per-node attention
// colsums + Y accumulation (phase 2). V is algebraically folded into k_proj4.
// 16 nodes (160 rows) per 640-thread block. LDS: qks[160][66] u32 = 42.2KB.
// ---------------------------------------------------------------------------
__global__ __launch_bounds__(640) void k_mha4(
    const float* __restrict__ xn,    // nei_features [300000,64] f32
    const u16* __restrict__ wtQK,    // [128][64] bf16
    const float* __restrict__ in_b,  // [192]
    u16* __restrict__ Yb) {          // [NN,256]
  __shared__ unsigned qks[160 * 66];
  int t = threadIdx.x, w = t >> 6, l = t & 63;
  int lr = l & 15, lq = l >> 4;
  const floatx4 zf = {0.f, 0.f, 0.f, 0.f};

  // ---- phase 1: QK = X @ wtQK (+bias) -> LDS packed (q|k<<16) ----
  {
    const float* xp = xn + (size_t)(blockIdx.x * 160 + w * 16 + lr) * 64 + lq * 8;
    float4 f0 = *(const float4*)xp;
    float4 f1 = *(const float4*)(xp + 4);
    float4 f2 = *(const float4*)(xp + 32);
    float4 f3 = *(const float4*)(xp + 36);
    short8 a0 = pack8(f0, f1), a1 = pack8(f2, f3);
    floatx4 acc[8];
#pragma unroll
    for (int ct = 0; ct < 8; ++ct) acc[ct] = zf;
#pragma unroll
    for (int ct = 0; ct < 8; ++ct) {
      const short8* bp = (const short8*)(wtQK + (size_t)(ct * 16 + lr) * 64);
      acc[ct] = MFMA32(a0, bp[lq], acc[ct], 0, 0, 0);
      acc[ct] = MFMA32(a1, bp[4 + lq], acc[ct], 0, 0, 0);
    }
#pragma unroll
    for (int ct = 0; ct < 4; ++ct) {
      float bq_ = in_b[ct * 16 + lr] * 0.25f;
      float bk_ = in_b[64 + ct * 16 + lr];
#pragma unroll
      for (int r = 0; r < 4; ++r)
        qks[(w * 16 + lq * 4 + r) * 66 + ct * 16 + lr] =
            packbf(acc[ct][r] + bq_, acc[ct + 4][r] + bk_);
    }
  }
  __syncthreads();

  // ---- phase 2: per-node scores -> softmax colsums -> Y ----
  int seqc = lr < 10 ? lr : 9;
  for (int node = w; node < 16; node += 10) {
    float af0 = 0.f, af1 = 0.f, af2 = 0.f, af3 = 0.f;
#pragma unroll
    for (int h = 0; h < 4; ++h) {
      const unsigned* rp = &qks[(node * 10 + seqc) * 66 + h * 16 + lq * 4];
      uint2 u0 = *(const uint2*)rp;
      uint2 u1 = *(const uint2*)(rp + 2);
      union { unsigned u[2]; short4v s; } qv, kv;
      qv.u[0] = (u0.x & 0xFFFFu) | (u0.y << 16);
      qv.u[1] = (u1.x & 0xFFFFu) | (u1.y << 16);
      kv.u[0] = (u0.x >> 16) | (u0.y & 0xFFFF0000u);
      kv.u[1] = (u1.x >> 16) | (u1.y & 0xFFFF0000u);
      // S^T[j=lq*4+r][i=lr]
      floatx4 s4 = MFMA16(kv.s, qv.s, zf);
      int j0 = lq * 4;
      float e0 = (j0 + 0 < 10) ? __expf(s4[0]) : 0.f;
      float e1 = (j0 + 1 < 10) ? __expf(s4[1]) : 0.f;
      float e2 = (j0 + 2 < 10) ? __expf(s4[2]) : 0.f;
      float e3 = (j0 + 3 < 10) ? __expf(s4[3]) : 0.f;
      float den = e0 + e1 + e2 + e3;
      den += __shfl_xor(den, 16, 64);
      den += __shfl_xor(den, 32, 64);
      float rden = 0.1f / den;  // fold the seq-mean 1/10 here
      float v0 = (lr < 10) ? e0 * rden : 0.f;
      float v1 = (lr < 10) ? e1 * rden : 0.f;
      float v2 = (lr < 10) ? e2 * rden : 0.f;
      float v3 = (lr < 10) ? e3 * rden : 0.f;
#pragma unroll
      for (int off = 1; off < 16; off <<= 1) {
        v0 += __shfl_xor(v0, off, 64);
        v1 += __shfl_xor(v1, off, 64);
        v2 += __shfl_xor(v2, off, 64);
        v3 += __shfl_xor(v3, off, 64);
      }
      if (lr == h) { af0 = v0; af1 = v1; af2 = v2; af3 = v3; }
    }
    union { unsigned u[2]; short4v s; } afv;
    afv.u[0] = packbf(af0, af1);
    afv.u[1] = packbf(af2, af3);
    const float* xnp = xn + (size_t)(blockIdx.x * 16 + node) * 640;
    int jc0 = lq * 4 < 10 ? lq * 4 : 9;
    int jc1 = lq * 4 + 1 < 10 ? lq * 4 + 1 : 9;
    int jc2 = lq * 4 + 2 < 10 ? lq * 4 + 2 : 9;
    int jc3 = lq * 4 + 3 < 10 ? lq * 4 + 3 : 9;
#pragma unroll
    for (int ct = 0; ct < 4; ++ct) {
      union { unsigned u[2]; short4v s; } bx;
      bx.u[0] = packbf(xnp[jc0 * 64 + ct * 16 + lr], xnp[jc1 * 64 + ct * 16 + lr]);
      bx.u[1] = packbf(xnp[jc2 * 64 + ct * 16 + lr], xnp[jc3 * 64 + ct * 16 + lr]);
      // Y[h=row][d=ct*16+lr]
      floatx4 y4 = MFMA16(afv.s, bx.s, zf);
      if (lq == 0) {
        size_t yb = (size_t)(blockIdx.x * 16 + node) * 256;
#pragma unroll
        for (int r = 0; r < 4; ++r)
          Yb[yb + r * 64 + ct * 16 + lr] = f2bf(y4[r]);
      }
    }
  }
}

// ---------------------------------------------------------------------------
// k_proj4: h_bf = bf16( [xb | Y] @ wtP2 + fusedB2 ), MFMA, K=384.
// ---------------------------------------------------------------------------
__global__ __launch_bounds__(256) void k_proj4(
    const u16* __restrict__ xb, const u16* __restrict__ Yb,
    const u16* __restrict__ wtP2, const float* __restrict__ fusedB2,
    u16* __restrict__ hb) {
  int t = threadIdx.x, w = t >> 6, l = t & 63, lr = l & 15, lq = l >> 4;
  int row0 = blockIdx.x * 64 + w * 16;
  int arow = row0 + lr; if (arow >= NN) arow = NN - 1;
  const short8* ap = (const short8*)(xb + (size_t)arow * 128);
  const short8* yp = (const short8*)(Yb + (size_t)arow * 256);
  short8 afr[12];
#pragma unroll
  for (int kb = 0; kb < 4; ++kb) afr[kb] = ap[kb * 4 + lq];
#pragma unroll
  for (int m = 0; m < 8; ++m) afr[4 + m] = yp[m * 4 + lq];
  floatx4 acc[8];
#pragma unroll
  for (int ct = 0; ct < 8; ++ct) acc[ct] = (floatx4){0.f, 0.f, 0.f, 0.f};
#pragma unroll
  for (int ct = 0; ct < 8; ++ct) {
    const short8* bp = (const short8*)(wtP2 + (size_t)(ct * 16 + lr) * 384);
#pragma unroll
    for (int kb = 0; kb < 12; ++kb)
      acc[ct] = MFMA32(afr[kb], bp[kb * 4 + lq], acc[ct], 0, 0, 0);
  }
#pragma unroll
  for (int ct = 0; ct < 8; ++ct) {
    int col = ct * 16 + lr;
    float bias = fusedB2[col];
#pragma unroll
    for (int r = 0; r < 4; ++r) {
      int row = row0 + lq * 4 + r;
      if (row < NN) hb[(size_t)row * 128 + col] = f2bf(acc[ct][r] + bias);
    }
  }
}

// ---------------------------------------------------------------------------
// k_qkv4: q,k,v = h_bf @ {wq,wk,wv} + b, MFMA; PAIRED u32 output layout.
// ---------------------------------------------------------------------------
__global__ __launch_bounds__(256) void k_qkv4(
    const u16* __restrict__ hb, const u16* __restrict__ wt3l,
    const float* __restrict__ bqL, const float* __restrict__ bkL,
    const float* __restrict__ bvL,
    unsigned* __restrict__ q2, unsigned* __restrict__ k2, unsigned* __restrict__ v2) {
  int t = threadIdx.x, w = t >> 6, l = t & 63, lr = l & 15, lq = l >> 4;
  int row0 = blockIdx.x * 64 + w * 16;
  int arow = row0 + lr; if (arow >= NN) arow = NN - 1;
  const short8* ap = (const short8*)(hb + (size_t)arow * 128);
  short8 a0 = ap[lq], a1 = ap[4 + lq], a2 = ap[8 + lq], a3 = ap[12 + lq];
  const short8* wt8 = (const short8*)wt3l;
  floatx4 acc[24];
#pragma unroll
  for (int ct = 0; ct < 24; ++ct) acc[ct] = (floatx4){0.f, 0.f, 0.f, 0.f};
#pragma unroll
  for (int ct = 0; ct < 24; ++ct) {
    const short8* bp = wt8 + (size_t)((ct >> 3) * 128 + (ct & 7) * 16 + lr) * 16;
    acc[ct] = MFMA32(a0, bp[lq], acc[ct], 0, 0, 0);
    acc[ct] = MFMA32(a1, bp[4 + lq], acc[ct], 0, 0, 0);
    acc[ct] = MFMA32(a2, bp[8 + lq], acc[ct], 0, 0, 0);
    acc[ct] = MFMA32(a3, bp[12 + lq], acc[ct], 0, 0, 0);
  }
#pragma unroll
  for (int o = 0; o < 3; ++o) {
    unsigned* op = o == 0 ? q2 : (o == 1 ? k2 : v2);
    const float* bp2 = o == 0 ? bqL : (o == 1 ? bkL : bvL);
#pragma unroll
    for (int cc = 0; cc < 4; ++cc) {
      int col = cc * 16 + lr;
      float blo = bp2[col], bhi = bp2[64 + col];
      floatx4 alo = acc[o * 8 + cc], ahi = acc[o * 8 + cc + 4];
#pragma unroll
      for (int r = 0; r < 4; ++r) {
        int row = row0 + lq * 4 + r;
        if (row < NN)
          op[(size_t)row * 64 + col] = packbf(alo[r] + blo, ahi[r] + bhi);
      }
    }
  }
}

// ---------------------------------------------------------------------------
// k_fill: bucketed adjacency, both layers. esrc[(l*NN+d)*64 + slot] = src.
// ---------------------------------------------------------------------------
__global__ __launch_bounds__(256) void k_fill(const int* __restrict__ ei,
                                              int* __restrict__ cnt,
                                              int* __restrict__ esrc) {
  int gthr = blockIdx.x * 256 + threadIdx.x;
  if (gthr < 2 * EE) {
    int l = gthr >= EE;
    int e = gthr - l * EE;
    int s = ei[(size_t)(2 * l) * EE + e];
    int d = ei[(size_t)(2 * l + 1) * EE + e];
    int c = atomicAdd(&cnt[l * NN + d], 1);
    if (c < 64) esrc[((size_t)l * NN + d) * 64 + c] = s;
  }
}

// ---------------------------------------------------------------------------
// k_sagg4: fused edge-score + online segment-softmax + PV + ReLU + LayerNorm.
// ---------------------------------------------------------------------------
__global__ __launch_bounds__(256) void k_sagg4(
    const unsigned* __restrict__ q2, const unsigned* __restrict__ k2,
    const unsigned* __restrict__ v2, const int* __restrict__ esrc,
    const int* __restrict__ cnt, const float* __restrict__ g,
    const float* __restrict__ bb, u16* __restrict__ hb) {
  int t = threadIdx.x, w = t >> 6, l = t & 63;
  int e = l >> 4, dd = l & 15;
  int n = blockIdx.x * 4 + w;
  int deg = cnt[n]; if (deg > 64) deg = 64;
  const int* sp = esrc + (size_t)n * 64;
  uint4 qp = *(const uint4*)(q2 + (size_t)n * 64 + dd * 4);
  float ql0 = bflo(qp.x), ql1 = bflo(qp.y), ql2 = bflo(qp.z), ql3 = bflo(qp.w);
  float qh0 = bfhi(qp.x), qh1 = bfhi(qp.y), qh2 = bfhi(qp.z), qh3 = bfhi(qp.w);
  float m0 = -1e30f, m1 = -1e30f, d0 = 0.f, d1 = 0.f;
  float al0 = 0.f, al1 = 0.f, al2 = 0.f, al3 = 0.f;
  float ah0 = 0.f, ah1 = 0.f, ah2 = 0.f, ah3 = 0.f;
  uint4 kp_c, vp_c;
  bool v_c = false;
  if (deg > 0) {
    int ii = (e < deg) ? e : deg - 1;
    v_c = e < deg;
    int s = sp[ii];
    kp_c = *(const uint4*)(k2 + (size_t)s * 64 + dd * 4);
    vp_c = *(const uint4*)(v2 + (size_t)s * 64 + dd * 4);
  }
  for (int base = 0; base < deg; base += 4) {
    uint4 kp_n, vp_n;
    bool v_n = false;
    int nb = base + 4;
    if (nb < deg) {
      int idx = nb + e;
      int ii = (idx < deg) ? idx : deg - 1;
      v_n = idx < deg;
      int s = sp[ii];
      kp_n = *(const uint4*)(k2 + (size_t)s * 64 + dd * 4);
      vp_n = *(const uint4*)(v2 + (size_t)s * 64 + dd * 4);
    }
    float r0 = ql0 * bflo(kp_c.x) + ql1 * bflo(kp_c.y) + ql2 * bflo(kp_c.z) + ql3 * bflo(kp_c.w);
    float r1 = qh0 * bfhi(kp_c.x) + qh1 * bfhi(kp_c.y) + qh2 * bfhi(kp_c.z) + qh3 * bfhi(kp_c.w);
    r0 += __shfl_xor(r0, 1, 64); r0 += __shfl_xor(r0, 2, 64); r0 += __shfl_xor(r0, 4, 64);
    r1 += __shfl_xor(r1, 1, 64); r1 += __shfl_xor(r1, 2, 64); r1 += __shfl_xor(r1, 4, 64);
    float sc0 = v_c ? r0 * 0.17677669529663687f : -__builtin_inff();
    float sc1 = v_c ? r1 * 0.17677669529663687f : -__builtin_inff();
    if (sc0 > m0) { float f = __expf(m0 - sc0); d0 *= f; al0 *= f; al1 *= f; al2 *= f; al3 *= f; m0 = sc0; }
    if (sc1 > m1) { float f = __expf(m1 - sc1); d1 *= f; ah0 *= f; ah1 *= f; ah2 *= f; ah3 *= f; m1 = sc1; }
    float p0 = __expf(sc0 - m0), p1 = __expf(sc1 - m1);
    d0 += p0; d1 += p1;
    al0 = fmaf(p0, bflo(vp_c.x), al0); al1 = fmaf(p0, bflo(vp_c.y), al1);
    al2 = fmaf(p0, bflo(vp_c.z), al2); al3 = fmaf(p0, bflo(vp_c.w), al3);
    ah0 = fmaf(p1, bfhi(vp_c.x), ah0); ah1 = fmaf(p1, bfhi(vp_c.y), ah1);
    ah2 = fmaf(p1, bfhi(vp_c.z), ah2); ah3 = fmaf(p1, bfhi(vp_c.w), ah3);
    kp_c = kp_n; vp_c = vp_n; v_c = v_n;
  }
  float M0 = fmaxf(m0, __shfl_xor(m0, 16, 64)); M0 = fmaxf(M0, __shfl_xor(M0, 32, 64));
  float M1 = fmaxf(m1, __shfl_xor(m1, 16, 64)); M1 = fmaxf(M1, __shfl_xor(M1, 32, 64));
  float f0 = __expf(m0 - M0), f1 = __expf(m1 - M1);
  d0 *= f0; d1 *= f1;
  al0 *= f0; al1 *= f0; al2 *= f0; al3 *= f0;
  ah0 *= f1; ah1 *= f1; ah2 *= f1; ah3 *= f1;
  d0 += __shfl_xor(d0, 16, 64); d0 += __shfl_xor(d0, 32, 64);
  d1 += __shfl_xor(d1, 16, 64); d1 += __shfl_xor(d1, 32, 64);
  al0 += __shfl_xor(al0, 16, 64); al0 += __shfl_xor(al0, 32, 64);
  al1 += __shfl_xor(al1, 16, 64); al1 += __shfl_xor(al1, 32, 64);
  al2 += __shfl_xor(al2, 16, 64); al2 += __shfl_xor(al2, 32, 64);
  al3 += __shfl_xor(al3, 16, 64); al3 += __shfl_xor(al3, 32, 64);
  ah0 += __shfl_xor(ah0, 16, 64); ah0 += __shfl_xor(ah0, 32, 64);
  ah1 += __shfl_xor(ah1, 16, 64); ah1 += __shfl_xor(ah1, 32, 64);
  ah2 += __shfl_xor(ah2, 16, 64); ah2 += __shfl_xor(ah2, 32, 64);
  ah3 += __shfl_xor(ah3, 16, 64); ah3 += __shfl_xor(ah3, 32, 64);
  float rd0 = 1.f / fmaxf(d0, 1e-9f), rd1 = 1.f / fmaxf(d1, 1e-9f);
  float ol0 = fmaxf(al0 * rd0, 0.f), ol1 = fmaxf(al1 * rd0, 0.f);
  float ol2 = fmaxf(al2 * rd0, 0.f), ol3 = fmaxf(al3 * rd0, 0.f);
  float oh0 = fmaxf(ah0 * rd1, 0.f), oh1 = fmaxf(ah1 * rd1, 0.f);
  float oh2 = fmaxf(ah2 * rd1, 0.f), oh3 = fmaxf(ah3 * rd1, 0.f);
  float s1 = ol0 + ol1 + ol2 + ol3 + oh0 + oh1 + oh2 + oh3;
  float s2 = ol0 * ol0 + ol1 * ol1 + ol2 * ol2 + ol3 * ol3 +
             oh0 * oh0 + oh1 * oh1 + oh2 * oh2 + oh3 * oh3;
  s1 += __shfl_xor(s1, 1, 64); s1 += __shfl_xor(s1, 2, 64);
  s1 += __shfl_xor(s1, 4, 64); s1 += __shfl_xor(s1, 8, 64);
  s2 += __shfl_xor(s2, 1, 64); s2 += __shfl_xor(s2, 2, 64);
  s2 += __shfl_xor(s2, 4, 64); s2 += __shfl_xor(s2, 8, 64);
  float mean = s1 * (1.f / 128.f);
  float var = s2 * (1.f / 128.f) - mean * mean;
  float rs = rsqrtf(var + 1e-5f);
  if (e == 0) {
    floatx4 gl = *(const floatx4*)(g + dd * 4);
    floatx4 bl = *(const floatx4*)(bb + dd * 4);
    floatx4 gh = *(const floatx4*)(g + 64 + dd * 4);
    floatx4 bh = *(const floatx4*)(bb + 64 + dd * 4);
    uint2 w0, w1;
    w0.x = packbf((ol0 - mean) * rs * gl[0] + bl[0], (ol1 - mean) * rs * gl[1] + bl[1]);
    w0.y = packbf((ol2 - mean) * rs * gl[2] + bl[2], (ol3 - mean) * rs * gl[3] + bl[3]);
    w1.x = packbf((oh0 - mean) * rs * gh[0] + bh[0], (oh1 - mean) * rs * gh[1] + bh[1]);
    w1.y = packbf((oh2 - mean) * rs * gh[2] + bh[2], (oh3 - mean) * rs * gh[3] + bh[3]);
    *(uint2*)(hb + (size_t)n * 128 + dd * 4) = w0;
    *(uint2*)(hb + (size_t)n * 128 + 64 + dd * 4) = w1;
  }
}

// ---------------------------------------------------------------------------
__global__ __launch_bounds__(256) void k_out(
    const u16* __restrict__ hb, const float* __restrict__ w_out,
    const float* __restrict__ b_out, float* __restrict__ out) {
  int t = threadIdx.x, w = t >> 6, lane = t & 63;
  int n = blockIdx.x * 4 + w;
  float h0 = bf2f(hb[(size_t)n * 128 + lane]);
  float h1 = bf2f(hb[(size_t)n * 128 + 64 + lane]);
  float p0 = h0 * w_out[lane * 2] + h1 * w_out[(lane + 64) * 2];
  float p1 = h0 * w_out[lane * 2 + 1] + h1 * w_out[(lane + 64) * 2 + 1];
#pragma unroll
  for (int off = 1; off < 64; off <<= 1) {
    p0 += __shfl_xor(p0, off, 64);
    p1 += __shfl_xor(p1, off, 64);
  }
  if (lane == 0) {
    out[n * 2] = p0 + b_out[0];
    out[n * 2 + 1] = p1 + b_out[1];
  }
}

// ---------------------------------------------------------------------------
extern "C" void kernel_launch(void* const* d_in, const int* in_sizes, int n_in,
                              void* d_out, int out_size, void* d_ws, size_t ws_size,
                              hipStream_t stream) {
  const float* x = (const float*)d_in[0];
  const float* neif = (const float*)d_in[1];
  const int* ei = (const int*)d_in[2];
  const float* w_in = (const float*)d_in[3];
  const float* b_in = (const float*)d_in[4];
  const float* mha_in_w = (const float*)d_in[5];
  const float* mha_in_b = (const float*)d_in[6];
  const float* mha_out_w = (const float*)d_in[7];
  const float* mha_out_b = (const float*)d_in[8];
  const float* w_nei = (const float*)d_in[9];
  const float* b_nei = (const float*)d_in[10];
  const float* wq = (const float*)d_in[11];
  const float* bq = (const float*)d_in[12];
  const float* wk = (const float*)d_in[13];
  const float* bk = (const float*)d_in[14];
  const float* wv = (const float*)d_in[15];
  const float* bv = (const float*)d_in[16];
  const float* ln_g = (const float*)d_in[17];
  const float* ln_b = (const float*)d_in[18];
  const float* w_out = (const float*)d_in[19];
  const float* b_out = (const float*)d_in[20];
  float* out = (float*)d_out;

  // workspace layout (~70 MB)
  char* wsb = (char*)d_ws;
  size_t off = 0;
  unsigned* q2 = (unsigned*)(wsb + off); off += (size_t)NN * 64 * 4;
  unsigned* k2 = (unsigned*)(wsb + off); off += (size_t)NN * 64 * 4;
  unsigned* v2 = (unsigned*)(wsb + off); off += (size_t)NN * 64 * 4;
  int* esrc = (int*)(wsb + off);         off += (size_t)2 * NN * 64 * 4;
  u16* Yb = (u16*)(wsb + off);           off += (size_t)NN * 256 * 2;
  u16* hb = (u16*)(wsb + off);           off += (size_t)NN * 128 * 2;
  u16* xb = (u16*)(wsb + off);           off += (size_t)NN * 128 * 2;
  u16* wt3 = (u16*)(wsb + off);          off += (size_t)768 * 128 * 2;
  u16* wtP2 = (u16*)(wsb + off);         off += (size_t)128 * 384 * 2;
  u16* wtQK = (u16*)(wsb + off);         off += (size_t)128 * 64 * 2;
  float* G = (float*)(wsb + off);        off += (size_t)256 * 128 * 4;
  float* fusedW = (float*)(wsb + off);   off += 64 * 128 * 4;
  float* fusedB = (float*)(wsb + off);   off += 128 * 4;
  float* fusedB2 = (float*)(wsb + off);  off += 128 * 4;
  int* cnt = (int*)(wsb + off);          off += (size_t)2 * NN * 4;

  k_fuse<<<65, 128, 0, stream>>>(mha_out_w, mha_out_b, w_nei, b_nei, b_in, fusedW, fusedB);
  k_fuseB<<<1, 128, 0, stream>>>(fusedW, fusedB, mha_in_b, fusedB2);
  k_prepG<<<256, 128, 0, stream>>>(mha_in_w, fusedW, G);
  k_prepP2<<<128, 384, 0, stream>>>(w_in, G, wtP2);
  k_prepQK<<<128, 64, 0, stream>>>(mha_in_w, wtQK);
  k_prepW<<<768, 128, 0, stream>>>(wq, wk, wv, wt3);
  k_prepX<<<3750, 256, 0, stream>>>(x, xb);

  k_mha4<<<1875, 640, 0, stream>>>(neif, wtQK, mha_in_b, Yb);
  k_proj4<<<469, 256, 0, stream>>>(xb, Yb, wtP2, fusedB2, hb);

  hipMemsetAsync(cnt, 0, 2 * NN * sizeof(int), stream);
  k_fill<<<3750, 256, 0, stream>>>(ei, cnt, esrc);

  for (int l = 0; l < 2; ++l) {
    k_qkv4<<<469, 256, 0, stream>>>(hb, wt3 + (size_t)l * 3 * 128 * 128,
                                    bq + l * 128, bk + l * 128, bv + l * 128,
                                    q2, k2, v2);
    k_sagg4<<<NN / 4, 256, 0, stream>>>(q2, k2, v2, esrc + (size_t)l * NN * 64,
                                        cnt + l * NN, ln_g + l * 128,
                                        ln_b + l * 128, hb);
  }

  k_out<<<NN / 4, 256, 0, stream>>>(hb, w_out, b_out, out);
}

// Round 6
// 337.856 us; speedup vs baseline: 3.0497x; 1.0343x over previous
//
#include <hip/hip_runtime.h>
#include <hip/hip_bf16.h>

#define NN 30000
#define EE 480000

typedef __attribute__((ext_vector_type(8))) short short8;
typedef __attribute__((ext_vector_type(4))) short short4v;
typedef __attribute__((ext_vector_type(4))) float floatx4;
typedef unsigned short u16;

__device__ __forceinline__ u16 f2bf(float f) {
  union { float f; unsigned u; } v; v.f = f;
  unsigned u = v.u;
  u += 0x7FFFu + ((u >> 16) & 1u);  // RNE
  return (u16)(u >> 16);
}
__device__ __forceinline__ float bf2f(u16 u) {
  union { unsigned u; float f; } v; v.u = ((unsigned)u) << 16;
  return v.f;
}
__device__ __forceinline__ float bflo(unsigned u) {
  union { unsigned x; float f; } v; v.x = u << 16; return v.f;
}
__device__ __forceinline__ float bfhi(unsigned u) {
  union { unsigned x; float f; } v; v.x = u & 0xFFFF0000u; return v.f;
}
__device__ __forceinline__ unsigned packbf(float a, float b) {
  return (unsigned)f2bf(a) | ((unsigned)f2bf(b) << 16);
}
__device__ __forceinline__ short8 pack8(float4 A, float4 B) {
  union { unsigned u[4]; short8 s; } r;
  r.u[0] = packbf(A.x, A.y);
  r.u[1] = packbf(A.z, A.w);
  r.u[2] = packbf(B.x, B.y);
  r.u[3] = packbf(B.z, B.w);
  return r.s;
}

#define MFMA32 __builtin_amdgcn_mfma_f32_16x16x32_bf16

#if __has_builtin(__builtin_amdgcn_mfma_f32_16x16x16bf16_1k)
__device__ __forceinline__ floatx4 MFMA16(short4v a, short4v b, floatx4 c) {
  return __builtin_amdgcn_mfma_f32_16x16x16bf16_1k(a, b, c, 0, 0, 0);
}
#else
__device__ __forceinline__ floatx4 MFMA16(short4v a, short4v b, floatx4 c) {
  asm volatile("v_mfma_f32_16x16x16_bf16 %0, %1, %2, %0"
               : "+v"(c) : "v"(a), "v"(b));
  return c;
}
#endif

// ---------------------------------------------------------------------------
// k_fuse: fusedW[64][128] = mha_out_w @ w_nei ; fusedB = b_in + b_nei + mha_out_b @ w_nei
// ---------------------------------------------------------------------------
__global__ __launch_bounds__(128) void k_fuse(
    const float* __restrict__ out_w, const float* __restrict__ out_b,
    const float* __restrict__ w_nei, const float* __restrict__ b_nei,
    const float* __restrict__ b_in,
    float* __restrict__ fusedW, float* __restrict__ fusedB) {
  int i = blockIdx.x, j = threadIdx.x;
  if (i < 64) {
    float a = 0.f;
    for (int kk = 0; kk < 64; ++kk) a = fmaf(out_w[i * 64 + kk], w_nei[kk * 128 + j], a);
    fusedW[i * 128 + j] = a;
  } else {
    float a = b_in[j] + b_nei[j];
    for (int kk = 0; kk < 64; ++kk) a = fmaf(out_b[kk], w_nei[kk * 128 + j], a);
    fusedB[j] = a;
  }
}

// fusedB2[c] = fusedB[c] + sum_d mha_in_b[128+d] * fusedW[d][c]
__global__ __launch_bounds__(128) void k_fuseB(
    const float* __restrict__ fusedW, const float* __restrict__ fusedB,
    const float* __restrict__ in_b, float* __restrict__ fusedB2) {
  int c = threadIdx.x;
  float a = fusedB[c];
  for (int d = 0; d < 64; ++d) a = fmaf(in_b[128 + d], fusedW[d * 128 + c], a);
  fusedB2[c] = a;
}

// G[h*64+d][c] = sum_dd Wv[d][h*16+dd] * fusedW[h*16+dd][c]
__global__ __launch_bounds__(128) void k_prepG(
    const float* __restrict__ in_w, const float* __restrict__ fusedW,
    float* __restrict__ G) {
  int row = blockIdx.x, c = threadIdx.x;
  int h = row >> 6, d = row & 63;
  float a = 0.f;
  for (int dd = 0; dd < 16; ++dd)
    a = fmaf(in_w[d * 192 + 128 + h * 16 + dd], fusedW[(h * 16 + dd) * 128 + c], a);
  G[row * 128 + c] = a;
}

// wtP2[c][k] (k<128: w_in^T, k>=128: G^T), bf16
__global__ __launch_bounds__(384) void k_prepP2(
    const float* __restrict__ w_in, const float* __restrict__ G,
    u16* __restrict__ wtP2) {
  int c = blockIdx.x, k = threadIdx.x;
  float v = (k < 128) ? w_in[(size_t)k * 128 + c] : G[(size_t)(k - 128) * 128 + c];
  wtP2[(size_t)c * 384 + k] = f2bf(v);
}

// wtQK[c][kk] = (c<64 ? 0.25 : 1) * in_w[kk][c]
__global__ __launch_bounds__(64) void k_prepQK(
    const float* __restrict__ in_w, u16* __restrict__ wtQK) {
  int c = blockIdx.x, kk = threadIdx.x;
  float s = (c < 64) ? 0.25f : 1.f;
  wtQK[(size_t)c * 64 + kk] = f2bf(s * in_w[(size_t)kk * 192 + c]);
}

__global__ __launch_bounds__(128) void k_prepW(
    const float* __restrict__ wq, const float* __restrict__ wk,
    const float* __restrict__ wv, u16* __restrict__ wt3) {
  int bx = blockIdx.x;  // (l*3+o)*128 + c
  int l = bx / 384, rem = bx % 384, o = rem >> 7, c = rem & 127, k = threadIdx.x;
  const float* w = (o == 0 ? wq : (o == 1 ? wk : wv)) + (size_t)l * 16384;
  wt3[(size_t)bx * 128 + k] = f2bf(w[(size_t)k * 128 + c]);
}

__global__ __launch_bounds__(256) void k_prepX(const float* __restrict__ x, u16* __restrict__ xb) {
  int i = blockIdx.x * 256 + threadIdx.x;
  if (i < NN * 128 / 4) {
    float4 v = ((const float4*)x)[i];
    uint2 o;
    o.x = packbf(v.x, v.y);
    o.y = packbf(v.z, v.w);
    ((uint2*)xb)[i] = o;
  }
}

// ---------------------------------------------------------------------------
// k_mha5: fused QK-GEMM + per-node attention colsums + Y. 10 nodes (100 rows)
// per 640-thread block; phase1 on waves 0-6 (7 row-tiles incl. padded tail),
// phase2 exactly 1 node per wave. LDS qks[112][66] u32 = 29.6KB.
// ---------------------------------------------------------------------------
__global__ __launch_bounds__(640) void k_mha5(
    const float* __restrict__ xn,    // nei_features [300000,64] f32
    const u16* __restrict__ wtQK,    // [128][64] bf16
    const float* __restrict__ in_b,  // [192]
    u16* __restrict__ Yb) {          // [NN,256]
  __shared__ unsigned qks[112 * 66];
  int t = threadIdx.x, w = t >> 6, l = t & 63;
  int lr = l & 15, lq = l >> 4;
  const floatx4 zf = {0.f, 0.f, 0.f, 0.f};
  size_t r0 = (size_t)blockIdx.x * 100;

  // ---- phase 1 (waves 0-6): QK = X @ wtQK (+bias) -> LDS packed (q|k<<16) ----
  if (w < 7) {
    size_t arow = r0 + w * 16 + lr;
    if (arow > 299999) arow = 299999;
    const float* xp = xn + arow * 64 + lq * 8;
    float4 f0 = *(const float4*)xp;
    float4 f1 = *(const float4*)(xp + 4);
    float4 f2 = *(const float4*)(xp + 32);
    float4 f3 = *(const float4*)(xp + 36);
    short8 a0 = pack8(f0, f1), a1 = pack8(f2, f3);
    floatx4 acc[8];
#pragma unroll
    for (int ct = 0; ct < 8; ++ct) acc[ct] = zf;
#pragma unroll
    for (int ct = 0; ct < 8; ++ct) {
      const short8* bp = (const short8*)(wtQK + (size_t)(ct * 16 + lr) * 64);
      acc[ct] = MFMA32(a0, bp[lq], acc[ct], 0, 0, 0);
      acc[ct] = MFMA32(a1, bp[4 + lq], acc[ct], 0, 0, 0);
    }
#pragma unroll
    for (int ct = 0; ct < 4; ++ct) {
      float bq_ = in_b[ct * 16 + lr] * 0.25f;
      float bk_ = in_b[64 + ct * 16 + lr];
#pragma unroll
      for (int r = 0; r < 4; ++r)
        qks[(w * 16 + lq * 4 + r) * 66 + ct * 16 + lr] =
            packbf(acc[ct][r] + bq_, acc[ct + 4][r] + bk_);
    }
  }
  __syncthreads();

  // ---- phase 2: one node per wave ----
  int seqc = lr < 10 ? lr : 9;
  {
    float af0 = 0.f, af1 = 0.f, af2 = 0.f, af3 = 0.f;
#pragma unroll
    for (int h = 0; h < 4; ++h) {
      const unsigned* rp = &qks[(w * 10 + seqc) * 66 + h * 16 + lq * 4];
      uint2 u0 = *(const uint2*)rp;
      uint2 u1 = *(const uint2*)(rp + 2);
      union { unsigned u[2]; short4v s; } qv, kv;
      qv.u[0] = (u0.x & 0xFFFFu) | (u0.y << 16);
      qv.u[1] = (u1.x & 0xFFFFu) | (u1.y << 16);
      kv.u[0] = (u0.x >> 16) | (u0.y & 0xFFFF0000u);
      kv.u[1] = (u1.x >> 16) | (u1.y & 0xFFFF0000u);
      // S^T[j=lq*4+r][i=lr]
      floatx4 s4 = MFMA16(kv.s, qv.s, zf);
      int j0 = lq * 4;
      float e0 = (j0 + 0 < 10) ? __expf(s4[0]) : 0.f;
      float e1 = (j0 + 1 < 10) ? __expf(s4[1]) : 0.f;
      float e2 = (j0 + 2 < 10) ? __expf(s4[2]) : 0.f;
      float e3 = (j0 + 3 < 10) ? __expf(s4[3]) : 0.f;
      float den = e0 + e1 + e2 + e3;
      den += __shfl_xor(den, 16, 64);
      den += __shfl_xor(den, 32, 64);
      float rden = 0.1f / den;  // fold the seq-mean 1/10
      float v0 = (lr < 10) ? e0 * rden : 0.f;
      float v1 = (lr < 10) ? e1 * rden : 0.f;
      float v2 = (lr < 10) ? e2 * rden : 0.f;
      float v3 = (lr < 10) ? e3 * rden : 0.f;
#pragma unroll
      for (int off = 1; off < 16; off <<= 1) {
        v0 += __shfl_xor(v0, off, 64);
        v1 += __shfl_xor(v1, off, 64);
        v2 += __shfl_xor(v2, off, 64);
        v3 += __shfl_xor(v3, off, 64);
      }
      if (lr == h) { af0 = v0; af1 = v1; af2 = v2; af3 = v3; }
    }
    union { unsigned u[2]; short4v s; } afv;
    afv.u[0] = packbf(af0, af1);
    afv.u[1] = packbf(af2, af3);
    size_t node = (size_t)blockIdx.x * 10 + w;
    const float* xnp = xn + node * 640;
    int jc0 = lq * 4 < 10 ? lq * 4 : 9;
    int jc1 = lq * 4 + 1 < 10 ? lq * 4 + 1 : 9;
    int jc2 = lq * 4 + 2 < 10 ? lq * 4 + 2 : 9;
    int jc3 = lq * 4 + 3 < 10 ? lq * 4 + 3 : 9;
#pragma unroll
    for (int ct = 0; ct < 4; ++ct) {
      union { unsigned u[2]; short4v s; } bx;
      bx.u[0] = packbf(xnp[jc0 * 64 + ct * 16 + lr], xnp[jc1 * 64 + ct * 16 + lr]);
      bx.u[1] = packbf(xnp[jc2 * 64 + ct * 16 + lr], xnp[jc3 * 64 + ct * 16 + lr]);
      // Y[h=row][d=ct*16+lr]
      floatx4 y4 = MFMA16(afv.s, bx.s, zf);
      if (lq == 0) {
        size_t yb = node * 256;
#pragma unroll
        for (int r = 0; r < 4; ++r)
          Yb[yb + r * 64 + ct * 16 + lr] = f2bf(y4[r]);
      }
    }
  }
}

// ---------------------------------------------------------------------------
// k_proj4: h_bf = bf16( [xb | Y] @ wtP2 + fusedB2 ), MFMA, K=384.
// ---------------------------------------------------------------------------
__global__ __launch_bounds__(256) void k_proj4(
    const u16* __restrict__ xb, const u16* __restrict__ Yb,
    const u16* __restrict__ wtP2, const float* __restrict__ fusedB2,
    u16* __restrict__ hb) {
  int t = threadIdx.x, w = t >> 6, l = t & 63, lr = l & 15, lq = l >> 4;
  int row0 = blockIdx.x * 64 + w * 16;
  int arow = row0 + lr; if (arow >= NN) arow = NN - 1;
  const short8* ap = (const short8*)(xb + (size_t)arow * 128);
  const short8* yp = (const short8*)(Yb + (size_t)arow * 256);
  short8 afr[12];
#pragma unroll
  for (int kb = 0; kb < 4; ++kb) afr[kb] = ap[kb * 4 + lq];
#pragma unroll
  for (int m = 0; m < 8; ++m) afr[4 + m] = yp[m * 4 + lq];
  floatx4 acc[8];
#pragma unroll
  for (int ct = 0; ct < 8; ++ct) acc[ct] = (floatx4){0.f, 0.f, 0.f, 0.f};
#pragma unroll
  for (int ct = 0; ct < 8; ++ct) {
    const short8* bp = (const short8*)(wtP2 + (size_t)(ct * 16 + lr) * 384);
#pragma unroll
    for (int kb = 0; kb < 12; ++kb)
      acc[ct] = MFMA32(afr[kb], bp[kb * 4 + lq], acc[ct], 0, 0, 0);
  }
#pragma unroll
  for (int ct = 0; ct < 8; ++ct) {
    int col = ct * 16 + lr;
    float bias = fusedB2[col];
#pragma unroll
    for (int r = 0; r < 4; ++r) {
      int row = row0 + lq * 4 + r;
      if (row < NN) hb[(size_t)row * 128 + col] = f2bf(acc[ct][r] + bias);
    }
  }
}

// ---------------------------------------------------------------------------
// k_qkv4: q,k,v = h_bf @ {wq,wk,wv} + b, MFMA; PAIRED u32 output layout.
// ---------------------------------------------------------------------------
__global__ __launch_bounds__(256) void k_qkv4(
    const u16* __restrict__ hb, const u16* __restrict__ wt3l,
    const float* __restrict__ bqL, const float* __restrict__ bkL,
    const float* __restrict__ bvL,
    unsigned* __restrict__ q2, unsigned* __restrict__ k2, unsigned* __restrict__ v2) {
  int t = threadIdx.x, w = t >> 6, l = t & 63, lr = l & 15, lq = l >> 4;
  int row0 = blockIdx.x * 64 + w * 16;
  int arow = row0 + lr; if (arow >= NN) arow = NN - 1;
  const short8* ap = (const short8*)(hb + (size_t)arow * 128);
  short8 a0 = ap[lq], a1 = ap[4 + lq], a2 = ap[8 + lq], a3 = ap[12 + lq];
  const short8* wt8 = (const short8*)wt3l;
  floatx4 acc[24];
#pragma unroll
  for (int ct = 0; ct < 24; ++ct) acc[ct] = (floatx4){0.f, 0.f, 0.f, 0.f};
#pragma unroll
  for (int ct = 0; ct < 24; ++ct) {
    const short8* bp = wt8 + (size_t)((ct >> 3) * 128 + (ct & 7) * 16 + lr) * 16;
    acc[ct] = MFMA32(a0, bp[lq], acc[ct], 0, 0, 0);
    acc[ct] = MFMA32(a1, bp[4 + lq], acc[ct], 0, 0, 0);
    acc[ct] = MFMA32(a2, bp[8 + lq], acc[ct], 0, 0, 0);
    acc[ct] = MFMA32(a3, bp[12 + lq], acc[ct], 0, 0, 0);
  }
#pragma unroll
  for (int o = 0; o < 3; ++o) {
    unsigned* op = o == 0 ? q2 : (o == 1 ? k2 : v2);
    const float* bp2 = o == 0 ? bqL : (o == 1 ? bkL : bvL);
#pragma unroll
    for (int cc = 0; cc < 4; ++cc) {
      int col = cc * 16 + lr;
      float blo = bp2[col], bhi = bp2[64 + col];
      floatx4 alo = acc[o * 8 + cc], ahi = acc[o * 8 + cc + 4];
#pragma unroll
      for (int r = 0; r < 4; ++r) {
        int row = row0 + lq * 4 + r;
        if (row < NN)
          op[(size_t)row * 64 + col] = packbf(alo[r] + blo, ahi[r] + bhi);
      }
    }
  }
}

// ---------------------------------------------------------------------------
// k_fill: bucketed adjacency, both layers. esrc[(l*NN+d)*64 + slot] = src.
// ---------------------------------------------------------------------------
__global__ __launch_bounds__(256) void k_fill(const int* __restrict__ ei,
                                              int* __restrict__ cnt,
                                              int* __restrict__ esrc) {
  int gthr = blockIdx.x * 256 + threadIdx.x;
  if (gthr < 2 * EE) {
    int l = gthr >= EE;
    int e = gthr - l * EE;
    int s = ei[(size_t)(2 * l) * EE + e];
    int d = ei[(size_t)(2 * l + 1) * EE + e];
    int c = atomicAdd(&cnt[l * NN + d], 1);
    if (c < 64) esrc[((size_t)l * NN + d) * 64 + c] = s;
  }
}

// ---------------------------------------------------------------------------
// k_sagg5: fused edge-score + segment-softmax (no max: scores provably small,
// softmax shift-invariant) + PV + ReLU + LayerNorm. Optionally fuses the
// final 128x2 output projection (outp != null) and skips the hb write.
// ---------------------------------------------------------------------------
__global__ __launch_bounds__(256) void k_sagg5(
    const unsigned* __restrict__ q2, const unsigned* __restrict__ k2,
    const unsigned* __restrict__ v2, const int* __restrict__ esrc,
    const int* __restrict__ cnt, const float* __restrict__ g,
    const float* __restrict__ bb, u16* __restrict__ hb,
    const float* __restrict__ wo, const float* __restrict__ bo,
    float* __restrict__ outp) {
  int t = threadIdx.x, w = t >> 6, l = t & 63;
  int e = l >> 4, dd = l & 15;
  int n = blockIdx.x * 4 + w;
  int deg = cnt[n]; if (deg > 64) deg = 64;
  const int* sp = esrc + (size_t)n * 64;
  uint4 qp = *(const uint4*)(q2 + (size_t)n * 64 + dd * 4);
  float ql0 = bflo(qp.x), ql1 = bflo(qp.y), ql2 = bflo(qp.z), ql3 = bflo(qp.w);
  float qh0 = bfhi(qp.x), qh1 = bfhi(qp.y), qh2 = bfhi(qp.z), qh3 = bfhi(qp.w);
  float d0 = 0.f, d1 = 0.f;
  float al0 = 0.f, al1 = 0.f, al2 = 0.f, al3 = 0.f;
  float ah0 = 0.f, ah1 = 0.f, ah2 = 0.f, ah3 = 0.f;
  uint4 kp_c, vp_c;
  bool v_c = false;
  if (deg > 0) {
    int ii = (e < deg) ? e : deg - 1;
    v_c = e < deg;
    int s = sp[ii];
    kp_c = *(const uint4*)(k2 + (size_t)s * 64 + dd * 4);
    vp_c = *(const uint4*)(v2 + (size_t)s * 64 + dd * 4);
  }
  for (int base = 0; base < deg; base += 4) {
    uint4 kp_n, vp_n;
    bool v_n = false;
    int nb = base + 4;
    if (nb < deg) {
      int idx = nb + e;
      int ii = (idx < deg) ? idx : deg - 1;
      v_n = idx < deg;
      int s = sp[ii];
      kp_n = *(const uint4*)(k2 + (size_t)s * 64 + dd * 4);
      vp_n = *(const uint4*)(v2 + (size_t)s * 64 + dd * 4);
    }
    float r0 = ql0 * bflo(kp_c.x) + ql1 * bflo(kp_c.y) + ql2 * bflo(kp_c.z) + ql3 * bflo(kp_c.w);
    float r1 = qh0 * bfhi(kp_c.x) + qh1 * bfhi(kp_c.y) + qh2 * bfhi(kp_c.z) + qh3 * bfhi(kp_c.w);
    r0 += __shfl_xor(r0, 1, 64); r0 += __shfl_xor(r0, 2, 64); r0 += __shfl_xor(r0, 4, 64);
    r1 += __shfl_xor(r1, 1, 64); r1 += __shfl_xor(r1, 2, 64); r1 += __shfl_xor(r1, 4, 64);
    float p0 = v_c ? __expf(r0 * 0.17677669529663687f) : 0.f;
    float p1 = v_c ? __expf(r1 * 0.17677669529663687f) : 0.f;
    d0 += p0; d1 += p1;
    al0 = fmaf(p0, bflo(vp_c.x), al0); al1 = fmaf(p0, bflo(vp_c.y), al1);
    al2 = fmaf(p0, bflo(vp_c.z), al2); al3 = fmaf(p0, bflo(vp_c.w), al3);
    ah0 = fmaf(p1, bfhi(vp_c.x), ah0); ah1 = fmaf(p1, bfhi(vp_c.y), ah1);
    ah2 = fmaf(p1, bfhi(vp_c.z), ah2); ah3 = fmaf(p1, bfhi(vp_c.w), ah3);
    kp_c = kp_n; vp_c = vp_n; v_c = v_n;
  }
  // merge 4 edge-subgroups (lane bits 4,5): plain sums, no rescale needed
  d0 += __shfl_xor(d0, 16, 64); d0 += __shfl_xor(d0, 32, 64);
  d1 += __shfl_xor(d1, 16, 64); d1 += __shfl_xor(d1, 32, 64);
  al0 += __shfl_xor(al0, 16, 64); al0 += __shfl_xor(al0, 32, 64);
  al1 += __shfl_xor(al1, 16, 64); al1 += __shfl_xor(al1, 32, 64);
  al2 += __shfl_xor(al2, 16, 64); al2 += __shfl_xor(al2, 32, 64);
  al3 += __shfl_xor(al3, 16, 64); al3 += __shfl_xor(al3, 32, 64);
  ah0 += __shfl_xor(ah0, 16, 64); ah0 += __shfl_xor(ah0, 32, 64);
  ah1 += __shfl_xor(ah1, 16, 64); ah1 += __shfl_xor(ah1, 32, 64);
  ah2 += __shfl_xor(ah2, 16, 64); ah2 += __shfl_xor(ah2, 32, 64);
  ah3 += __shfl_xor(ah3, 16, 64); ah3 += __shfl_xor(ah3, 32, 64);
  float rd0 = 1.f / fmaxf(d0, 1e-9f), rd1 = 1.f / fmaxf(d1, 1e-9f);
  float ol0 = fmaxf(al0 * rd0, 0.f), ol1 = fmaxf(al1 * rd0, 0.f);
  float ol2 = fmaxf(al2 * rd0, 0.f), ol3 = fmaxf(al3 * rd0, 0.f);
  float oh0 = fmaxf(ah0 * rd1, 0.f), oh1 = fmaxf(ah1 * rd1, 0.f);
  float oh2 = fmaxf(ah2 * rd1, 0.f), oh3 = fmaxf(ah3 * rd1, 0.f);
  float s1 = ol0 + ol1 + ol2 + ol3 + oh0 + oh1 + oh2 + oh3;
  float s2 = ol0 * ol0 + ol1 * ol1 + ol2 * ol2 + ol3 * ol3 +
             oh0 * oh0 + oh1 * oh1 + oh2 * oh2 + oh3 * oh3;
  s1 += __shfl_xor(s1, 1, 64); s1 += __shfl_xor(s1, 2, 64);
  s1 += __shfl_xor(s1, 4, 64); s1 += __shfl_xor(s1, 8, 64);
  s2 += __shfl_xor(s2, 1, 64); s2 += __shfl_xor(s2, 2, 64);
  s2 += __shfl_xor(s2, 4, 64); s2 += __shfl_xor(s2, 8, 64);
  float mean = s1 * (1.f / 128.f);
  float var = s2 * (1.f / 128.f) - mean * mean;
  float rs = rsqrtf(var + 1e-5f);
  if (e == 0) {
    floatx4 gl = *(const floatx4*)(g + dd * 4);
    floatx4 bl = *(const floatx4*)(bb + dd * 4);
    floatx4 gh = *(const floatx4*)(g + 64 + dd * 4);
    floatx4 bh = *(const floatx4*)(bb + 64 + dd * 4);
    float hl0 = (ol0 - mean) * rs * gl[0] + bl[0];
    float hl1 = (ol1 - mean) * rs * gl[1] + bl[1];
    float hl2 = (ol2 - mean) * rs * gl[2] + bl[2];
    float hl3 = (ol3 - mean) * rs * gl[3] + bl[3];
    float hh0 = (oh0 - mean) * rs * gh[0] + bh[0];
    float hh1 = (oh1 - mean) * rs * gh[1] + bh[1];
    float hh2 = (oh2 - mean) * rs * gh[2] + bh[2];
    float hh3 = (oh3 - mean) * rs * gh[3] + bh[3];
    if (outp == nullptr) {
      uint2 w0, w1;
      w0.x = packbf(hl0, hl1); w0.y = packbf(hl2, hl3);
      w1.x = packbf(hh0, hh1); w1.y = packbf(hh2, hh3);
      *(uint2*)(hb + (size_t)n * 128 + dd * 4) = w0;
      *(uint2*)(hb + (size_t)n * 128 + 64 + dd * 4) = w1;
    } else {
      // fused final projection: out[n][c] = h . w_out[:,c] + b_out[c]
      const float2* wo2 = (const float2*)wo;
      float2 wa0 = wo2[dd * 4], wa1 = wo2[dd * 4 + 1];
      float2 wa2 = wo2[dd * 4 + 2], wa3 = wo2[dd * 4 + 3];
      float2 wb0 = wo2[64 + dd * 4], wb1 = wo2[64 + dd * 4 + 1];
      float2 wb2 = wo2[64 + dd * 4 + 2], wb3 = wo2[64 + dd * 4 + 3];
      float p0 = hl0 * wa0.x + hl1 * wa1.x + hl2 * wa2.x + hl3 * wa3.x +
                 hh0 * wb0.x + hh1 * wb1.x + hh2 * wb2.x + hh3 * wb3.x;
      float p1 = hl0 * wa0.y + hl1 * wa1.y + hl2 * wa2.y + hl3 * wa3.y +
                 hh0 * wb0.y + hh1 * wb1.y + hh2 * wb2.y + hh3 * wb3.y;
      p0 += __shfl_xor(p0, 1, 16); p0 += __shfl_xor(p0, 2, 16);
      p0 += __shfl_xor(p0, 4, 16); p0 += __shfl_xor(p0, 8, 16);
      p1 += __shfl_xor(p1, 1, 16); p1 += __shfl_xor(p1, 2, 16);
      p1 += __shfl_xor(p1, 4, 16); p1 += __shfl_xor(p1, 8, 16);
      if (dd == 0) {
        outp[n * 2] = p0 + bo[0];
        outp[n * 2 + 1] = p1 + bo[1];
      }
    }
  }
}

// ---------------------------------------------------------------------------
extern "C" void kernel_launch(void* const* d_in, const int* in_sizes, int n_in,
                              void* d_out, int out_size, void* d_ws, size_t ws_size,
                              hipStream_t stream) {
  const float* x = (const float*)d_in[0];
  const float* neif = (const float*)d_in[1];
  const int* ei = (const int*)d_in[2];
  const float* w_in = (const float*)d_in[3];
  const float* b_in = (const float*)d_in[4];
  const float* mha_in_w = (const float*)d_in[5];
  const float* mha_in_b = (const float*)d_in[6];
  const float* mha_out_w = (const float*)d_in[7];
  const float* mha_out_b = (const float*)d_in[8];
  const float* w_nei = (const float*)d_in[9];
  const float* b_nei = (const float*)d_in[10];
  const float* wq = (const float*)d_in[11];
  const float* bq = (const float*)d_in[12];
  const float* wk = (const float*)d_in[13];
  const float* bk = (const float*)d_in[14];
  const float* wv = (const float*)d_in[15];
  const float* bv = (const float*)d_in[16];
  const float* ln_g = (const float*)d_in[17];
  const float* ln_b = (const float*)d_in[18];
  const float* w_out = (const float*)d_in[19];
  const float* b_out = (const float*)d_in[20];
  float* out = (float*)d_out;

  // workspace layout (~70 MB)
  char* wsb = (char*)d_ws;
  size_t off = 0;
  unsigned* q2 = (unsigned*)(wsb + off); off += (size_t)NN * 64 * 4;
  unsigned* k2 = (unsigned*)(wsb + off); off += (size_t)NN * 64 * 4;
  unsigned* v2 = (unsigned*)(wsb + off); off += (size_t)NN * 64 * 4;
  int* esrc = (int*)(wsb + off);         off += (size_t)2 * NN * 64 * 4;
  u16* Yb = (u16*)(wsb + off);           off += (size_t)NN * 256 * 2;
  u16* hb = (u16*)(wsb + off);           off += (size_t)NN * 128 * 2;
  u16* xb = (u16*)(wsb + off);           off += (size_t)NN * 128 * 2;
  u16* wt3 = (u16*)(wsb + off);          off += (size_t)768 * 128 * 2;
  u16* wtP2 = (u16*)(wsb + off);         off += (size_t)128 * 384 * 2;
  u16* wtQK = (u16*)(wsb + off);         off += (size_t)128 * 64 * 2;
  float* G = (float*)(wsb + off);        off += (size_t)256 * 128 * 4;
  float* fusedW = (float*)(wsb + off);   off += 64 * 128 * 4;
  float* fusedB = (float*)(wsb + off);   off += 128 * 4;
  float* fusedB2 = (float*)(wsb + off);  off += 128 * 4;
  int* cnt = (int*)(wsb + off);          off += (size_t)2 * NN * 4;

  k_fuse<<<65, 128, 0, stream>>>(mha_out_w, mha_out_b, w_nei, b_nei, b_in, fusedW, fusedB);
  k_fuseB<<<1, 128, 0, stream>>>(fusedW, fusedB, mha_in_b, fusedB2);
  k_prepG<<<256, 128, 0, stream>>>(mha_in_w, fusedW, G);
  k_prepP2<<<128, 384, 0, stream>>>(w_in, G, wtP2);
  k_prepQK<<<128, 64, 0, stream>>>(mha_in_w, wtQK);
  k_prepW<<<768, 128, 0, stream>>>(wq, wk, wv, wt3);
  k_prepX<<<3750, 256, 0, stream>>>(x, xb);

  k_mha5<<<3000, 640, 0, stream>>>(neif, wtQK, mha_in_b, Yb);
  k_proj4<<<469, 256, 0, stream>>>(xb, Yb, wtP2, fusedB2, hb);

  hipMemsetAsync(cnt, 0, 2 * NN * sizeof(int), stream);
  k_fill<<<3750, 256, 0, stream>>>(ei, cnt, esrc);

  for (int l = 0; l < 2; ++l) {
    k_qkv4<<<469, 256, 0, stream>>>(hb, wt3 + (size_t)l * 3 * 128 * 128,
                                    bq + l * 128, bk + l * 128, bv + l * 128,
                                    q2, k2, v2);
    k_sagg5<<<NN / 4, 256, 0, stream>>>(q2, k2, v2, esrc + (size_t)l * NN * 64,
                                        cnt + l * NN, ln_g + l * 128,
                                        ln_b + l * 128, hb,
                                        w_out, b_out, l == 0 ? nullptr : out);
  }
}

// Round 8
// 323.992 us; speedup vs baseline: 3.1802x; 1.0428x over previous
//
#include <hip/hip_runtime.h>
#include <hip/hip_bf16.h>

#define NN 30000
#define EE 480000

typedef __attribute__((ext_vector_type(8))) short short8;
typedef __attribute__((ext_vector_type(4))) short short4v;
typedef __attribute__((ext_vector_type(4))) float floatx4;
typedef unsigned short u16;

__device__ __forceinline__ u16 f2bf(float f) {
  union { float f; unsigned u; } v; v.f = f;
  unsigned u = v.u;
  u += 0x7FFFu + ((u >> 16) & 1u);  // RNE
  return (u16)(u >> 16);
}
__device__ __forceinline__ float bf2f(u16 u) {
  union { unsigned u; float f; } v; v.u = ((unsigned)u) << 16;
  return v.f;
}
__device__ __forceinline__ float bflo(unsigned u) {
  union { unsigned x; float f; } v; v.x = u << 16; return v.f;
}
__device__ __forceinline__ float bfhi(unsigned u) {
  union { unsigned x; float f; } v; v.x = u & 0xFFFF0000u; return v.f;
}
__device__ __forceinline__ unsigned packbf(float a, float b) {
  return (unsigned)f2bf(a) | ((unsigned)f2bf(b) << 16);
}
__device__ __forceinline__ short8 pack8(float4 A, float4 B) {
  union { unsigned u[4]; short8 s; } r;
  r.u[0] = packbf(A.x, A.y);
  r.u[1] = packbf(A.z, A.w);
  r.u[2] = packbf(B.x, B.y);
  r.u[3] = packbf(B.z, B.w);
  return r.s;
}

#define MFMA32 __builtin_amdgcn_mfma_f32_16x16x32_bf16

#if __has_builtin(__builtin_amdgcn_mfma_f32_16x16x16bf16_1k)
__device__ __forceinline__ floatx4 MFMA16(short4v a, short4v b, floatx4 c) {
  return __builtin_amdgcn_mfma_f32_16x16x16bf16_1k(a, b, c, 0, 0, 0);
}
#else
__device__ __forceinline__ floatx4 MFMA16(short4v a, short4v b, floatx4 c) {
  asm volatile("v_mfma_f32_16x16x16_bf16 %0, %1, %2, %0"
               : "+v"(c) : "v"(a), "v"(b));
  return c;
}
#endif

// ---------------------------------------------------------------------------
// k_fuse: fusedW = mha_out_w @ w_nei ; fusedB = b_in + b_nei + mha_out_b @ w_nei
// ---------------------------------------------------------------------------
__global__ __launch_bounds__(128) void k_fuse(
    const float* __restrict__ out_w, const float* __restrict__ out_b,
    const float* __restrict__ w_nei, const float* __restrict__ b_nei,
    const float* __restrict__ b_in,
    float* __restrict__ fusedW, float* __restrict__ fusedB) {
  int i = blockIdx.x, j = threadIdx.x;
  if (i < 64) {
    float a = 0.f;
    for (int kk = 0; kk < 64; ++kk) a = fmaf(out_w[i * 64 + kk], w_nei[kk * 128 + j], a);
    fusedW[i * 128 + j] = a;
  } else {
    float a = b_in[j] + b_nei[j];
    for (int kk = 0; kk < 64; ++kk) a = fmaf(out_b[kk], w_nei[kk * 128 + j], a);
    fusedB[j] = a;
  }
}

// merged: blocks 0-255 -> G rows; block 256 -> fusedB2
__global__ __launch_bounds__(128) void k_prepB(
    const float* __restrict__ in_w, const float* __restrict__ fusedW,
    const float* __restrict__ fusedB, const float* __restrict__ in_b,
    float* __restrict__ G, float* __restrict__ fusedB2) {
  int bx = blockIdx.x, c = threadIdx.x;
  if (bx < 256) {
    int h = bx >> 6, d = bx & 63;
    float a = 0.f;
    for (int dd = 0; dd < 16; ++dd)
      a = fmaf(in_w[d * 192 + 128 + h * 16 + dd], fusedW[(h * 16 + dd) * 128 + c], a);
    G[bx * 128 + c] = a;
  } else {
    float a = fusedB[c];
    for (int d = 0; d < 64; ++d) a = fmaf(in_b[128 + d], fusedW[d * 128 + c], a);
    fusedB2[c] = a;
  }
}

// wtP2[c][k] (k<128: w_in^T, k>=128: G^T), bf16
__global__ __launch_bounds__(384) void k_prepP2(
    const float* __restrict__ w_in, const float* __restrict__ G,
    u16* __restrict__ wtP2) {
  int c = blockIdx.x, k = threadIdx.x;
  float v = (k < 128) ? w_in[(size_t)k * 128 + c] : G[(size_t)(k - 128) * 128 + c];
  wtP2[(size_t)c * 384 + k] = f2bf(v);
}

// merged: blocks 0-767 -> wt3 (graph-layer weights transposed); 768-831 -> wtQK
__global__ __launch_bounds__(128) void k_prepA(
    const float* __restrict__ wq, const float* __restrict__ wk,
    const float* __restrict__ wv, const float* __restrict__ in_w,
    u16* __restrict__ wt3, u16* __restrict__ wtQK) {
  int bx = blockIdx.x, t = threadIdx.x;
  if (bx < 768) {
    int l = bx / 384, rem = bx % 384, o = rem >> 7, c = rem & 127;
    const float* w = (o == 0 ? wq : (o == 1 ? wk : wv)) + (size_t)l * 16384;
    wt3[(size_t)bx * 128 + t] = f2bf(w[(size_t)t * 128 + c]);
  } else {
    int c = (bx - 768) * 2 + (t >> 6), kk = t & 63;
    float s = (c < 64) ? 0.25f : 1.f;
    wtQK[(size_t)c * 64 + kk] = f2bf(s * in_w[(size_t)kk * 192 + c]);
  }
}

// ---------------------------------------------------------------------------
// k_mha6b: fused QK-GEMM + per-node attention colsums + Y. 10 nodes per block.
// Phase 1 (waves 0-6) stages x bf16-transposed into LDS with per-node stride
// 16 (j=10..15 slots zero-filled -> all MFMA B reads in-bounds and exact).
// Colsum reduce in f32 (known-good). LDS: qks 29.6KB + xsT 20.5KB = 50KB.
// ---------------------------------------------------------------------------
__global__ __launch_bounds__(640) void k_mha6b(
    const float* __restrict__ xn,    // nei_features [300000,64] f32
    const u16* __restrict__ wtQK,    // [128][64] bf16
    const float* __restrict__ in_b,  // [192]
    u16* __restrict__ Yb) {          // [NN,256]
  __shared__ unsigned qks[112 * 66];
  __shared__ u16 xsT[64 * 160];      // [dim][node*16 + j], j<10 data, 10..15 zero
  int t = threadIdx.x, w = t >> 6, l = t & 63;
  int lr = l & 15, lq = l >> 4;
  const floatx4 zf = {0.f, 0.f, 0.f, 0.f};
  size_t r0 = (size_t)blockIdx.x * 100;

  // zero-fill pad slots j=10..15 for all (dim, node)
  {
    int d = t / 10, nd = t - d * 10;  // t<640 covers d<64, nd<10
#pragma unroll
    for (int j = 10; j < 16; ++j) xsT[d * 160 + nd * 16 + j] = 0;
  }

  // ---- phase 1 (waves 0-6): QK GEMM -> LDS, x rows -> LDS transposed ----
  if (w < 7) {
    int row = w * 16 + lr;
    size_t arow = r0 + row;
    if (arow > 299999) arow = 299999;
    const float* xp = xn + arow * 64 + lq * 8;
    float4 f0 = *(const float4*)xp;
    float4 f1 = *(const float4*)(xp + 4);
    float4 f2 = *(const float4*)(xp + 32);
    float4 f3 = *(const float4*)(xp + 36);
    short8 a0 = pack8(f0, f1), a1 = pack8(f2, f3);
    if (row < 100) {
      int node = row / 10, j = row - node * 10;
      int base = node * 16 + j;
      union { short8 s; u16 u[8]; } ua0, ua1;
      ua0.s = a0; ua1.s = a1;
#pragma unroll
      for (int i = 0; i < 8; ++i) {
        xsT[(lq * 8 + i) * 160 + base] = ua0.u[i];
        xsT[(32 + lq * 8 + i) * 160 + base] = ua1.u[i];
      }
    }
    floatx4 acc[8];
#pragma unroll
    for (int ct = 0; ct < 8; ++ct) acc[ct] = zf;
#pragma unroll
    for (int ct = 0; ct < 8; ++ct) {
      const short8* bp = (const short8*)(wtQK + (size_t)(ct * 16 + lr) * 64);
      acc[ct] = MFMA32(a0, bp[lq], acc[ct], 0, 0, 0);
      acc[ct] = MFMA32(a1, bp[4 + lq], acc[ct], 0, 0, 0);
    }
#pragma unroll
    for (int ct = 0; ct < 4; ++ct) {
      float bq_ = in_b[ct * 16 + lr] * 0.25f;
      float bk_ = in_b[64 + ct * 16 + lr];
#pragma unroll
      for (int r = 0; r < 4; ++r)
        qks[(w * 16 + lq * 4 + r) * 66 + ct * 16 + lr] =
            packbf(acc[ct][r] + bq_, acc[ct + 4][r] + bk_);
    }
  }
  __syncthreads();

  // ---- phase 2: one node per wave ----
  int seqc = lr < 10 ? lr : 9;
  {
    float af0 = 0.f, af1 = 0.f, af2 = 0.f, af3 = 0.f;
#pragma unroll
    for (int h = 0; h < 4; ++h) {
      const unsigned* rp = &qks[(w * 10 + seqc) * 66 + h * 16 + lq * 4];
      uint2 u0 = *(const uint2*)rp;
      uint2 u1 = *(const uint2*)(rp + 2);
      union { unsigned u[2]; short4v s; } qv, kv;
      qv.u[0] = (u0.x & 0xFFFFu) | (u0.y << 16);
      qv.u[1] = (u1.x & 0xFFFFu) | (u1.y << 16);
      kv.u[0] = (u0.x >> 16) | (u0.y & 0xFFFF0000u);
      kv.u[1] = (u1.x >> 16) | (u1.y & 0xFFFF0000u);
      floatx4 s4 = MFMA16(kv.s, qv.s, zf);   // S^T[j=lq*4+r][i=lr]
      int j0 = lq * 4;
      float e0 = (j0 + 0 < 10) ? __expf(s4[0]) : 0.f;
      float e1 = (j0 + 1 < 10) ? __expf(s4[1]) : 0.f;
      float e2 = (j0 + 2 < 10) ? __expf(s4[2]) : 0.f;
      float e3 = (j0 + 3 < 10) ? __expf(s4[3]) : 0.f;
      float den = e0 + e1 + e2 + e3;
      den += __shfl_xor(den, 16, 64);
      den += __shfl_xor(den, 32, 64);
      float rden = 0.1f / den;  // fold seq-mean 1/10
      float v0 = (lr < 10) ? e0 * rden : 0.f;
      float v1 = (lr < 10) ? e1 * rden : 0.f;
      float v2 = (lr < 10) ? e2 * rden : 0.f;
      float v3 = (lr < 10) ? e3 * rden : 0.f;
#pragma unroll
      for (int off = 1; off < 16; off <<= 1) {
        v0 += __shfl_xor(v0, off, 64);
        v1 += __shfl_xor(v1, off, 64);
        v2 += __shfl_xor(v2, off, 64);
        v3 += __shfl_xor(v3, off, 64);
      }
      if (lr == h) { af0 = v0; af1 = v1; af2 = v2; af3 = v3; }
    }
    union { unsigned u[2]; short4v s; } afv;
    afv.u[0] = packbf(af0, af1);
    afv.u[1] = packbf(af2, af3);
    size_t node = (size_t)blockIdx.x * 10 + w;
#pragma unroll
    for (int ct = 0; ct < 4; ++ct) {
      // B-frag: x^T[dim=ct*16+lr][j=lq*4..+3] from LDS (8B aligned, pads zero)
      short4v bx = *(const short4v*)&xsT[(ct * 16 + lr) * 160 + w * 16 + lq * 4];
      floatx4 y4 = MFMA16(afv.s, bx, zf);  // Y[h=row][d=ct*16+lr]
      if (lq == 0) {
        size_t yb = node * 256;
#pragma unroll
        for (int r = 0; r < 4; ++r)
          Yb[yb + r * 64 + ct * 16 + lr] = f2bf(y4[r]);
      }
    }
  }
}

// ---------------------------------------------------------------------------
// k_proj5: h_bf = bf16( [x | Y] @ wtP2 + fusedB2 ), MFMA K=384; reads x f32
// directly (packs in-register).
// ---------------------------------------------------------------------------
__global__ __launch_bounds__(256) void k_proj5(
    const float* __restrict__ x, const u16* __restrict__ Yb,
    const u16* __restrict__ wtP2, const float* __restrict__ fusedB2,
    u16* __restrict__ hb) {
  int t = threadIdx.x, w = t >> 6, l = t & 63, lr = l & 15, lq = l >> 4;
  int row0 = blockIdx.x * 64 + w * 16;
  int arow = row0 + lr; if (arow >= NN) arow = NN - 1;
  const float* xp = x + (size_t)arow * 128;
  const short8* yp = (const short8*)(Yb + (size_t)arow * 256);
  short8 afr[12];
#pragma unroll
  for (int kb = 0; kb < 4; ++kb) {
    float4 fa = *(const float4*)(xp + kb * 32 + lq * 8);
    float4 fb = *(const float4*)(xp + kb * 32 + lq * 8 + 4);
    afr[kb] = pack8(fa, fb);
  }
#pragma unroll
  for (int m = 0; m < 8; ++m) afr[4 + m] = yp[m * 4 + lq];
  floatx4 acc[8];
#pragma unroll
  for (int ct = 0; ct < 8; ++ct) acc[ct] = (floatx4){0.f, 0.f, 0.f, 0.f};
#pragma unroll
  for (int ct = 0; ct < 8; ++ct) {
    const short8* bp = (const short8*)(wtP2 + (size_t)(ct * 16 + lr) * 384);
#pragma unroll
    for (int kb = 0; kb < 12; ++kb)
      acc[ct] = MFMA32(afr[kb], bp[kb * 4 + lq], acc[ct], 0, 0, 0);
  }
#pragma unroll
  for (int ct = 0; ct < 8; ++ct) {
    int col = ct * 16 + lr;
    float bias = fusedB2[col];
#pragma unroll
    for (int r = 0; r < 4; ++r) {
      int row = row0 + lq * 4 + r;
      if (row < NN) hb[(size_t)row * 128 + col] = f2bf(acc[ct][r] + bias);
    }
  }
}

// ---------------------------------------------------------------------------
// k_qkv4: q,k,v = h_bf @ {wq,wk,wv} + b, MFMA; PAIRED u32 output layout.
// ---------------------------------------------------------------------------
__global__ __launch_bounds__(256) void k_qkv4(
    const u16* __restrict__ hb, const u16* __restrict__ wt3l,
    const float* __restrict__ bqL, const float* __restrict__ bkL,
    const float* __restrict__ bvL,
    unsigned* __restrict__ q2, unsigned* __restrict__ k2, unsigned* __restrict__ v2) {
  int t = threadIdx.x, w = t >> 6, l = t & 63, lr = l & 15, lq = l >> 4;
  int row0 = blockIdx.x * 64 + w * 16;
  int arow = row0 + lr; if (arow >= NN) arow = NN - 1;
  const short8* ap = (const short8*)(hb + (size_t)arow * 128);
  short8 a0 = ap[lq], a1 = ap[4 + lq], a2 = ap[8 + lq], a3 = ap[12 + lq];
  const short8* wt8 = (const short8*)wt3l;
  floatx4 acc[24];
#pragma unroll
  for (int ct = 0; ct < 24; ++ct) acc[ct] = (floatx4){0.f, 0.f, 0.f, 0.f};
#pragma unroll
  for (int ct = 0; ct < 24; ++ct) {
    const short8* bp = wt8 + (size_t)((ct >> 3) * 128 + (ct & 7) * 16 + lr) * 16;
    acc[ct] = MFMA32(a0, bp[lq], acc[ct], 0, 0, 0);
    acc[ct] = MFMA32(a1, bp[4 + lq], acc[ct], 0, 0, 0);
    acc[ct] = MFMA32(a2, bp[8 + lq], acc[ct], 0, 0, 0);
    acc[ct] = MFMA32(a3, bp[12 + lq], acc[ct], 0, 0, 0);
  }
#pragma unroll
  for (int o = 0; o < 3; ++o) {
    unsigned* op = o == 0 ? q2 : (o == 1 ? k2 : v2);
    const float* bp2 = o == 0 ? bqL : (o == 1 ? bkL : bvL);
#pragma unroll
    for (int cc = 0; cc < 4; ++cc) {
      int col = cc * 16 + lr;
      float blo = bp2[col], bhi = bp2[64 + col];
      floatx4 alo = acc[o * 8 + cc], ahi = acc[o * 8 + cc + 4];
#pragma unroll
      for (int r = 0; r < 4; ++r) {
        int row = row0 + lq * 4 + r;
        if (row < NN)
          op[(size_t)row * 64 + col] = packbf(alo[r] + blo, ahi[r] + bhi);
      }
    }
  }
}

// ---------------------------------------------------------------------------
// k_fill: bucketed adjacency, both layers.
// ---------------------------------------------------------------------------
__global__ __launch_bounds__(256) void k_fill(const int* __restrict__ ei,
                                              int* __restrict__ cnt,
                                              int* __restrict__ esrc) {
  int gthr = blockIdx.x * 256 + threadIdx.x;
  if (gthr < 2 * EE) {
    int l = gthr >= EE;
    int e = gthr - l * EE;
    int s = ei[(size_t)(2 * l) * EE + e];
    int d = ei[(size_t)(2 * l + 1) * EE + e];
    int c = atomicAdd(&cnt[l * NN + d], 1);
    if (c < 64) esrc[((size_t)l * NN + d) * 64 + c] = s;
  }
}

// ---------------------------------------------------------------------------
// k_sagg6: fused edge-score + segment-softmax (no max) + PV + ReLU + LN.
// 2-way ILP; all prefetch registers zero-initialized (bf16 0 = 0.0f).
// Optionally fuses the final 128x2 projection (outp != null).
// ---------------------------------------------------------------------------
__global__ __launch_bounds__(256) void k_sagg6(
    const unsigned* __restrict__ q2, const unsigned* __restrict__ k2,
    const unsigned* __restrict__ v2, const int* __restrict__ esrc,
    const int* __restrict__ cnt, const float* __restrict__ g,
    const float* __restrict__ bb, u16* __restrict__ hb,
    const float* __restrict__ wo, const float* __restrict__ bo,
    float* __restrict__ outp) {
  const float SC = 0.17677669529663687f;
  int t = threadIdx.x, w = t >> 6, l = t & 63;
  int e = l >> 4, dd = l & 15;
  int n = blockIdx.x * 4 + w;
  int deg = cnt[n]; if (deg > 64) deg = 64;
  const int* sp = esrc + (size_t)n * 64;
  uint4 qp = *(const uint4*)(q2 + (size_t)n * 64 + dd * 4);
  float ql0 = bflo(qp.x), ql1 = bflo(qp.y), ql2 = bflo(qp.z), ql3 = bflo(qp.w);
  float qh0 = bfhi(qp.x), qh1 = bfhi(qp.y), qh2 = bfhi(qp.z), qh3 = bfhi(qp.w);
  float dA0 = 0.f, dA1 = 0.f, dB0 = 0.f, dB1 = 0.f;
  float alA0 = 0.f, alA1 = 0.f, alA2 = 0.f, alA3 = 0.f;
  float ahA0 = 0.f, ahA1 = 0.f, ahA2 = 0.f, ahA3 = 0.f;
  float alB0 = 0.f, alB1 = 0.f, alB2 = 0.f, alB3 = 0.f;
  float ahB0 = 0.f, ahB1 = 0.f, ahB2 = 0.f, ahB3 = 0.f;
  uint4 kA = {0, 0, 0, 0}, vA = {0, 0, 0, 0};
  uint4 kB = {0, 0, 0, 0}, vB = {0, 0, 0, 0};
  bool mA = false, mB = false;
  if (deg > 0) {
    int iA = e < deg ? e : deg - 1;           mA = e < deg;
    int iB = 4 + e < deg ? 4 + e : deg - 1;   mB = 4 + e < deg;
    int sA = sp[iA], sB = sp[iB];
    kA = *(const uint4*)(k2 + (size_t)sA * 64 + dd * 4);
    vA = *(const uint4*)(v2 + (size_t)sA * 64 + dd * 4);
    kB = *(const uint4*)(k2 + (size_t)sB * 64 + dd * 4);
    vB = *(const uint4*)(v2 + (size_t)sB * 64 + dd * 4);
  }
  for (int base = 0; base < deg; base += 8) {
    uint4 kAn = {0, 0, 0, 0}, vAn = {0, 0, 0, 0};
    uint4 kBn = {0, 0, 0, 0}, vBn = {0, 0, 0, 0};
    bool mAn = false, mBn = false;
    int nb = base + 8;
    if (nb < deg) {
      int iA = nb + e < deg ? nb + e : deg - 1;         mAn = nb + e < deg;
      int iB = nb + 4 + e < deg ? nb + 4 + e : deg - 1; mBn = nb + 4 + e < deg;
      int sA = sp[iA], sB = sp[iB];
      kAn = *(const uint4*)(k2 + (size_t)sA * 64 + dd * 4);
      vAn = *(const uint4*)(v2 + (size_t)sA * 64 + dd * 4);
      kBn = *(const uint4*)(k2 + (size_t)sB * 64 + dd * 4);
      vBn = *(const uint4*)(v2 + (size_t)sB * 64 + dd * 4);
    }
    float rA0 = ql0 * bflo(kA.x) + ql1 * bflo(kA.y) + ql2 * bflo(kA.z) + ql3 * bflo(kA.w);
    float rA1 = qh0 * bfhi(kA.x) + qh1 * bfhi(kA.y) + qh2 * bfhi(kA.z) + qh3 * bfhi(kA.w);
    float rB0 = ql0 * bflo(kB.x) + ql1 * bflo(kB.y) + ql2 * bflo(kB.z) + ql3 * bflo(kB.w);
    float rB1 = qh0 * bfhi(kB.x) + qh1 * bfhi(kB.y) + qh2 * bfhi(kB.z) + qh3 * bfhi(kB.w);
    rA0 += __shfl_xor(rA0, 1, 64); rB0 += __shfl_xor(rB0, 1, 64);
    rA1 += __shfl_xor(rA1, 1, 64); rB1 += __shfl_xor(rB1, 1, 64);
    rA0 += __shfl_xor(rA0, 2, 64); rB0 += __shfl_xor(rB0, 2, 64);
    rA1 += __shfl_xor(rA1, 2, 64); rB1 += __shfl_xor(rB1, 2, 64);
    rA0 += __shfl_xor(rA0, 4, 64); rB0 += __shfl_xor(rB0, 4, 64);
    rA1 += __shfl_xor(rA1, 4, 64); rB1 += __shfl_xor(rB1, 4, 64);
    float pA0 = mA ? __expf(rA0 * SC) : 0.f;
    float pA1 = mA ? __expf(rA1 * SC) : 0.f;
    float pB0 = mB ? __expf(rB0 * SC) : 0.f;
    float pB1 = mB ? __expf(rB1 * SC) : 0.f;
    dA0 += pA0; dA1 += pA1; dB0 += pB0; dB1 += pB1;
    alA0 = fmaf(pA0, bflo(vA.x), alA0); alA1 = fmaf(pA0, bflo(vA.y), alA1);
    alA2 = fmaf(pA0, bflo(vA.z), alA2); alA3 = fmaf(pA0, bflo(vA.w), alA3);
    ahA0 = fmaf(pA1, bfhi(vA.x), ahA0); ahA1 = fmaf(pA1, bfhi(vA.y), ahA1);
    ahA2 = fmaf(pA1, bfhi(vA.z), ahA2); ahA3 = fmaf(pA1, bfhi(vA.w), ahA3);
    alB0 = fmaf(pB0, bflo(vB.x), alB0); alB1 = fmaf(pB0, bflo(vB.y), alB1);
    alB2 = fmaf(pB0, bflo(vB.z), alB2); alB3 = fmaf(pB0, bflo(vB.w), alB3);
    ahB0 = fmaf(pB1, bfhi(vB.x), ahB0); ahB1 = fmaf(pB1, bfhi(vB.y), ahB1);
    ahB2 = fmaf(pB1, bfhi(vB.z), ahB2); ahB3 = fmaf(pB1, bfhi(vB.w), ahB3);
    kA = kAn; vA = vAn; mA = mAn;
    kB = kBn; vB = vBn; mB = mBn;
  }
  float d0 = dA0 + dB0, d1 = dA1 + dB1;
  float al0 = alA0 + alB0, al1 = alA1 + alB1, al2 = alA2 + alB2, al3 = alA3 + alB3;
  float ah0 = ahA0 + ahB0, ah1 = ahA1 + ahB1, ah2 = ahA2 + ahB2, ah3 = ahA3 + ahB3;
  d0 += __shfl_xor(d0, 16, 64); d0 += __shfl_xor(d0, 32, 64);
  d1 += __shfl_xor(d1, 16, 64); d1 += __shfl_xor(d1, 32, 64);
  al0 += __shfl_xor(al0, 16, 64); al0 += __shfl_xor(al0, 32, 64);
  al1 += __shfl_xor(al1, 16, 64); al1 += __shfl_xor(al1, 32, 64);
  al2 += __shfl_xor(al2, 16, 64); al2 += __shfl_xor(al2, 32, 64);
  al3 += __shfl_xor(al3, 16, 64); al3 += __shfl_xor(al3, 32, 64);
  ah0 += __shfl_xor(ah0, 16, 64); ah0 += __shfl_xor(ah0, 32, 64);
  ah1 += __shfl_xor(ah1, 16, 64); ah1 += __shfl_xor(ah1, 32, 64);
  ah2 += __shfl_xor(ah2, 16, 64); ah2 += __shfl_xor(ah2, 32, 64);
  ah3 += __shfl_xor(ah3, 16, 64); ah3 += __shfl_xor(ah3, 32, 64);
  float rd0 = 1.f / fmaxf(d0, 1e-9f), rd1 = 1.f / fmaxf(d1, 1e-9f);
  float ol0 = fmaxf(al0 * rd0, 0.f), ol1 = fmaxf(al1 * rd0, 0.f);
  float ol2 = fmaxf(al2 * rd0, 0.f), ol3 = fmaxf(al3 * rd0, 0.f);
  float oh0 = fmaxf(ah0 * rd1, 0.f), oh1 = fmaxf(ah1 * rd1, 0.f);
  float oh2 = fmaxf(ah2 * rd1, 0.f), oh3 = fmaxf(ah3 * rd1, 0.f);
  float s1 = ol0 + ol1 + ol2 + ol3 + oh0 + oh1 + oh2 + oh3;
  float s2 = ol0 * ol0 + ol1 * ol1 + ol2 * ol2 + ol3 * ol3 +
             oh0 * oh0 + oh1 * oh1 + oh2 * oh2 + oh3 * oh3;
  s1 += __shfl_xor(s1, 1, 64); s1 += __shfl_xor(s1, 2, 64);
  s1 += __shfl_xor(s1, 4, 64); s1 += __shfl_xor(s1, 8, 64);
  s2 += __shfl_xor(s2, 1, 64); s2 += __shfl_xor(s2, 2, 64);
  s2 += __shfl_xor(s2, 4, 64); s2 += __shfl_xor(s2, 8, 64);
  float mean = s1 * (1.f / 128.f);
  float var = s2 * (1.f / 128.f) - mean * mean;
  float rs = rsqrtf(var + 1e-5f);
  if (e == 0) {
    floatx4 gl = *(const floatx4*)(g + dd * 4);
    floatx4 bl = *(const floatx4*)(bb + dd * 4);
    floatx4 gh = *(const floatx4*)(g + 64 + dd * 4);
    floatx4 bh = *(const floatx4*)(bb + 64 + dd * 4);
    float hl0 = (ol0 - mean) * rs * gl[0] + bl[0];
    float hl1 = (ol1 - mean) * rs * gl[1] + bl[1];
    float hl2 = (ol2 - mean) * rs * gl[2] + bl[2];
    float hl3 = (ol3 - mean) * rs * gl[3] + bl[3];
    float hh0 = (oh0 - mean) * rs * gh[0] + bh[0];
    float hh1 = (oh1 - mean) * rs * gh[1] + bh[1];
    float hh2 = (oh2 - mean) * rs * gh[2] + bh[2];
    float hh3 = (oh3 - mean) * rs * gh[3] + bh[3];
    if (outp == nullptr) {
      uint2 w0, w1;
      w0.x = packbf(hl0, hl1); w0.y = packbf(hl2, hl3);
      w1.x = packbf(hh0, hh1); w1.y = packbf(hh2, hh3);
      *(uint2*)(hb + (size_t)n * 128 + dd * 4) = w0;
      *(uint2*)(hb + (size_t)n * 128 + 64 + dd * 4) = w1;
    } else {
      const float2* wo2 = (const float2*)wo;
      float2 wa0 = wo2[dd * 4], wa1 = wo2[dd * 4 + 1];
      float2 wa2 = wo2[dd * 4 + 2], wa3 = wo2[dd * 4 + 3];
      float2 wb0 = wo2[64 + dd * 4], wb1 = wo2[64 + dd * 4 + 1];
      float2 wb2 = wo2[64 + dd * 4 + 2], wb3 = wo2[64 + dd * 4 + 3];
      float p0 = hl0 * wa0.x + hl1 * wa1.x + hl2 * wa2.x + hl3 * wa3.x +
                 hh0 * wb0.x + hh1 * wb1.x + hh2 * wb2.x + hh3 * wb3.x;
      float p1 = hl0 * wa0.y + hl1 * wa1.y + hl2 * wa2.y + hl3 * wa3.y +
                 hh0 * wb0.y + hh1 * wb1.y + hh2 * wb2.y + hh3 * wb3.y;
      p0 += __shfl_xor(p0, 1, 16); p0 += __shfl_xor(p0, 2, 16);
      p0 += __shfl_xor(p0, 4, 16); p0 += __shfl_xor(p0, 8, 16);
      p1 += __shfl_xor(p1, 1, 16); p1 += __shfl_xor(p1, 2, 16);
      p1 += __shfl_xor(p1, 4, 16); p1 += __shfl_xor(p1, 8, 16);
      if (dd == 0) {
        outp[n * 2] = p0 + bo[0];
        outp[n * 2 + 1] = p1 + bo[1];
      }
    }
  }
}

// ---------------------------------------------------------------------------
extern "C" void kernel_launch(void* const* d_in, const int* in_sizes, int n_in,
                              void* d_out, int out_size, void* d_ws, size_t ws_size,
                              hipStream_t stream) {
  const float* x = (const float*)d_in[0];
  const float* neif = (const float*)d_in[1];
  const int* ei = (const int*)d_in[2];
  const float* w_in = (const float*)d_in[3];
  const float* b_in = (const float*)d_in[4];
  const float* mha_in_w = (const float*)d_in[5];
  const float* mha_in_b = (const float*)d_in[6];
  const float* mha_out_w = (const float*)d_in[7];
  const float* mha_out_b = (const float*)d_in[8];
  const float* w_nei = (const float*)d_in[9];
  const float* b_nei = (const float*)d_in[10];
  const float* wq = (const float*)d_in[11];
  const float* bq = (const float*)d_in[12];
  const float* wk = (const float*)d_in[13];
  const float* bk = (const float*)d_in[14];
  const float* wv = (const float*)d_in[15];
  const float* bv = (const float*)d_in[16];
  const float* ln_g = (const float*)d_in[17];
  const float* ln_b = (const float*)d_in[18];
  const float* w_out = (const float*)d_in[19];
  const float* b_out = (const float*)d_in[20];
  float* out = (float*)d_out;

  // workspace layout (~62 MB)
  char* wsb = (char*)d_ws;
  size_t off = 0;
  unsigned* q2 = (unsigned*)(wsb + off); off += (size_t)NN * 64 * 4;
  unsigned* k2 = (unsigned*)(wsb + off); off += (size_t)NN * 64 * 4;
  unsigned* v2 = (unsigned*)(wsb + off); off += (size_t)NN * 64 * 4;
  int* esrc = (int*)(wsb + off);         off += (size_t)2 * NN * 64 * 4;
  u16* Yb = (u16*)(wsb + off);           off += (size_t)NN * 256 * 2;
  u16* hb = (u16*)(wsb + off);           off += (size_t)NN * 128 * 2;
  u16* wt3 = (u16*)(wsb + off);          off += (size_t)768 * 128 * 2;
  u16* wtP2 = (u16*)(wsb + off);         off += (size_t)128 * 384 * 2;
  u16* wtQK = (u16*)(wsb + off);         off += (size_t)128 * 64 * 2;
  float* G = (float*)(wsb + off);        off += (size_t)256 * 128 * 4;
  float* fusedW = (float*)(wsb + off);   off += 64 * 128 * 4;
  float* fusedB = (float*)(wsb + off);   off += 128 * 4;
  float* fusedB2 = (float*)(wsb + off);  off += 128 * 4;
  int* cnt = (int*)(wsb + off);          off += (size_t)2 * NN * 4;

  k_fuse<<<65, 128, 0, stream>>>(mha_out_w, mha_out_b, w_nei, b_nei, b_in, fusedW, fusedB);
  k_prepB<<<257, 128, 0, stream>>>(mha_in_w, fusedW, fusedB, mha_in_b, G, fusedB2);
  k_prepP2<<<128, 384, 0, stream>>>(w_in, G, wtP2);
  k_prepA<<<832, 128, 0, stream>>>(wq, wk, wv, mha_in_w, wt3, wtQK);

  k_mha6b<<<3000, 640, 0, stream>>>(neif, wtQK, mha_in_b, Yb);
  k_proj5<<<469, 256, 0, stream>>>(x, Yb, wtP2, fusedB2, hb);

  hipMemsetAsync(cnt, 0, 2 * NN * sizeof(int), stream);
  k_fill<<<3750, 256, 0, stream>>>(ei, cnt, esrc);

  for (int l = 0; l < 2; ++l) {
    k_qkv4<<<469, 256, 0, stream>>>(hb, wt3 + (size_t)l * 3 * 128 * 128,
                                    bq + l * 128, bk + l * 128, bv + l * 128,
                                    q2, k2, v2);
    k_sagg6<<<NN / 4, 256, 0, stream>>>(q2, k2, v2, esrc + (size_t)l * NN * 64,
                                        cnt + l * NN, ln_g + l * 128,
                                        ln_b + l * 128, hb,
                                        w_out, b_out, l == 0 ? nullptr : out);
  }
}

// Round 9
// 315.816 us; speedup vs baseline: 3.2625x; 1.0259x over previous
//
#include <hip/hip_runtime.h>
#include <hip/hip_bf16.h>

#define NN 30000
#define EE 480000

typedef __attribute__((ext_vector_type(8))) short short8;
typedef __attribute__((ext_vector_type(4))) short short4v;
typedef __attribute__((ext_vector_type(4))) float floatx4;
typedef unsigned short u16;

__device__ __forceinline__ u16 f2bf(float f) {
  union { float f; unsigned u; } v; v.f = f;
  unsigned u = v.u;
  u += 0x7FFFu + ((u >> 16) & 1u);  // RNE
  return (u16)(u >> 16);
}
__device__ __forceinline__ float bf2f(u16 u) {
  union { unsigned u; float f; } v; v.u = ((unsigned)u) << 16;
  return v.f;
}
__device__ __forceinline__ float bflo(unsigned u) {
  union { unsigned x; float f; } v; v.x = u << 16; return v.f;
}
__device__ __forceinline__ float bfhi(unsigned u) {
  union { unsigned x; float f; } v; v.x = u & 0xFFFF0000u; return v.f;
}
__device__ __forceinline__ unsigned packbf(float a, float b) {
  return (unsigned)f2bf(a) | ((unsigned)f2bf(b) << 16);
}
__device__ __forceinline__ short8 pack8(float4 A, float4 B) {
  union { unsigned u[4]; short8 s; } r;
  r.u[0] = packbf(A.x, A.y);
  r.u[1] = packbf(A.z, A.w);
  r.u[2] = packbf(B.x, B.y);
  r.u[3] = packbf(B.z, B.w);
  return r.s;
}

// ---- DPP cross-lane adds (VALU pipe, no LDS) ----
template <int CTRL>
__device__ __forceinline__ float dppadd(float v) {
  int s = __builtin_amdgcn_update_dpp(0, __builtin_bit_cast(int, v), CTRL, 0xF, 0xF, true);
  return v + __builtin_bit_cast(float, s);
}
// sum over all 16 lanes of a row (result in every lane): row_ror 1,2,4,8
__device__ __forceinline__ float rowsum16(float v) {
  v = dppadd<0x121>(v); v = dppadd<0x122>(v); v = dppadd<0x124>(v); v = dppadd<0x128>(v);
  return v;
}
// sum over each 8-lane half-row: quad_perm xor1 (0xB1), xor2 (0x4E), quad-swap (half_mirror)
__device__ __forceinline__ float rowsum8(float v) {
  v = dppadd<0xB1>(v); v = dppadd<0x4E>(v); v = dppadd<0x141>(v);
  return v;
}

#define MFMA32 __builtin_amdgcn_mfma_f32_16x16x32_bf16

#if __has_builtin(__builtin_amdgcn_mfma_f32_16x16x16bf16_1k)
__device__ __forceinline__ floatx4 MFMA16(short4v a, short4v b, floatx4 c) {
  return __builtin_amdgcn_mfma_f32_16x16x16bf16_1k(a, b, c, 0, 0, 0);
}
#else
__device__ __forceinline__ floatx4 MFMA16(short4v a, short4v b, floatx4 c) {
  asm volatile("v_mfma_f32_16x16x16_bf16 %0, %1, %2, %0"
               : "+v"(c) : "v"(a), "v"(b));
  return c;
}
#endif

// ---------------------------------------------------------------------------
// k_fuse: fusedW = mha_out_w @ w_nei ; fusedB = b_in + b_nei + mha_out_b @ w_nei
// ---------------------------------------------------------------------------
__global__ __launch_bounds__(128) void k_fuse(
    const float* __restrict__ out_w, const float* __restrict__ out_b,
    const float* __restrict__ w_nei, const float* __restrict__ b_nei,
    const float* __restrict__ b_in,
    float* __restrict__ fusedW, float* __restrict__ fusedB) {
  int i = blockIdx.x, j = threadIdx.x;
  if (i < 64) {
    float a = 0.f;
    for (int kk = 0; kk < 64; ++kk) a = fmaf(out_w[i * 64 + kk], w_nei[kk * 128 + j], a);
    fusedW[i * 128 + j] = a;
  } else {
    float a = b_in[j] + b_nei[j];
    for (int kk = 0; kk < 64; ++kk) a = fmaf(out_b[kk], w_nei[kk * 128 + j], a);
    fusedB[j] = a;
  }
}

// merged: blocks 0-255 -> G rows; block 256 -> fusedB2
__global__ __launch_bounds__(128) void k_prepB(
    const float* __restrict__ in_w, const float* __restrict__ fusedW,
    const float* __restrict__ fusedB, const float* __restrict__ in_b,
    float* __restrict__ G, float* __restrict__ fusedB2) {
  int bx = blockIdx.x, c = threadIdx.x;
  if (bx < 256) {
    int h = bx >> 6, d = bx & 63;
    float a = 0.f;
    for (int dd = 0; dd < 16; ++dd)
      a = fmaf(in_w[d * 192 + 128 + h * 16 + dd], fusedW[(h * 16 + dd) * 128 + c], a);
    G[bx * 128 + c] = a;
  } else {
    float a = fusedB[c];
    for (int d = 0; d < 64; ++d) a = fmaf(in_b[128 + d], fusedW[d * 128 + c], a);
    fusedB2[c] = a;
  }
}

// wtP2[c][k] (k<128: w_in^T, k>=128: G^T), bf16
__global__ __launch_bounds__(384) void k_prepP2(
    const float* __restrict__ w_in, const float* __restrict__ G,
    u16* __restrict__ wtP2) {
  int c = blockIdx.x, k = threadIdx.x;
  float v = (k < 128) ? w_in[(size_t)k * 128 + c] : G[(size_t)(k - 128) * 128 + c];
  wtP2[(size_t)c * 384 + k] = f2bf(v);
}

// merged: blocks 0-767 -> wt3 (graph-layer weights transposed); 768-831 -> wtQK
__global__ __launch_bounds__(128) void k_prepA(
    const float* __restrict__ wq, const float* __restrict__ wk,
    const float* __restrict__ wv, const float* __restrict__ in_w,
    u16* __restrict__ wt3, u16* __restrict__ wtQK) {
  int bx = blockIdx.x, t = threadIdx.x;
  if (bx < 768) {
    int l = bx / 384, rem = bx % 384, o = rem >> 7, c = rem & 127;
    const float* w = (o == 0 ? wq : (o == 1 ? wk : wv)) + (size_t)l * 16384;
    wt3[(size_t)bx * 128 + t] = f2bf(w[(size_t)t * 128 + c]);
  } else {
    int c = (bx - 768) * 2 + (t >> 6), kk = t & 63;
    float s = (c < 64) ? 0.25f : 1.f;
    wtQK[(size_t)c * 64 + kk] = f2bf(s * in_w[(size_t)kk * 192 + c]);
  }
}

// ---------------------------------------------------------------------------
// k_mha7: as k_mha6b, but colsum reduce done with DPP row_ror adds (VALU)
// instead of ds_swizzle shfl chains.
// ---------------------------------------------------------------------------
__global__ __launch_bounds__(640) void k_mha7(
    const float* __restrict__ xn,    // nei_features [300000,64] f32
    const u16* __restrict__ wtQK,    // [128][64] bf16
    const float* __restrict__ in_b,  // [192]
    u16* __restrict__ Yb) {          // [NN,256]
  __shared__ unsigned qks[112 * 66];
  __shared__ u16 xsT[64 * 160];      // [dim][node*16 + j], j<10 data, 10..15 zero
  int t = threadIdx.x, w = t >> 6, l = t & 63;
  int lr = l & 15, lq = l >> 4;
  const floatx4 zf = {0.f, 0.f, 0.f, 0.f};
  size_t r0 = (size_t)blockIdx.x * 100;

  {
    int d = t / 10, nd = t - d * 10;
#pragma unroll
    for (int j = 10; j < 16; ++j) xsT[d * 160 + nd * 16 + j] = 0;
  }

  // ---- phase 1 (waves 0-6): QK GEMM -> LDS, x rows -> LDS transposed ----
  if (w < 7) {
    int row = w * 16 + lr;
    size_t arow = r0 + row;
    if (arow > 299999) arow = 299999;
    const float* xp = xn + arow * 64 + lq * 8;
    float4 f0 = *(const float4*)xp;
    float4 f1 = *(const float4*)(xp + 4);
    float4 f2 = *(const float4*)(xp + 32);
    float4 f3 = *(const float4*)(xp + 36);
    short8 a0 = pack8(f0, f1), a1 = pack8(f2, f3);
    if (row < 100) {
      int node = row / 10, j = row - node * 10;
      int base = node * 16 + j;
      union { short8 s; u16 u[8]; } ua0, ua1;
      ua0.s = a0; ua1.s = a1;
#pragma unroll
      for (int i = 0; i < 8; ++i) {
        xsT[(lq * 8 + i) * 160 + base] = ua0.u[i];
        xsT[(32 + lq * 8 + i) * 160 + base] = ua1.u[i];
      }
    }
    floatx4 acc[8];
#pragma unroll
    for (int ct = 0; ct < 8; ++ct) acc[ct] = zf;
#pragma unroll
    for (int ct = 0; ct < 8; ++ct) {
      const short8* bp = (const short8*)(wtQK + (size_t)(ct * 16 + lr) * 64);
      acc[ct] = MFMA32(a0, bp[lq], acc[ct], 0, 0, 0);
      acc[ct] = MFMA32(a1, bp[4 + lq], acc[ct], 0, 0, 0);
    }
#pragma unroll
    for (int ct = 0; ct < 4; ++ct) {
      float bq_ = in_b[ct * 16 + lr] * 0.25f;
      float bk_ = in_b[64 + ct * 16 + lr];
#pragma unroll
      for (int r = 0; r < 4; ++r)
        qks[(w * 16 + lq * 4 + r) * 66 + ct * 16 + lr] =
            packbf(acc[ct][r] + bq_, acc[ct + 4][r] + bk_);
    }
  }
  __syncthreads();

  // ---- phase 2: one node per wave ----
  int seqc = lr < 10 ? lr : 9;
  {
    float af0 = 0.f, af1 = 0.f, af2 = 0.f, af3 = 0.f;
#pragma unroll
    for (int h = 0; h < 4; ++h) {
      const unsigned* rp = &qks[(w * 10 + seqc) * 66 + h * 16 + lq * 4];
      uint2 u0 = *(const uint2*)rp;
      uint2 u1 = *(const uint2*)(rp + 2);
      union { unsigned u[2]; short4v s; } qv, kv;
      qv.u[0] = (u0.x & 0xFFFFu) | (u0.y << 16);
      qv.u[1] = (u1.x & 0xFFFFu) | (u1.y << 16);
      kv.u[0] = (u0.x >> 16) | (u0.y & 0xFFFF0000u);
      kv.u[1] = (u1.x >> 16) | (u1.y & 0xFFFF0000u);
      floatx4 s4 = MFMA16(kv.s, qv.s, zf);   // S^T[j=lq*4+r][i=lr]
      int j0 = lq * 4;
      float e0 = (j0 + 0 < 10) ? __expf(s4[0]) : 0.f;
      float e1 = (j0 + 1 < 10) ? __expf(s4[1]) : 0.f;
      float e2 = (j0 + 2 < 10) ? __expf(s4[2]) : 0.f;
      float e3 = (j0 + 3 < 10) ? __expf(s4[3]) : 0.f;
      float den = e0 + e1 + e2 + e3;
      den += __shfl_xor(den, 16, 64);
      den += __shfl_xor(den, 32, 64);
      float rden = 0.1f / den;  // fold seq-mean 1/10
      float v0 = (lr < 10) ? e0 * rden : 0.f;
      float v1 = (lr < 10) ? e1 * rden : 0.f;
      float v2 = (lr < 10) ? e2 * rden : 0.f;
      float v3 = (lr < 10) ? e3 * rden : 0.f;
      // colsum over i=lr (16-lane row) via DPP row_ror adds - VALU only
      v0 = rowsum16(v0);
      v1 = rowsum16(v1);
      v2 = rowsum16(v2);
      v3 = rowsum16(v3);
      if (lr == h) { af0 = v0; af1 = v1; af2 = v2; af3 = v3; }
    }
    union { unsigned u[2]; short4v s; } afv;
    afv.u[0] = packbf(af0, af1);
    afv.u[1] = packbf(af2, af3);
    size_t node = (size_t)blockIdx.x * 10 + w;
#pragma unroll
    for (int ct = 0; ct < 4; ++ct) {
      short4v bx = *(const short4v*)&xsT[(ct * 16 + lr) * 160 + w * 16 + lq * 4];
      floatx4 y4 = MFMA16(afv.s, bx, zf);  // Y[h=row][d=ct*16+lr]
      if (lq == 0) {
        size_t yb = node * 256;
#pragma unroll
        for (int r = 0; r < 4; ++r)
          Yb[yb + r * 64 + ct * 16 + lr] = f2bf(y4[r]);
      }
    }
  }
}

// ---------------------------------------------------------------------------
// k_proj5: h_bf = bf16( [x | Y] @ wtP2 + fusedB2 ), MFMA K=384.
// ---------------------------------------------------------------------------
__global__ __launch_bounds__(256) void k_proj5(
    const float* __restrict__ x, const u16* __restrict__ Yb,
    const u16* __restrict__ wtP2, const float* __restrict__ fusedB2,
    u16* __restrict__ hb) {
  int t = threadIdx.x, w = t >> 6, l = t & 63, lr = l & 15, lq = l >> 4;
  int row0 = blockIdx.x * 64 + w * 16;
  int arow = row0 + lr; if (arow >= NN) arow = NN - 1;
  const float* xp = x + (size_t)arow * 128;
  const short8* yp = (const short8*)(Yb + (size_t)arow * 256);
  short8 afr[12];
#pragma unroll
  for (int kb = 0; kb < 4; ++kb) {
    float4 fa = *(const float4*)(xp + kb * 32 + lq * 8);
    float4 fb = *(const float4*)(xp + kb * 32 + lq * 8 + 4);
    afr[kb] = pack8(fa, fb);
  }
#pragma unroll
  for (int m = 0; m < 8; ++m) afr[4 + m] = yp[m * 4 + lq];
  floatx4 acc[8];
#pragma unroll
  for (int ct = 0; ct < 8; ++ct) acc[ct] = (floatx4){0.f, 0.f, 0.f, 0.f};
#pragma unroll
  for (int ct = 0; ct < 8; ++ct) {
    const short8* bp = (const short8*)(wtP2 + (size_t)(ct * 16 + lr) * 384);
#pragma unroll
    for (int kb = 0; kb < 12; ++kb)
      acc[ct] = MFMA32(afr[kb], bp[kb * 4 + lq], acc[ct], 0, 0, 0);
  }
#pragma unroll
  for (int ct = 0; ct < 8; ++ct) {
    int col = ct * 16 + lr;
    float bias = fusedB2[col];
#pragma unroll
    for (int r = 0; r < 4; ++r) {
      int row = row0 + lq * 4 + r;
      if (row < NN) hb[(size_t)row * 128 + col] = f2bf(acc[ct][r] + bias);
    }
  }
}

// ---------------------------------------------------------------------------
// k_qkv4: q,k,v = h_bf @ {wq,wk,wv} + b, MFMA; PAIRED u32 output layout.
// ---------------------------------------------------------------------------
__global__ __launch_bounds__(256) void k_qkv4(
    const u16* __restrict__ hb, const u16* __restrict__ wt3l,
    const float* __restrict__ bqL, const float* __restrict__ bkL,
    const float* __restrict__ bvL,
    unsigned* __restrict__ q2, unsigned* __restrict__ k2, unsigned* __restrict__ v2) {
  int t = threadIdx.x, w = t >> 6, l = t & 63, lr = l & 15, lq = l >> 4;
  int row0 = blockIdx.x * 64 + w * 16;
  int arow = row0 + lr; if (arow >= NN) arow = NN - 1;
  const short8* ap = (const short8*)(hb + (size_t)arow * 128);
  short8 a0 = ap[lq], a1 = ap[4 + lq], a2 = ap[8 + lq], a3 = ap[12 + lq];
  const short8* wt8 = (const short8*)wt3l;
  floatx4 acc[24];
#pragma unroll
  for (int ct = 0; ct < 24; ++ct) acc[ct] = (floatx4){0.f, 0.f, 0.f, 0.f};
#pragma unroll
  for (int ct = 0; ct < 24; ++ct) {
    const short8* bp = wt8 + (size_t)((ct >> 3) * 128 + (ct & 7) * 16 + lr) * 16;
    acc[ct] = MFMA32(a0, bp[lq], acc[ct], 0, 0, 0);
    acc[ct] = MFMA32(a1, bp[4 + lq], acc[ct], 0, 0, 0);
    acc[ct] = MFMA32(a2, bp[8 + lq], acc[ct], 0, 0, 0);
    acc[ct] = MFMA32(a3, bp[12 + lq], acc[ct], 0, 0, 0);
  }
#pragma unroll
  for (int o = 0; o < 3; ++o) {
    unsigned* op = o == 0 ? q2 : (o == 1 ? k2 : v2);
    const float* bp2 = o == 0 ? bqL : (o == 1 ? bkL : bvL);
#pragma unroll
    for (int cc = 0; cc < 4; ++cc) {
      int col = cc * 16 + lr;
      float blo = bp2[col], bhi = bp2[64 + col];
      floatx4 alo = acc[o * 8 + cc], ahi = acc[o * 8 + cc + 4];
#pragma unroll
      for (int r = 0; r < 4; ++r) {
        int row = row0 + lq * 4 + r;
        if (row < NN)
          op[(size_t)row * 64 + col] = packbf(alo[r] + blo, ahi[r] + bhi);
      }
    }
  }
}

// ---------------------------------------------------------------------------
// k_fill: bucketed adjacency, both layers.
// ---------------------------------------------------------------------------
__global__ __launch_bounds__(256) void k_fill(const int* __restrict__ ei,
                                              int* __restrict__ cnt,
                                              int* __restrict__ esrc) {
  int gthr = blockIdx.x * 256 + threadIdx.x;
  if (gthr < 2 * EE) {
    int l = gthr >= EE;
    int e = gthr - l * EE;
    int s = ei[(size_t)(2 * l) * EE + e];
    int d = ei[(size_t)(2 * l + 1) * EE + e];
    int c = atomicAdd(&cnt[l * NN + d], 1);
    if (c < 64) esrc[((size_t)l * NN + d) * 64 + c] = s;
  }
}

// ---------------------------------------------------------------------------
// k_sagg7: as k_sagg6 but score dot-reduce via DPP (quad_perm + half_mirror,
// VALU) and LN / fused-out reduces via DPP row_ror - LDS pipe only for the
// once-per-node cross-row merges.
// ---------------------------------------------------------------------------
__global__ __launch_bounds__(256) void k_sagg7(
    const unsigned* __restrict__ q2, const unsigned* __restrict__ k2,
    const unsigned* __restrict__ v2, const int* __restrict__ esrc,
    const int* __restrict__ cnt, const float* __restrict__ g,
    const float* __restrict__ bb, u16* __restrict__ hb,
    const float* __restrict__ wo, const float* __restrict__ bo,
    float* __restrict__ outp) {
  const float SC = 0.17677669529663687f;
  int t = threadIdx.x, w = t >> 6, l = t & 63;
  int e = l >> 4, dd = l & 15;
  int n = blockIdx.x * 4 + w;
  int deg = cnt[n]; if (deg > 64) deg = 64;
  const int* sp = esrc + (size_t)n * 64;
  uint4 qp = *(const uint4*)(q2 + (size_t)n * 64 + dd * 4);
  float ql0 = bflo(qp.x), ql1 = bflo(qp.y), ql2 = bflo(qp.z), ql3 = bflo(qp.w);
  float qh0 = bfhi(qp.x), qh1 = bfhi(qp.y), qh2 = bfhi(qp.z), qh3 = bfhi(qp.w);
  float dA0 = 0.f, dA1 = 0.f, dB0 = 0.f, dB1 = 0.f;
  float alA0 = 0.f, alA1 = 0.f, alA2 = 0.f, alA3 = 0.f;
  float ahA0 = 0.f, ahA1 = 0.f, ahA2 = 0.f, ahA3 = 0.f;
  float alB0 = 0.f, alB1 = 0.f, alB2 = 0.f, alB3 = 0.f;
  float ahB0 = 0.f, ahB1 = 0.f, ahB2 = 0.f, ahB3 = 0.f;
  uint4 kA = {0, 0, 0, 0}, vA = {0, 0, 0, 0};
  uint4 kB = {0, 0, 0, 0}, vB = {0, 0, 0, 0};
  bool mA = false, mB = false;
  if (deg > 0) {
    int iA = e < deg ? e : deg - 1;           mA = e < deg;
    int iB = 4 + e < deg ? 4 + e : deg - 1;   mB = 4 + e < deg;
    int sA = sp[iA], sB = sp[iB];
    kA = *(const uint4*)(k2 + (size_t)sA * 64 + dd * 4);
    vA = *(const uint4*)(v2 + (size_t)sA * 64 + dd * 4);
    kB = *(const uint4*)(k2 + (size_t)sB * 64 + dd * 4);
    vB = *(const uint4*)(v2 + (size_t)sB * 64 + dd * 4);
  }
  for (int base = 0; base < deg; base += 8) {
    uint4 kAn = {0, 0, 0, 0}, vAn = {0, 0, 0, 0};
    uint4 kBn = {0, 0, 0, 0}, vBn = {0, 0, 0, 0};
    bool mAn = false, mBn = false;
    int nb = base + 8;
    if (nb < deg) {
      int iA = nb + e < deg ? nb + e : deg - 1;         mAn = nb + e < deg;
      int iB = nb + 4 + e < deg ? nb + 4 + e : deg - 1; mBn = nb + 4 + e < deg;
      int sA = sp[iA], sB = sp[iB];
      kAn = *(const uint4*)(k2 + (size_t)sA * 64 + dd * 4);
      vAn = *(const uint4*)(v2 + (size_t)sA * 64 + dd * 4);
      kBn = *(const uint4*)(k2 + (size_t)sB * 64 + dd * 4);
      vBn = *(const uint4*)(v2 + (size_t)sB * 64 + dd * 4);
    }
    float rA0 = ql0 * bflo(kA.x) + ql1 * bflo(kA.y) + ql2 * bflo(kA.z) + ql3 * bflo(kA.w);
    float rA1 = qh0 * bfhi(kA.x) + qh1 * bfhi(kA.y) + qh2 * bfhi(kA.z) + qh3 * bfhi(kA.w);
    float rB0 = ql0 * bflo(kB.x) + ql1 * bflo(kB.y) + ql2 * bflo(kB.z) + ql3 * bflo(kB.w);
    float rB1 = qh0 * bfhi(kB.x) + qh1 * bfhi(kB.y) + qh2 * bfhi(kB.z) + qh3 * bfhi(kB.w);
    // 8-lane head-group dot reduce: pure VALU DPP
    rA0 = rowsum8(rA0); rA1 = rowsum8(rA1);
    rB0 = rowsum8(rB0); rB1 = rowsum8(rB1);
    float pA0 = mA ? __expf(rA0 * SC) : 0.f;
    float pA1 = mA ? __expf(rA1 * SC) : 0.f;
    float pB0 = mB ? __expf(rB0 * SC) : 0.f;
    float pB1 = mB ? __expf(rB1 * SC) : 0.f;
    dA0 += pA0; dA1 += pA1; dB0 += pB0; dB1 += pB1;
    alA0 = fmaf(pA0, bflo(vA.x), alA0); alA1 = fmaf(pA0, bflo(vA.y), alA1);
    alA2 = fmaf(pA0, bflo(vA.z), alA2); alA3 = fmaf(pA0, bflo(vA.w), alA3);
    ahA0 = fmaf(pA1, bfhi(vA.x), ahA0); ahA1 = fmaf(pA1, bfhi(vA.y), ahA1);
    ahA2 = fmaf(pA1, bfhi(vA.z), ahA2); ahA3 = fmaf(pA1, bfhi(vA.w), ahA3);
    alB0 = fmaf(pB0, bflo(vB.x), alB0); alB1 = fmaf(pB0, bflo(vB.y), alB1);
    alB2 = fmaf(pB0, bflo(vB.z), alB2); alB3 = fmaf(pB0, bflo(vB.w), alB3);
    ahB0 = fmaf(pB1, bfhi(vB.x), ahB0); ahB1 = fmaf(pB1, bfhi(vB.y), ahB1);
    ahB2 = fmaf(pB1, bfhi(vB.z), ahB2); ahB3 = fmaf(pB1, bfhi(vB.w), ahB3);
    kA = kAn; vA = vAn; mA = mAn;
    kB = kBn; vB = vBn; mB = mBn;
  }
  float d0 = dA0 + dB0, d1 = dA1 + dB1;
  float al0 = alA0 + alB0, al1 = alA1 + alB1, al2 = alA2 + alB2, al3 = alA3 + alB3;
  float ah0 = ahA0 + ahB0, ah1 = ahA1 + ahB1, ah2 = ahA2 + ahB2, ah3 = ahA3 + ahB3;
  // cross-row merges (once per node)
  d0 += __shfl_xor(d0, 16, 64); d0 += __shfl_xor(d0, 32, 64);
  d1 += __shfl_xor(d1, 16, 64); d1 += __shfl_xor(d1, 32, 64);
  al0 += __shfl_xor(al0, 16, 64); al0 += __shfl_xor(al0, 32, 64);
  al1 += __shfl_xor(al1, 16, 64); al1 += __shfl_xor(al1, 32, 64);
  al2 += __shfl_xor(al2, 16, 64); al2 += __shfl_xor(al2, 32, 64);
  al3 += __shfl_xor(al3, 16, 64); al3 += __shfl_xor(al3, 32, 64);
  ah0 += __shfl_xor(ah0, 16, 64); ah0 += __shfl_xor(ah0, 32, 64);
  ah1 += __shfl_xor(ah1, 16, 64); ah1 += __shfl_xor(ah1, 32, 64);
  ah2 += __shfl_xor(ah2, 16, 64); ah2 += __shfl_xor(ah2, 32, 64);
  ah3 += __shfl_xor(ah3, 16, 64); ah3 += __shfl_xor(ah3, 32, 64);
  float rd0 = 1.f / fmaxf(d0, 1e-9f), rd1 = 1.f / fmaxf(d1, 1e-9f);
  float ol0 = fmaxf(al0 * rd0, 0.f), ol1 = fmaxf(al1 * rd0, 0.f);
  float ol2 = fmaxf(al2 * rd0, 0.f), ol3 = fmaxf(al3 * rd0, 0.f);
  float oh0 = fmaxf(ah0 * rd1, 0.f), oh1 = fmaxf(ah1 * rd1, 0.f);
  float oh2 = fmaxf(ah2 * rd1, 0.f), oh3 = fmaxf(ah3 * rd1, 0.f);
  float s1 = ol0 + ol1 + ol2 + ol3 + oh0 + oh1 + oh2 + oh3;
  float s2 = ol0 * ol0 + ol1 * ol1 + ol2 * ol2 + ol3 * ol3 +
             oh0 * oh0 + oh1 * oh1 + oh2 * oh2 + oh3 * oh3;
  // LN reduce over dd (16-lane row): DPP
  s1 = rowsum16(s1);
  s2 = rowsum16(s2);
  float mean = s1 * (1.f / 128.f);
  float var = s2 * (1.f / 128.f) - mean * mean;
  float rs = rsqrtf(var + 1e-5f);
  if (e == 0) {
    floatx4 gl = *(const floatx4*)(g + dd * 4);
    floatx4 bl = *(const floatx4*)(bb + dd * 4);
    floatx4 gh = *(const floatx4*)(g + 64 + dd * 4);
    floatx4 bh = *(const floatx4*)(bb + 64 + dd * 4);
    float hl0 = (ol0 - mean) * rs * gl[0] + bl[0];
    float hl1 = (ol1 - mean) * rs * gl[1] + bl[1];
    float hl2 = (ol2 - mean) * rs * gl[2] + bl[2];
    float hl3 = (ol3 - mean) * rs * gl[3] + bl[3];
    float hh0 = (oh0 - mean) * rs * gh[0] + bh[0];
    float hh1 = (oh1 - mean) * rs * gh[1] + bh[1];
    float hh2 = (oh2 - mean) * rs * gh[2] + bh[2];
    float hh3 = (oh3 - mean) * rs * gh[3] + bh[3];
    if (outp == nullptr) {
      uint2 w0, w1;
      w0.x = packbf(hl0, hl1); w0.y = packbf(hl2, hl3);
      w1.x = packbf(hh0, hh1); w1.y = packbf(hh2, hh3);
      *(uint2*)(hb + (size_t)n * 128 + dd * 4) = w0;
      *(uint2*)(hb + (size_t)n * 128 + 64 + dd * 4) = w1;
    } else {
      const float2* wo2 = (const float2*)wo;
      float2 wa0 = wo2[dd * 4], wa1 = wo2[dd * 4 + 1];
      float2 wa2 = wo2[dd * 4 + 2], wa3 = wo2[dd * 4 + 3];
      float2 wb0 = wo2[64 + dd * 4], wb1 = wo2[64 + dd * 4 + 1];
      float2 wb2 = wo2[64 + dd * 4 + 2], wb3 = wo2[64 + dd * 4 + 3];
      float p0 = hl0 * wa0.x + hl1 * wa1.x + hl2 * wa2.x + hl3 * wa3.x +
                 hh0 * wb0.x + hh1 * wb1.x + hh2 * wb2.x + hh3 * wb3.x;
      float p1 = hl0 * wa0.y + hl1 * wa1.y + hl2 * wa2.y + hl3 * wa3.y +
                 hh0 * wb0.y + hh1 * wb1.y + hh2 * wb2.y + hh3 * wb3.y;
      p0 = rowsum16(p0);
      p1 = rowsum16(p1);
      if (dd == 0) {
        outp[n * 2] = p0 + bo[0];
        outp[n * 2 + 1] = p1 + bo[1];
      }
    }
  }
}

// ---------------------------------------------------------------------------
extern "C" void kernel_launch(void* const* d_in, const int* in_sizes, int n_in,
                              void* d_out, int out_size, void* d_ws, size_t ws_size,
                              hipStream_t stream) {
  const float* x = (const float*)d_in[0];
  const float* neif = (const float*)d_in[1];
  const int* ei = (const int*)d_in[2];
  const float* w_in = (const float*)d_in[3];
  const float* b_in = (const float*)d_in[4];
  const float* mha_in_w = (const float*)d_in[5];
  const float* mha_in_b = (const float*)d_in[6];
  const float* mha_out_w = (const float*)d_in[7];
  const float* mha_out_b = (const float*)d_in[8];
  const float* w_nei = (const float*)d_in[9];
  const float* b_nei = (const float*)d_in[10];
  const float* wq = (const float*)d_in[11];
  const float* bq = (const float*)d_in[12];
  const float* wk = (const float*)d_in[13];
  const float* bk = (const float*)d_in[14];
  const float* wv = (const float*)d_in[15];
  const float* bv = (const float*)d_in[16];
  const float* ln_g = (const float*)d_in[17];
  const float* ln_b = (const float*)d_in[18];
  const float* w_out = (const float*)d_in[19];
  const float* b_out = (const float*)d_in[20];
  float* out = (float*)d_out;

  // workspace layout (~62 MB)
  char* wsb = (char*)d_ws;
  size_t off = 0;
  unsigned* q2 = (unsigned*)(wsb + off); off += (size_t)NN * 64 * 4;
  unsigned* k2 = (unsigned*)(wsb + off); off += (size_t)NN * 64 * 4;
  unsigned* v2 = (unsigned*)(wsb + off); off += (size_t)NN * 64 * 4;
  int* esrc = (int*)(wsb + off);         off += (size_t)2 * NN * 64 * 4;
  u16* Yb = (u16*)(wsb + off);           off += (size_t)NN * 256 * 2;
  u16* hb = (u16*)(wsb + off);           off += (size_t)NN * 128 * 2;
  u16* wt3 = (u16*)(wsb + off);          off += (size_t)768 * 128 * 2;
  u16* wtP2 = (u16*)(wsb + off);         off += (size_t)128 * 384 * 2;
  u16* wtQK = (u16*)(wsb + off);         off += (size_t)128 * 64 * 2;
  float* G = (float*)(wsb + off);        off += (size_t)256 * 128 * 4;
  float* fusedW = (float*)(wsb + off);   off += 64 * 128 * 4;
  float* fusedB = (float*)(wsb + off);   off += 128 * 4;
  float* fusedB2 = (float*)(wsb + off);  off += 128 * 4;
  int* cnt = (int*)(wsb + off);          off += (size_t)2 * NN * 4;

  k_fuse<<<65, 128, 0, stream>>>(mha_out_w, mha_out_b, w_nei, b_nei, b_in, fusedW, fusedB);
  k_prepB<<<257, 128, 0, stream>>>(mha_in_w, fusedW, fusedB, mha_in_b, G, fusedB2);
  k_prepP2<<<128, 384, 0, stream>>>(w_in, G, wtP2);
  k_prepA<<<832, 128, 0, stream>>>(wq, wk, wv, mha_in_w, wt3, wtQK);

  k_mha7<<<3000, 640, 0, stream>>>(neif, wtQK, mha_in_b, Yb);
  k_proj5<<<469, 256, 0, stream>>>(x, Yb, wtP2, fusedB2, hb);

  hipMemsetAsync(cnt, 0, 2 * NN * sizeof(int), stream);
  k_fill<<<3750, 256, 0, stream>>>(ei, cnt, esrc);

  for (int l = 0; l < 2; ++l) {
    k_qkv4<<<469, 256, 0, stream>>>(hb, wt3 + (size_t)l * 3 * 128 * 128,
                                    bq + l * 128, bk + l * 128, bv + l * 128,
                                    q2, k2, v2);
    k_sagg7<<<NN / 4, 256, 0, stream>>>(q2, k2, v2, esrc + (size_t)l * NN * 64,
                                        cnt + l * NN, ln_g + l * 128,
                                        ln_b + l * 128, hb,
                                        w_out, b_out, l == 0 ? nullptr : out);
  }
}

// Round 10
// 300.028 us; speedup vs baseline: 3.4342x; 1.0526x over previous
//
#include <hip/hip_runtime.h>
#include <hip/hip_bf16.h>

#define NN 30000
#define EE 480000

typedef __attribute__((ext_vector_type(8))) short short8;
typedef __attribute__((ext_vector_type(4))) short short4v;
typedef __attribute__((ext_vector_type(4))) float floatx4;
typedef unsigned short u16;

__device__ __forceinline__ u16 f2bf(float f) {
  union { float f; unsigned u; } v; v.f = f;
  unsigned u = v.u;
  u += 0x7FFFu + ((u >> 16) & 1u);  // RNE
  return (u16)(u >> 16);
}
__device__ __forceinline__ float bf2f(u16 u) {
  union { unsigned u; float f; } v; v.u = ((unsigned)u) << 16;
  return v.f;
}
__device__ __forceinline__ float bflo(unsigned u) {
  union { unsigned x; float f; } v; v.x = u << 16; return v.f;
}
__device__ __forceinline__ float bfhi(unsigned u) {
  union { unsigned x; float f; } v; v.x = u & 0xFFFF0000u; return v.f;
}
__device__ __forceinline__ unsigned packbf(float a, float b) {
  return (unsigned)f2bf(a) | ((unsigned)f2bf(b) << 16);
}
__device__ __forceinline__ short8 pack8(float4 A, float4 B) {
  union { unsigned u[4]; short8 s; } r;
  r.u[0] = packbf(A.x, A.y);
  r.u[1] = packbf(A.z, A.w);
  r.u[2] = packbf(B.x, B.y);
  r.u[3] = packbf(B.z, B.w);
  return r.s;
}

// ---- DPP cross-lane adds (VALU pipe, no LDS) ----
template <int CTRL>
__device__ __forceinline__ float dppadd(float v) {
  int s = __builtin_amdgcn_update_dpp(0, __builtin_bit_cast(int, v), CTRL, 0xF, 0xF, true);
  return v + __builtin_bit_cast(float, s);
}
__device__ __forceinline__ float rowsum16(float v) {
  v = dppadd<0x121>(v); v = dppadd<0x122>(v); v = dppadd<0x124>(v); v = dppadd<0x128>(v);
  return v;
}
__device__ __forceinline__ float rowsum8(float v) {
  v = dppadd<0xB1>(v); v = dppadd<0x4E>(v); v = dppadd<0x141>(v);
  return v;
}

#define MFMA32 __builtin_amdgcn_mfma_f32_16x16x32_bf16

#if __has_builtin(__builtin_amdgcn_mfma_f32_16x16x16bf16_1k)
__device__ __forceinline__ floatx4 MFMA16(short4v a, short4v b, floatx4 c) {
  return __builtin_amdgcn_mfma_f32_16x16x16bf16_1k(a, b, c, 0, 0, 0);
}
#else
__device__ __forceinline__ floatx4 MFMA16(short4v a, short4v b, floatx4 c) {
  asm volatile("v_mfma_f32_16x16x16_bf16 %0, %1, %2, %0"
               : "+v"(c) : "v"(a), "v"(b));
  return c;
}
#endif

// ---------------------------------------------------------------------------
// k_fuse: fusedW = mha_out_w @ w_nei ; fusedB = b_in + b_nei + mha_out_b @ w_nei
// ---------------------------------------------------------------------------
__global__ __launch_bounds__(128) void k_fuse(
    const float* __restrict__ out_w, const float* __restrict__ out_b,
    const float* __restrict__ w_nei, const float* __restrict__ b_nei,
    const float* __restrict__ b_in,
    float* __restrict__ fusedW, float* __restrict__ fusedB) {
  int i = blockIdx.x, j = threadIdx.x;
  if (i < 64) {
    float a = 0.f;
    for (int kk = 0; kk < 64; ++kk) a = fmaf(out_w[i * 64 + kk], w_nei[kk * 128 + j], a);
    fusedW[i * 128 + j] = a;
  } else {
    float a = b_in[j] + b_nei[j];
    for (int kk = 0; kk < 64; ++kk) a = fmaf(out_b[kk], w_nei[kk * 128 + j], a);
    fusedB[j] = a;
  }
}

// merged: blocks 0-255 -> G rows; block 256 -> fusedB2
__global__ __launch_bounds__(128) void k_prepB(
    const float* __restrict__ in_w, const float* __restrict__ fusedW,
    const float* __restrict__ fusedB, const float* __restrict__ in_b,
    float* __restrict__ G, float* __restrict__ fusedB2) {
  int bx = blockIdx.x, c = threadIdx.x;
  if (bx < 256) {
    int h = bx >> 6, d = bx & 63;
    float a = 0.f;
    for (int dd = 0; dd < 16; ++dd)
      a = fmaf(in_w[d * 192 + 128 + h * 16 + dd], fusedW[(h * 16 + dd) * 128 + c], a);
    G[bx * 128 + c] = a;
  } else {
    float a = fusedB[c];
    for (int d = 0; d < 64; ++d) a = fmaf(in_b[128 + d], fusedW[d * 128 + c], a);
    fusedB2[c] = a;
  }
}

// merged: blocks 0-127 -> wtP2; 128-895 -> wt3; 896-959 -> wtQK
__global__ __launch_bounds__(128) void k_prep2(
    const float* __restrict__ w_in, const float* __restrict__ G,
    const float* __restrict__ wq, const float* __restrict__ wk,
    const float* __restrict__ wv, const float* __restrict__ in_w,
    u16* __restrict__ wtP2, u16* __restrict__ wt3, u16* __restrict__ wtQK) {
  int bx = blockIdx.x, t = threadIdx.x;
  if (bx < 128) {
    int c = bx;
#pragma unroll
    for (int part = 0; part < 3; ++part) {
      int k = part * 128 + t;
      float v = (k < 128) ? w_in[(size_t)k * 128 + c] : G[(size_t)(k - 128) * 128 + c];
      wtP2[(size_t)c * 384 + k] = f2bf(v);
    }
  } else if (bx < 896) {
    int b2 = bx - 128;
    int l = b2 / 384, rem = b2 % 384, o = rem >> 7, c = rem & 127;
    const float* w = (o == 0 ? wq : (o == 1 ? wk : wv)) + (size_t)l * 16384;
    wt3[(size_t)b2 * 128 + t] = f2bf(w[(size_t)t * 128 + c]);
  } else {
    int c = (bx - 896) * 2 + (t >> 6), kk = t & 63;
    float s = (c < 64) ? 0.25f : 1.f;
    wtQK[(size_t)c * 64 + kk] = f2bf(s * in_w[(size_t)kk * 192 + c]);
  }
}

// ---------------------------------------------------------------------------
// k_mha8: fused QK-GEMM + per-node attention colsums + Y. 10 nodes per block.
// Phase 2 Y-step: cs (wave-uniform after DPP colsum) -> tiny LDS broadcast;
// Y computed with lane=d, 10 coalesced x reads (L1-warm) + 40 VALU FMA.
// No xsT staging, no MFMA in Y-step. LDS: qks 29.6KB + cs 1.9KB.
// ---------------------------------------------------------------------------
__global__ __launch_bounds__(640) void k_mha8(
    const float* __restrict__ xn,    // nei_features [300000,64] f32
    const u16* __restrict__ wtQK,    // [128][64] bf16
    const float* __restrict__ in_b,  // [192]
    u16* __restrict__ Yb) {          // [NN,256]
  __shared__ unsigned qks[112 * 66];
  __shared__ float cs_lds[10][4][12];
  int t = threadIdx.x, w = t >> 6, l = t & 63;
  int lr = l & 15, lq = l >> 4;
  const floatx4 zf = {0.f, 0.f, 0.f, 0.f};
  size_t r0 = (size_t)blockIdx.x * 100;

  // ---- phase 1 (waves 0-6): QK GEMM -> LDS ----
  if (w < 7) {
    int row = w * 16 + lr;
    size_t arow = r0 + row;
    if (arow > 299999) arow = 299999;
    const float* xp = xn + arow * 64 + lq * 8;
    float4 f0 = *(const float4*)xp;
    float4 f1 = *(const float4*)(xp + 4);
    float4 f2 = *(const float4*)(xp + 32);
    float4 f3 = *(const float4*)(xp + 36);
    short8 a0 = pack8(f0, f1), a1 = pack8(f2, f3);
    floatx4 acc[8];
#pragma unroll
    for (int ct = 0; ct < 8; ++ct) acc[ct] = zf;
#pragma unroll
    for (int ct = 0; ct < 8; ++ct) {
      const short8* bp = (const short8*)(wtQK + (size_t)(ct * 16 + lr) * 64);
      acc[ct] = MFMA32(a0, bp[lq], acc[ct], 0, 0, 0);
      acc[ct] = MFMA32(a1, bp[4 + lq], acc[ct], 0, 0, 0);
    }
#pragma unroll
    for (int ct = 0; ct < 4; ++ct) {
      float bq_ = in_b[ct * 16 + lr] * 0.25f;
      float bk_ = in_b[64 + ct * 16 + lr];
#pragma unroll
      for (int r = 0; r < 4; ++r)
        qks[(w * 16 + lq * 4 + r) * 66 + ct * 16 + lr] =
            packbf(acc[ct][r] + bq_, acc[ct + 4][r] + bk_);
    }
  }
  __syncthreads();

  // ---- phase 2: one node per wave ----
  int seqc = lr < 10 ? lr : 9;
  {
#pragma unroll
    for (int h = 0; h < 4; ++h) {
      const unsigned* rp = &qks[(w * 10 + seqc) * 66 + h * 16 + lq * 4];
      uint2 u0 = *(const uint2*)rp;
      uint2 u1 = *(const uint2*)(rp + 2);
      union { unsigned u[2]; short4v s; } qv, kv;
      qv.u[0] = (u0.x & 0xFFFFu) | (u0.y << 16);
      qv.u[1] = (u1.x & 0xFFFFu) | (u1.y << 16);
      kv.u[0] = (u0.x >> 16) | (u0.y & 0xFFFF0000u);
      kv.u[1] = (u1.x >> 16) | (u1.y & 0xFFFF0000u);
      floatx4 s4 = MFMA16(kv.s, qv.s, zf);   // S^T[j=lq*4+r][i=lr]
      int j0 = lq * 4;
      float e0 = (j0 + 0 < 10) ? __expf(s4[0]) : 0.f;
      float e1 = (j0 + 1 < 10) ? __expf(s4[1]) : 0.f;
      float e2 = (j0 + 2 < 10) ? __expf(s4[2]) : 0.f;
      float e3 = (j0 + 3 < 10) ? __expf(s4[3]) : 0.f;
      float den = e0 + e1 + e2 + e3;
      den += __shfl_xor(den, 16, 64);
      den += __shfl_xor(den, 32, 64);
      float rden = 0.1f / den;  // fold seq-mean 1/10
      float v0 = (lr < 10) ? e0 * rden : 0.f;
      float v1 = (lr < 10) ? e1 * rden : 0.f;
      float v2 = (lr < 10) ? e2 * rden : 0.f;
      float v3 = (lr < 10) ? e3 * rden : 0.f;
      // colsum over i (16-lane row) via DPP - result uniform in row
      v0 = rowsum16(v0);
      v1 = rowsum16(v1);
      v2 = rowsum16(v2);
      v3 = rowsum16(v3);
      if (lr == 0) {
        cs_lds[w][h][lq * 4 + 0] = v0;
        cs_lds[w][h][lq * 4 + 1] = v1;
        cs_lds[w][h][lq * 4 + 2] = v2;
        cs_lds[w][h][lq * 4 + 3] = v3;
      }
    }
    // same-wave LDS write->read: no barrier needed (lgkmcnt by compiler)
    size_t node = (size_t)blockIdx.x * 10 + w;
    const float* xp2 = xn + node * 640 + l;  // lane l = dim d
    float y0 = 0.f, y1 = 0.f, y2 = 0.f, y3 = 0.f;
#pragma unroll
    for (int j = 0; j < 10; ++j) {
      float xv = xp2[j * 64];                // coalesced 256B, L1-warm
      y0 = fmaf(cs_lds[w][0][j], xv, y0);
      y1 = fmaf(cs_lds[w][1][j], xv, y1);
      y2 = fmaf(cs_lds[w][2][j], xv, y2);
      y3 = fmaf(cs_lds[w][3][j], xv, y3);
    }
    size_t yb = node * 256;
    Yb[yb + l] = f2bf(y0);
    Yb[yb + 64 + l] = f2bf(y1);
    Yb[yb + 128 + l] = f2bf(y2);
    Yb[yb + 192 + l] = f2bf(y3);
  }
}

// ---------------------------------------------------------------------------
// k_projqkv: h0 = [x | Y] @ wtP2 + fusedB2 (K=384 MFMA) staged in LDS (bf16),
// then layer-0 q,k,v = h0 @ {wq,wk,wv} + b directly (h0 never hits HBM).
// ---------------------------------------------------------------------------
__global__ __launch_bounds__(256) void k_projqkv(
    const float* __restrict__ x, const u16* __restrict__ Yb,
    const u16* __restrict__ wtP2, const float* __restrict__ fusedB2,
    const u16* __restrict__ wt3l,
    const float* __restrict__ bqL, const float* __restrict__ bkL,
    const float* __restrict__ bvL,
    unsigned* __restrict__ q2, unsigned* __restrict__ k2, unsigned* __restrict__ v2) {
  __shared__ u16 hs[64 * 128];
  int t = threadIdx.x, w = t >> 6, l = t & 63, lr = l & 15, lq = l >> 4;
  int row0 = blockIdx.x * 64 + w * 16;
  int arow = row0 + lr; if (arow >= NN) arow = NN - 1;
  // ---- phase A: projection ----
  {
    const float* xp = x + (size_t)arow * 128;
    const short8* yp = (const short8*)(Yb + (size_t)arow * 256);
    short8 afr[12];
#pragma unroll
    for (int kb = 0; kb < 4; ++kb) {
      float4 fa = *(const float4*)(xp + kb * 32 + lq * 8);
      float4 fb = *(const float4*)(xp + kb * 32 + lq * 8 + 4);
      afr[kb] = pack8(fa, fb);
    }
#pragma unroll
    for (int m = 0; m < 8; ++m) afr[4 + m] = yp[m * 4 + lq];
    floatx4 acc[8];
#pragma unroll
    for (int ct = 0; ct < 8; ++ct) acc[ct] = (floatx4){0.f, 0.f, 0.f, 0.f};
#pragma unroll
    for (int ct = 0; ct < 8; ++ct) {
      const short8* bp = (const short8*)(wtP2 + (size_t)(ct * 16 + lr) * 384);
#pragma unroll
      for (int kb = 0; kb < 12; ++kb)
        acc[ct] = MFMA32(afr[kb], bp[kb * 4 + lq], acc[ct], 0, 0, 0);
    }
    int lrow = w * 16;
#pragma unroll
    for (int ct = 0; ct < 8; ++ct) {
      int col = ct * 16 + lr;
      float bias = fusedB2[col];
#pragma unroll
      for (int r = 0; r < 4; ++r)
        hs[(lrow + lq * 4 + r) * 128 + col] = f2bf(acc[ct][r] + bias);
    }
  }
  __syncthreads();
  // ---- phase B: layer-0 QKV from LDS h-tile ----
  {
    int lrow = w * 16 + lr;
    const short8* ap = (const short8*)(hs + lrow * 128);
    short8 a0 = ap[lq], a1 = ap[4 + lq], a2 = ap[8 + lq], a3 = ap[12 + lq];
    const short8* wt8 = (const short8*)wt3l;
    floatx4 acc[24];
#pragma unroll
    for (int ct = 0; ct < 24; ++ct) acc[ct] = (floatx4){0.f, 0.f, 0.f, 0.f};
#pragma unroll
    for (int ct = 0; ct < 24; ++ct) {
      const short8* bp = wt8 + (size_t)((ct >> 3) * 128 + (ct & 7) * 16 + lr) * 16;
      acc[ct] = MFMA32(a0, bp[lq], acc[ct], 0, 0, 0);
      acc[ct] = MFMA32(a1, bp[4 + lq], acc[ct], 0, 0, 0);
      acc[ct] = MFMA32(a2, bp[8 + lq], acc[ct], 0, 0, 0);
      acc[ct] = MFMA32(a3, bp[12 + lq], acc[ct], 0, 0, 0);
    }
#pragma unroll
    for (int o = 0; o < 3; ++o) {
      unsigned* op = o == 0 ? q2 : (o == 1 ? k2 : v2);
      const float* bp2 = o == 0 ? bqL : (o == 1 ? bkL : bvL);
#pragma unroll
      for (int cc = 0; cc < 4; ++cc) {
        int col = cc * 16 + lr;
        float blo = bp2[col], bhi = bp2[64 + col];
        floatx4 alo = acc[o * 8 + cc], ahi = acc[o * 8 + cc + 4];
#pragma unroll
        for (int r = 0; r < 4; ++r) {
          int row = row0 + lq * 4 + r;
          if (row < NN)
            op[(size_t)row * 64 + col] = packbf(alo[r] + blo, ahi[r] + bhi);
        }
      }
    }
  }
}

// ---------------------------------------------------------------------------
// k_qkv4: q,k,v = h_bf @ {wq,wk,wv} + b, MFMA; PAIRED u32 output layout.
// ---------------------------------------------------------------------------
__global__ __launch_bounds__(256) void k_qkv4(
    const u16* __restrict__ hb, const u16* __restrict__ wt3l,
    const float* __restrict__ bqL, const float* __restrict__ bkL,
    const float* __restrict__ bvL,
    unsigned* __restrict__ q2, unsigned* __restrict__ k2, unsigned* __restrict__ v2) {
  int t = threadIdx.x, w = t >> 6, l = t & 63, lr = l & 15, lq = l >> 4;
  int row0 = blockIdx.x * 64 + w * 16;
  int arow = row0 + lr; if (arow >= NN) arow = NN - 1;
  const short8* ap = (const short8*)(hb + (size_t)arow * 128);
  short8 a0 = ap[lq], a1 = ap[4 + lq], a2 = ap[8 + lq], a3 = ap[12 + lq];
  const short8* wt8 = (const short8*)wt3l;
  floatx4 acc[24];
#pragma unroll
  for (int ct = 0; ct < 24; ++ct) acc[ct] = (floatx4){0.f, 0.f, 0.f, 0.f};
#pragma unroll
  for (int ct = 0; ct < 24; ++ct) {
    const short8* bp = wt8 + (size_t)((ct >> 3) * 128 + (ct & 7) * 16 + lr) * 16;
    acc[ct] = MFMA32(a0, bp[lq], acc[ct], 0, 0, 0);
    acc[ct] = MFMA32(a1, bp[4 + lq], acc[ct], 0, 0, 0);
    acc[ct] = MFMA32(a2, bp[8 + lq], acc[ct], 0, 0, 0);
    acc[ct] = MFMA32(a3, bp[12 + lq], acc[ct], 0, 0, 0);
  }
#pragma unroll
  for (int o = 0; o < 3; ++o) {
    unsigned* op = o == 0 ? q2 : (o == 1 ? k2 : v2);
    const float* bp2 = o == 0 ? bqL : (o == 1 ? bkL : bvL);
#pragma unroll
    for (int cc = 0; cc < 4; ++cc) {
      int col = cc * 16 + lr;
      float blo = bp2[col], bhi = bp2[64 + col];
      floatx4 alo = acc[o * 8 + cc], ahi = acc[o * 8 + cc + 4];
#pragma unroll
      for (int r = 0; r < 4; ++r) {
        int row = row0 + lq * 4 + r;
        if (row < NN)
          op[(size_t)row * 64 + col] = packbf(alo[r] + blo, ahi[r] + bhi);
      }
    }
  }
}

// ---------------------------------------------------------------------------
// k_fill: bucketed adjacency, both layers.
// ---------------------------------------------------------------------------
__global__ __launch_bounds__(256) void k_fill(const int* __restrict__ ei,
                                              int* __restrict__ cnt,
                                              int* __restrict__ esrc) {
  int gthr = blockIdx.x * 256 + threadIdx.x;
  if (gthr < 2 * EE) {
    int l = gthr >= EE;
    int e = gthr - l * EE;
    int s = ei[(size_t)(2 * l) * EE + e];
    int d = ei[(size_t)(2 * l + 1) * EE + e];
    int c = atomicAdd(&cnt[l * NN + d], 1);
    if (c < 64) esrc[((size_t)l * NN + d) * 64 + c] = s;
  }
}

// ---------------------------------------------------------------------------
// k_sagg7: fused edge-score + segment-softmax (no max) + PV + ReLU + LN,
// DPP reduces, 2-way ILP. Optionally fuses final 128x2 projection.
// ---------------------------------------------------------------------------
__global__ __launch_bounds__(256) void k_sagg7(
    const unsigned* __restrict__ q2, const unsigned* __restrict__ k2,
    const unsigned* __restrict__ v2, const int* __restrict__ esrc,
    const int* __restrict__ cnt, const float* __restrict__ g,
    const float* __restrict__ bb, u16* __restrict__ hb,
    const float* __restrict__ wo, const float* __restrict__ bo,
    float* __restrict__ outp) {
  const float SC = 0.17677669529663687f;
  int t = threadIdx.x, w = t >> 6, l = t & 63;
  int e = l >> 4, dd = l & 15;
  int n = blockIdx.x * 4 + w;
  int deg = cnt[n]; if (deg > 64) deg = 64;
  const int* sp = esrc + (size_t)n * 64;
  uint4 qp = *(const uint4*)(q2 + (size_t)n * 64 + dd * 4);
  float ql0 = bflo(qp.x), ql1 = bflo(qp.y), ql2 = bflo(qp.z), ql3 = bflo(qp.w);
  float qh0 = bfhi(qp.x), qh1 = bfhi(qp.y), qh2 = bfhi(qp.z), qh3 = bfhi(qp.w);
  float dA0 = 0.f, dA1 = 0.f, dB0 = 0.f, dB1 = 0.f;
  float alA0 = 0.f, alA1 = 0.f, alA2 = 0.f, alA3 = 0.f;
  float ahA0 = 0.f, ahA1 = 0.f, ahA2 = 0.f, ahA3 = 0.f;
  float alB0 = 0.f, alB1 = 0.f, alB2 = 0.f, alB3 = 0.f;
  float ahB0 = 0.f, ahB1 = 0.f, ahB2 = 0.f, ahB3 = 0.f;
  uint4 kA = {0, 0, 0, 0}, vA = {0, 0, 0, 0};
  uint4 kB = {0, 0, 0, 0}, vB = {0, 0, 0, 0};
  bool mA = false, mB = false;
  if (deg > 0) {
    int iA = e < deg ? e : deg - 1;           mA = e < deg;
    int iB = 4 + e < deg ? 4 + e : deg - 1;   mB = 4 + e < deg;
    int sA = sp[iA], sB = sp[iB];
    kA = *(const uint4*)(k2 + (size_t)sA * 64 + dd * 4);
    vA = *(const uint4*)(v2 + (size_t)sA * 64 + dd * 4);
    kB = *(const uint4*)(k2 + (size_t)sB * 64 + dd * 4);
    vB = *(const uint4*)(v2 + (size_t)sB * 64 + dd * 4);
  }
  for (int base = 0; base < deg; base += 8) {
    uint4 kAn = {0, 0, 0, 0}, vAn = {0, 0, 0, 0};
    uint4 kBn = {0, 0, 0, 0}, vBn = {0, 0, 0, 0};
    bool mAn = false, mBn = false;
    int nb = base + 8;
    if (nb < deg) {
      int iA = nb + e < deg ? nb + e : deg - 1;         mAn = nb + e < deg;
      int iB = nb + 4 + e < deg ? nb + 4 + e : deg - 1; mBn = nb + 4 + e < deg;
      int sA = sp[iA], sB = sp[iB];
      kAn = *(const uint4*)(k2 + (size_t)sA * 64 + dd * 4);
      vAn = *(const uint4*)(v2 + (size_t)sA * 64 + dd * 4);
      kBn = *(const uint4*)(k2 + (size_t)sB * 64 + dd * 4);
      vBn = *(const uint4*)(v2 + (size_t)sB * 64 + dd * 4);
    }
    float rA0 = ql0 * bflo(kA.x) + ql1 * bflo(kA.y) + ql2 * bflo(kA.z) + ql3 * bflo(kA.w);
    float rA1 = qh0 * bfhi(kA.x) + qh1 * bfhi(kA.y) + qh2 * bfhi(kA.z) + qh3 * bfhi(kA.w);
    float rB0 = ql0 * bflo(kB.x) + ql1 * bflo(kB.y) + ql2 * bflo(kB.z) + ql3 * bflo(kB.w);
    float rB1 = qh0 * bfhi(kB.x) + qh1 * bfhi(kB.y) + qh2 * bfhi(kB.z) + qh3 * bfhi(kB.w);
    rA0 = rowsum8(rA0); rA1 = rowsum8(rA1);
    rB0 = rowsum8(rB0); rB1 = rowsum8(rB1);
    float pA0 = mA ? __expf(rA0 * SC) : 0.f;
    float pA1 = mA ? __expf(rA1 * SC) : 0.f;
    float pB0 = mB ? __expf(rB0 * SC) : 0.f;
    float pB1 = mB ? __expf(rB1 * SC) : 0.f;
    dA0 += pA0; dA1 += pA1; dB0 += pB0; dB1 += pB1;
    alA0 = fmaf(pA0, bflo(vA.x), alA0); alA1 = fmaf(pA0, bflo(vA.y), alA1);
    alA2 = fmaf(pA0, bflo(vA.z), alA2); alA3 = fmaf(pA0, bflo(vA.w), alA3);
    ahA0 = fmaf(pA1, bfhi(vA.x), ahA0); ahA1 = fmaf(pA1, bfhi(vA.y), ahA1);
    ahA2 = fmaf(pA1, bfhi(vA.z), ahA2); ahA3 = fmaf(pA1, bfhi(vA.w), ahA3);
    alB0 = fmaf(pB0, bflo(vB.x), alB0); alB1 = fmaf(pB0, bflo(vB.y), alB1);
    alB2 = fmaf(pB0, bflo(vB.z), alB2); alB3 = fmaf(pB0, bflo(vB.w), alB3);
    ahB0 = fmaf(pB1, bfhi(vB.x), ahB0); ahB1 = fmaf(pB1, bfhi(vB.y), ahB1);
    ahB2 = fmaf(pB1, bfhi(vB.z), ahB2); ahB3 = fmaf(pB1, bfhi(vB.w), ahB3);
    kA = kAn; vA = vAn; mA = mAn;
    kB = kBn; vB = vBn; mB = mBn;
  }
  float d0 = dA0 + dB0, d1 = dA1 + dB1;
  float al0 = alA0 + alB0, al1 = alA1 + alB1, al2 = alA2 + alB2, al3 = alA3 + alB3;
  float ah0 = ahA0 + ahB0, ah1 = ahA1 + ahB1, ah2 = ahA2 + ahB2, ah3 = ahA3 + ahB3;
  d0 += __shfl_xor(d0, 16, 64); d0 += __shfl_xor(d0, 32, 64);
  d1 += __shfl_xor(d1, 16, 64); d1 += __shfl_xor(d1, 32, 64);
  al0 += __shfl_xor(al0, 16, 64); al0 += __shfl_xor(al0, 32, 64);
  al1 += __shfl_xor(al1, 16, 64); al1 += __shfl_xor(al1, 32, 64);
  al2 += __shfl_xor(al2, 16, 64); al2 += __shfl_xor(al2, 32, 64);
  al3 += __shfl_xor(al3, 16, 64); al3 += __shfl_xor(al3, 32, 64);
  ah0 += __shfl_xor(ah0, 16, 64); ah0 += __shfl_xor(ah0, 32, 64);
  ah1 += __shfl_xor(ah1, 16, 64); ah1 += __shfl_xor(ah1, 32, 64);
  ah2 += __shfl_xor(ah2, 16, 64); ah2 += __shfl_xor(ah2, 32, 64);
  ah3 += __shfl_xor(ah3, 16, 64); ah3 += __shfl_xor(ah3, 32, 64);
  float rd0 = 1.f / fmaxf(d0, 1e-9f), rd1 = 1.f / fmaxf(d1, 1e-9f);
  float ol0 = fmaxf(al0 * rd0, 0.f), ol1 = fmaxf(al1 * rd0, 0.f);
  float ol2 = fmaxf(al2 * rd0, 0.f), ol3 = fmaxf(al3 * rd0, 0.f);
  float oh0 = fmaxf(ah0 * rd1, 0.f), oh1 = fmaxf(ah1 * rd1, 0.f);
  float oh2 = fmaxf(ah2 * rd1, 0.f), oh3 = fmaxf(ah3 * rd1, 0.f);
  float s1 = ol0 + ol1 + ol2 + ol3 + oh0 + oh1 + oh2 + oh3;
  float s2 = ol0 * ol0 + ol1 * ol1 + ol2 * ol2 + ol3 * ol3 +
             oh0 * oh0 + oh1 * oh1 + oh2 * oh2 + oh3 * oh3;
  s1 = rowsum16(s1);
  s2 = rowsum16(s2);
  float mean = s1 * (1.f / 128.f);
  float var = s2 * (1.f / 128.f) - mean * mean;
  float rs = rsqrtf(var + 1e-5f);
  if (e == 0) {
    floatx4 gl = *(const floatx4*)(g + dd * 4);
    floatx4 bl = *(const floatx4*)(bb + dd * 4);
    floatx4 gh = *(const floatx4*)(g + 64 + dd * 4);
    floatx4 bh = *(const floatx4*)(bb + 64 + dd * 4);
    float hl0 = (ol0 - mean) * rs * gl[0] + bl[0];
    float hl1 = (ol1 - mean) * rs * gl[1] + bl[1];
    float hl2 = (ol2 - mean) * rs * gl[2] + bl[2];
    float hl3 = (ol3 - mean) * rs * gl[3] + bl[3];
    float hh0 = (oh0 - mean) * rs * gh[0] + bh[0];
    float hh1 = (oh1 - mean) * rs * gh[1] + bh[1];
    float hh2 = (oh2 - mean) * rs * gh[2] + bh[2];
    float hh3 = (oh3 - mean) * rs * gh[3] + bh[3];
    if (outp == nullptr) {
      uint2 w0, w1;
      w0.x = packbf(hl0, hl1); w0.y = packbf(hl2, hl3);
      w1.x = packbf(hh0, hh1); w1.y = packbf(hh2, hh3);
      *(uint2*)(hb + (size_t)n * 128 + dd * 4) = w0;
      *(uint2*)(hb + (size_t)n * 128 + 64 + dd * 4) = w1;
    } else {
      const float2* wo2 = (const float2*)wo;
      float2 wa0 = wo2[dd * 4], wa1 = wo2[dd * 4 + 1];
      float2 wa2 = wo2[dd * 4 + 2], wa3 = wo2[dd * 4 + 3];
      float2 wb0 = wo2[64 + dd * 4], wb1 = wo2[64 + dd * 4 + 1];
      float2 wb2 = wo2[64 + dd * 4 + 2], wb3 = wo2[64 + dd * 4 + 3];
      float p0 = hl0 * wa0.x + hl1 * wa1.x + hl2 * wa2.x + hl3 * wa3.x +
                 hh0 * wb0.x + hh1 * wb1.x + hh2 * wb2.x + hh3 * wb3.x;
      float p1 = hl0 * wa0.y + hl1 * wa1.y + hl2 * wa2.y + hl3 * wa3.y +
                 hh0 * wb0.y + hh1 * wb1.y + hh2 * wb2.y + hh3 * wb3.y;
      p0 = rowsum16(p0);
      p1 = rowsum16(p1);
      if (dd == 0) {
        outp[n * 2] = p0 + bo[0];
        outp[n * 2 + 1] = p1 + bo[1];
      }
    }
  }
}

// ---------------------------------------------------------------------------
extern "C" void kernel_launch(void* const* d_in, const int* in_sizes, int n_in,
                              void* d_out, int out_size, void* d_ws, size_t ws_size,
                              hipStream_t stream) {
  const float* x = (const float*)d_in[0];
  const float* neif = (const float*)d_in[1];
  const int* ei = (const int*)d_in[2];
  const float* w_in = (const float*)d_in[3];
  const float* b_in = (const float*)d_in[4];
  const float* mha_in_w = (const float*)d_in[5];
  const float* mha_in_b = (const float*)d_in[6];
  const float* mha_out_w = (const float*)d_in[7];
  const float* mha_out_b = (const float*)d_in[8];
  const float* w_nei = (const float*)d_in[9];
  const float* b_nei = (const float*)d_in[10];
  const float* wq = (const float*)d_in[11];
  const float* bq = (const float*)d_in[12];
  const float* wk = (const float*)d_in[13];
  const float* bk = (const float*)d_in[14];
  const float* wv = (const float*)d_in[15];
  const float* bv = (const float*)d_in[16];
  const float* ln_g = (const float*)d_in[17];
  const float* ln_b = (const float*)d_in[18];
  const float* w_out = (const float*)d_in[19];
  const float* b_out = (const float*)d_in[20];
  float* out = (float*)d_out;

  // workspace layout (~62 MB)
  char* wsb = (char*)d_ws;
  size_t off = 0;
  unsigned* q2 = (unsigned*)(wsb + off); off += (size_t)NN * 64 * 4;
  unsigned* k2 = (unsigned*)(wsb + off); off += (size_t)NN * 64 * 4;
  unsigned* v2 = (unsigned*)(wsb + off); off += (size_t)NN * 64 * 4;
  int* esrc = (int*)(wsb + off);         off += (size_t)2 * NN * 64 * 4;
  u16* Yb = (u16*)(wsb + off);           off += (size_t)NN * 256 * 2;
  u16* hb = (u16*)(wsb + off);           off += (size_t)NN * 128 * 2;
  u16* wt3 = (u16*)(wsb + off);          off += (size_t)768 * 128 * 2;
  u16* wtP2 = (u16*)(wsb + off);         off += (size_t)128 * 384 * 2;
  u16* wtQK = (u16*)(wsb + off);         off += (size_t)128 * 64 * 2;
  float* G = (float*)(wsb + off);        off += (size_t)256 * 128 * 4;
  float* fusedW = (float*)(wsb + off);   off += 64 * 128 * 4;
  float* fusedB = (float*)(wsb + off);   off += 128 * 4;
  float* fusedB2 = (float*)(wsb + off);  off += 128 * 4;
  int* cnt = (int*)(wsb + off);          off += (size_t)2 * NN * 4;

  k_fuse<<<65, 128, 0, stream>>>(mha_out_w, mha_out_b, w_nei, b_nei, b_in, fusedW, fusedB);
  k_prepB<<<257, 128, 0, stream>>>(mha_in_w, fusedW, fusedB, mha_in_b, G, fusedB2);
  k_prep2<<<960, 128, 0, stream>>>(w_in, G, wq, wk, wv, mha_in_w, wtP2, wt3, wtQK);

  k_mha8<<<3000, 640, 0, stream>>>(neif, wtQK, mha_in_b, Yb);

  hipMemsetAsync(cnt, 0, 2 * NN * sizeof(int), stream);
  k_fill<<<3750, 256, 0, stream>>>(ei, cnt, esrc);

  // layer 0: proj + qkv fused (h0 stays in LDS)
  k_projqkv<<<469, 256, 0, stream>>>(x, Yb, wtP2, fusedB2, wt3,
                                     bq, bk, bv, q2, k2, v2);
  k_sagg7<<<NN / 4, 256, 0, stream>>>(q2, k2, v2, esrc, cnt,
                                      ln_g, ln_b, hb, w_out, b_out, nullptr);
  // layer 1
  k_qkv4<<<469, 256, 0, stream>>>(hb, wt3 + (size_t)3 * 128 * 128,
                                  bq + 128, bk + 128, bv + 128, q2, k2, v2);
  k_sagg7<<<NN / 4, 256, 0, stream>>>(q2, k2, v2, esrc + (size_t)NN * 64,
                                      cnt + NN, ln_g + 128, ln_b + 128, hb,
                                      w_out, b_out, out);
}